// Round 12
// baseline (572.360 us; speedup 1.0000x reference)
//
#include <hip/hip_runtime.h>
#include <hip/hip_fp16.h>
#include <math.h>

// ---------------- problem constants ----------------
#define G_    32
#define NPG_  128
#define D_    128
#define N_    4096          // G_*NPG_
#define E_    65536
#define ND_   (N_*D_)       // 524288

// ---------------- workspace layout (float offsets, per side) ----------------
#define W_OFF     0                     // E_ edge weights w
#define DEG_OFF   65536                 // N_ degrees (atomic, zeroed)
#define STATS_OFF 69632                 // 2048 floats of stats (zeroed):
//   [0:128) edge colsum  [128:256) edge colsumsq [256:384) alpha [384] beta
//   [512..1024) bn1: sum/ssq/scale/shift   [1024..1536) bn2: same
#define BUF0      71680
#define HL_OFF    (BUF0 + 0*ND_)        // h_local (bern output)
#define HA_OFF    (BUF0 + 1*ND_)        // mamba out (scattered); later x2
#define X1_OFF    (BUF0 + 2*ND_)        // pre-bn1 sum; later h2 (post-attn)
#define HMID_OFF  (BUF0 + 3*ND_)        // (unused since bn1 is fused into qkv/attn)
#define XC_OFF    (BUF0 + 4*ND_)        // conv output; later q
#define DTB_OFF   (BUF0 + 5*ND_)        // k
#define YB_OFF    (BUF0 + 6*ND_)        // v
#define XZ_OFF    (BUF0 + 7*ND_)        // 2*ND_: [xq|z] per row (256); scan gate overwrites xq
#define DBL_OFF   (BUF0 + 9*ND_)        // N_*40
#define WT_OFF    (DBL_OFF + N_*40)     // (unused scratch, kept for layout stability)
#define SS_       ((size_t)(WT_OFF + 4096))
// fp16 t-scratch [E][128] halfs = 4*ND_ float slots, aliases HL..XZ+ND_.
// Edge phase (stats -> finalize -> w) completes before bern/mamba write those.
#define TBUF_OFF  HL_OFF

__device__ __forceinline__ float leakyf(float x){ return x >= 0.f ? x : 0.02f*x; }
__device__ __forceinline__ float siluf (float x){ return x / (1.f + expf(-x)); }

// ---------------- edge feature helper ----------------
__device__ __forceinline__ void edge_feat(const float* __restrict__ x,
                                          const float* __restrict__ he,
                                          const int* __restrict__ ei,
                                          int e, float* feat, int& sN, int& dN)
{
  sN = ei[e]; dN = ei[E_ + e];
  float dx = x[sN*3+0]-x[dN*3+0];
  float dy = x[sN*3+1]-x[dN*3+1];
  float dz = x[sN*3+2]-x[dN*3+2];
  float d2 = dx*dx + dy*dy + dz*dz;
  feat[0] = expf(-d2);
  feat[1] = expf(d2 * -0.1f);
  feat[2] = expf(d2 * -0.01f);
  feat[3] = expf(d2 * -0.001f);
  feat[4] = expf(d2 * -0.0001f);
#pragma unroll
  for (int j = 0; j < 27; ++j) feat[5+j] = he[(size_t)e*27 + j];
}

// ---------------- E1: per-column stats of t + fp16 t-store via LDS tile ----------------
// Compute loop has NO global stores (R11's 128 scalar short-stores serialized it).
// t goes to an LDS tile (b16 writes, conflict-free); every 16 edges the block
// flushes the 32x256B tile with coalesced dwordx4 stores (2KB/wave contiguous).
__global__ __launch_bounds__(256)
void edge_stats_kernel(const float* __restrict__ xl, const float* __restrict__ xr,
                       const float* __restrict__ hel, const float* __restrict__ her,
                       const int* __restrict__ ei1, const int* __restrict__ ei2,
                       const float* __restrict__ w1, const float* __restrict__ b1,
                       float* __restrict__ ws)
{
  int side = blockIdx.y;
  const float* x  = side ? xr  : xl;
  const float* he = side ? her : hel;
  const int*   ei = side ? ei2 : ei1;
  float* base = ws + (size_t)side*SS_;
  float* stats = base + STATS_OFF;
  __half* tbuf = (__half*)(base + TBUF_OFF);
  __shared__ float featl[256*37];
  __shared__ __half tileh[32][136];    // 2hh x 16 edges x 128 cols (rows 272B, 16B-aligned)
  __shared__ float csum[2][128], cssq[2][128];
  int tid = threadIdx.x;
  {
    int sN, dN; float feat[32];
    edge_feat(x, he, ei, blockIdx.x*256 + tid, feat, sN, dN);
#pragma unroll
    for (int j4 = 0; j4 < 8; ++j4)
      *(float4*)&featl[tid*37 + j4*4] = *(float4*)&feat[j4*4];
  }
  int c = tid & 127, hh = tid >> 7;
  float w1c[32];
#pragma unroll
  for (int j = 0; j < 32; ++j) w1c[j] = w1[j*128 + c];
  float b1c = b1[c];
  __syncthreads();
  float s1 = 0.f, s2 = 0.f;
  for (int ch = 0; ch < 8; ++ch) {
#pragma unroll
    for (int el = 0; el < 16; ++el) {
      int eb = hh*128 + ch*16 + el;
      const float* f = &featl[eb*37];
      float acc = b1c;
#pragma unroll
      for (int j4 = 0; j4 < 8; ++j4) {
        float4 f4 = *(const float4*)&f[j4*4];
        acc += f4.x*w1c[j4*4] + f4.y*w1c[j4*4+1] + f4.z*w1c[j4*4+2] + f4.w*w1c[j4*4+3];
      }
      float t = leakyf(acc);
      tileh[hh*16 + el][c] = __float2half_rn(t);
      s1 += t; s2 += t*t;
    }
    __syncthreads();
    // cooperative flush: 32 rows x 16 float4 (8 halfs each)
#pragma unroll
    for (int p = 0; p < 2; ++p) {
      int row = p*16 + (tid >> 4);     // 0..31
      int fq  = tid & 15;
      float4 v = *(const float4*)&tileh[row][fq*8];
      int eg = blockIdx.x*256 + (row >> 4)*128 + ch*16 + (row & 15);
      *(float4*)&tbuf[(size_t)eg*128 + fq*8] = v;
    }
    __syncthreads();
  }
  csum[hh][c] = s1; cssq[hh][c] = s2;
  __syncthreads();
  if (tid < 128) {
    atomicAdd(&stats[tid],     csum[0][tid] + csum[1][tid]);
    atomicAdd(&stats[128+tid], cssq[0][tid] + cssq[1][tid]);
  }
}

// ---------------- E2: finalize edge bn folded with emlp_w2 -> alpha,beta ----------------
__global__ void edge_finalize_kernel(const float* __restrict__ g_, const float* __restrict__ b_,
                                     const float* __restrict__ w2, const float* __restrict__ b2,
                                     float* __restrict__ ws)
{
  int side = blockIdx.y;
  float* stats = ws + (size_t)side*SS_ + STATS_OFF;
  __shared__ float red[128];
  int c = threadIdx.x;  // 128 threads
  const float invE = 1.f/(float)E_;
  float mean = stats[c]*invE;
  float var  = fmaxf(stats[128+c]*invE - mean*mean, 0.f);
  float scale = rsqrtf(var + 1e-5f) * g_[c];
  stats[256+c] = scale * w2[c];
  red[c] = (b_[c] - mean*scale) * w2[c];
  __syncthreads();
  for (int off = 64; off; off >>= 1) { if (c < off) red[c] += red[c+off]; __syncthreads(); }
  if (c == 0) stats[384] = red[0] + b2[0];
}

// ---------------- E3: w_e = relu(beta + sum_c alpha_c * t_c) from fp16 t-scratch -----
__global__ __launch_bounds__(256)
void edge_w_kernel(const int* __restrict__ ei1, const int* __restrict__ ei2,
                   float* __restrict__ ws)
{
  int side = blockIdx.y;
  const int* ei = side ? ei2 : ei1;
  float* base = ws + (size_t)side*SS_;
  const float* stats = base + STATS_OFF;
  const __half* tbuf = (const __half*)(base + TBUF_OFF);
  float* wbuf = base + W_OFF;
  float* deg  = base + DEG_OFF;
  __shared__ float al[128];
  int tid = threadIdx.x;
  if (tid < 128) al[tid] = stats[256+tid];
  __syncthreads();
  int e = blockIdx.x*256 + tid;
  const __half* tp = tbuf + (size_t)e*128;
  float a0 = 0.f, a1 = 0.f, a2 = 0.f, a3 = 0.f;
#pragma unroll
  for (int j = 0; j < 16; ++j) {
    float4 raw = *(const float4*)&tp[j*8];
    const __half2* hp = (const __half2*)&raw;
    float2 f0 = __half22float2(hp[0]);
    float2 f1 = __half22float2(hp[1]);
    float2 f2 = __half22float2(hp[2]);
    float2 f3 = __half22float2(hp[3]);
    const float* ac = &al[j*8];
    a0 += f0.x*ac[0] + f0.y*ac[1];
    a1 += f1.x*ac[2] + f1.y*ac[3];
    a2 += f2.x*ac[4] + f2.y*ac[5];
    a3 += f3.x*ac[6] + f3.y*ac[7];
  }
  float w = fmaxf(stats[384] + ((a0+a1) + (a2+a3)), 0.f);
  wbuf[e] = w;
  atomicAdd(&deg[ei[e]], w);
}

// ---------------- Bernstein propagation via Horner (6 matmuls) ----------------
__global__ __launch_bounds__(256)
void bern_horner_kernel(const float* __restrict__ hl_in, const float* __restrict__ hr_in,
                        const int* __restrict__ ei1, const int* __restrict__ ei2,
                        const float* __restrict__ bern_temp, float* __restrict__ ws)
{
  int side = blockIdx.y;
  int g  = blockIdx.x >> 2;
  int d0 = (blockIdx.x & 3) * 32;
  const float* h  = side ? hr_in : hl_in;
  const int*   ei = side ? ei2 : ei1;
  float* base = ws + (size_t)side*SS_;
  const float* wbuf = base + W_OFF;
  const float* deg  = base + DEG_OFF;
  float* hloc = base + HL_OFF;

  __shared__ float A[128*132];
  __shared__ float v[128*32];
  int tid = threadIdx.x;
  for (int i = tid; i < 128*132; i += 256) A[i] = 0.f;

  const float btab[7][7] = {
    { 1,  6, 15,  20, 15,  6,  1},
    { 1,  4,  5,   0, -5, -4, -1},
    { 1,  2, -1,  -4, -1,  2,  1},
    { 1,  0, -3,   0,  3,  0, -1},
    { 1, -2, -1,   4, -1, -2,  1},
    { 1, -4,  5,   0, -5,  4, -1},
    { 1, -6, 15, -20, 15, -6,  1}};
  const float comb6[7] = {1,6,15,20,15,6,1};
  float a[7];
#pragma unroll
  for (int m = 0; m < 7; ++m) a[m] = 0.f;
#pragma unroll
  for (int j = 0; j < 7; ++j) {
    float tj = fmaxf(bern_temp[j], 0.f) * comb6[j] * (1.f/64.f);
#pragma unroll
    for (int m = 0; m < 7; ++m) a[m] += tj * btab[j][m];
  }
  __syncthreads();

  int ebase = g*2048, nbase = g*128;
  for (int i = tid; i < 2048; i += 256) {
    int e = ebase + i;
    int sN = ei[e], dN = ei[E_ + e];
    float ds_ = deg[sN], dd_ = deg[dN];
    float aa = ds_ > 0.f ? rsqrtf(ds_ + 1e-12f) : 0.f;
    float bb = dd_ > 0.f ? rsqrtf(dd_ + 1e-12f) : 0.f;
    atomicAdd(&A[(dN - nbase)*132 + (sN - nbase)], wbuf[e]*aa*bb);
  }

  const int db = (tid & 7)*4;
  const int rb = (tid >> 3)*4;
  float hreg[4][4], r[4][4], t[4][4];
#pragma unroll
  for (int i = 0; i < 4; ++i) {
    float4 h4 = *(const float4*)&h[(size_t)(nbase + rb + i)*128 + d0 + db];
    hreg[i][0]=h4.x; hreg[i][1]=h4.y; hreg[i][2]=h4.z; hreg[i][3]=h4.w;
#pragma unroll
    for (int jj = 0; jj < 4; ++jj) r[i][jj] = a[6]*hreg[i][jj];
  }

  for (int step = 5; step >= 0; --step) {
    __syncthreads();
#pragma unroll
    for (int i = 0; i < 4; ++i)
      *(float4*)&v[(rb+i)*32 + db] = make_float4(r[i][0], r[i][1], r[i][2], r[i][3]);
    __syncthreads();
#pragma unroll
    for (int i = 0; i < 4; ++i)
#pragma unroll
      for (int jj = 0; jj < 4; ++jj) t[i][jj] = 0.f;
    for (int k = 0; k < 128; k += 4) {
      float4 V0 = *(const float4*)&v[(k+0)*32 + db];
      float4 V1 = *(const float4*)&v[(k+1)*32 + db];
      float4 V2 = *(const float4*)&v[(k+2)*32 + db];
      float4 V3 = *(const float4*)&v[(k+3)*32 + db];
#pragma unroll
      for (int i = 0; i < 4; ++i) {
        float4 A4 = *(const float4*)&A[(rb+i)*132 + k];
        t[i][0] += A4.x*V0.x + A4.y*V1.x + A4.z*V2.x + A4.w*V3.x;
        t[i][1] += A4.x*V0.y + A4.y*V1.y + A4.z*V2.y + A4.w*V3.y;
        t[i][2] += A4.x*V0.z + A4.y*V1.z + A4.z*V2.z + A4.w*V3.z;
        t[i][3] += A4.x*V0.w + A4.y*V1.w + A4.z*V2.w + A4.w*V3.w;
      }
    }
    float ak = a[step];
#pragma unroll
    for (int i = 0; i < 4; ++i)
#pragma unroll
      for (int jj = 0; jj < 4; ++jj) r[i][jj] = t[i][jj] + ak*hreg[i][jj];
  }

#pragma unroll
  for (int i = 0; i < 4; ++i)
    *(float4*)&hloc[(size_t)(nbase + rb + i)*128 + d0 + db] =
        make_float4(r[i][0], r[i][1], r[i][2], r[i][3]);
}

// ---------------- generic f32 GEMM, col-split for occupancy, grid.y = side ----------------
template<int K, int NC, int TC, int CSPLIT, int ACT, int GATHER, int SCATTER, int ADDC, int BIAS>
__global__ __launch_bounds__(256)
void gemm_kernel(const float* __restrict__ A0, const float* __restrict__ A1, int lda,
                 const float* __restrict__ W, const float* __restrict__ bias,
                 float* __restrict__ C0, float* __restrict__ C1, int ldc,
                 const int* __restrict__ idx0, const int* __restrict__ idx1,
                 const float* __restrict__ add0, const float* __restrict__ add1)
{
  int side = blockIdx.y;
  const float* A = side ? A1 : A0;
  float* C = side ? C1 : C0;
  const int* idx = side ? idx1 : idx0;
  const float* addsrc = side ? add1 : add0;
  constexpr int RPT = TC/8;
  constexpr int CLEN = NC/CSPLIT;
  __shared__ float Alds[32][K];
  __shared__ float Wlds[K][TC];
  const int tid = threadIdx.x;
  const int r0 = (blockIdx.x / CSPLIT) * 32;
  const int cbase = (blockIdx.x % CSPLIT) * CLEN;
  for (int i = tid*4; i < 32*K; i += 1024) {
    int r = i / K, k = i % K;
    int row = GATHER ? idx[r0 + r] : (r0 + r);
    *(float4*)&Alds[r][k] = *(const float4*)&A[(size_t)row*lda + k];
  }
  for (int c0 = cbase; c0 < cbase + CLEN; c0 += TC) {
    __syncthreads();
    for (int i = tid*4; i < K*TC; i += 1024) {
      int k = i / TC, c = i % TC;
      if (c0 + c < NC) *(float4*)&Wlds[k][c] = *(const float4*)&W[k*NC + c0 + c];
      else             *(float4*)&Wlds[k][c] = make_float4(0.f,0.f,0.f,0.f);
    }
    __syncthreads();
    const int cl = tid % TC;
    const int rsub = (tid / TC) * RPT;
    float accv[RPT];
#pragma unroll
    for (int j = 0; j < RPT; ++j) accv[j] = 0.f;
    for (int k = 0; k < K; k += 4) {
      float w0 = Wlds[k][cl], w1v = Wlds[k+1][cl], w2v = Wlds[k+2][cl], w3v = Wlds[k+3][cl];
#pragma unroll
      for (int j = 0; j < RPT; ++j) {
        float4 a4 = *(const float4*)&Alds[rsub+j][k];
        accv[j] += a4.x*w0 + a4.y*w1v + a4.z*w2v + a4.w*w3v;
      }
    }
    int c = c0 + cl;
    if (c < NC) {
#pragma unroll
      for (int j = 0; j < RPT; ++j) {
        int row  = r0 + rsub + j;
        int orow = SCATTER ? idx[row] : row;
        float vv = accv[j];
        if (BIAS)     vv += bias[c];
        if (ACT == 1) vv = leakyf(vv);
        if (ACT == 2) vv = fmaxf(vv, 0.f);
        if (ADDC)     vv += addsrc[(size_t)orow*ldc + c];
        C[(size_t)orow*ldc + c] = vv;
      }
    }
  }
}

// ---------------- qkv: 3 projections in one dispatch; bn1 fused into A-staging ----------
__global__ __launch_bounds__(256)
void qkv_kernel(const float* __restrict__ qw, const float* __restrict__ kw,
                const float* __restrict__ vw, float* __restrict__ ws)
{
  int side = blockIdx.y;
  int mat  = blockIdx.z;
  float* base = ws + (size_t)side*SS_;
  const float* A = base + X1_OFF;                 // pre-bn1 x1
  const float* bns = base + STATS_OFF + 512;      // bn1: scale at +256, shift at +384
  const float* W = mat == 0 ? qw : (mat == 1 ? kw : vw);
  float* C = base + (mat == 0 ? XC_OFF : (mat == 1 ? DTB_OFF : YB_OFF));
  __shared__ float Alds[32][128];
  __shared__ float Wlds[128][64];
  const int tid = threadIdx.x;
  const int r0 = (blockIdx.x >> 1) * 32;
  const int c0 = (blockIdx.x & 1) * 64;
  for (int i = tid*4; i < 32*128; i += 1024) {
    int k = i & 127;
    float4 a4 = *(const float4*)&A[(size_t)(r0 + (i>>7))*128 + k];
    float4 sc = *(const float4*)&bns[256 + k];
    float4 sh = *(const float4*)&bns[384 + k];
    a4.x = a4.x*sc.x + sh.x;
    a4.y = a4.y*sc.y + sh.y;
    a4.z = a4.z*sc.z + sh.z;
    a4.w = a4.w*sc.w + sh.w;
    *(float4*)&Alds[i>>7][k] = a4;
  }
  for (int i = tid*4; i < 128*64; i += 1024)
    *(float4*)&Wlds[i>>6][i&63] = *(const float4*)&W[(i>>6)*128 + c0 + (i&63)];
  __syncthreads();
  const int cl = tid & 63;
  const int rsub = (tid >> 6) * 8;
  float accv[8];
#pragma unroll
  for (int j = 0; j < 8; ++j) accv[j] = 0.f;
  for (int k = 0; k < 128; k += 4) {
    float w0 = Wlds[k][cl], w1v = Wlds[k+1][cl], w2v = Wlds[k+2][cl], w3v = Wlds[k+3][cl];
#pragma unroll
    for (int j = 0; j < 8; ++j) {
      float4 a4 = *(const float4*)&Alds[rsub+j][k];
      accv[j] += a4.x*w0 + a4.y*w1v + a4.z*w2v + a4.w*w3v;
    }
  }
#pragma unroll
  for (int j = 0; j < 8; ++j) {
    float vv = accv[j];
    if (mat < 2) vv = leakyf(vv);
    C[(size_t)(r0 + rsub + j)*128 + c0 + cl] = vv;
  }
}

// ---------------- mamba: causal depthwise conv (DCONV=4) + silu ----------------
__global__ __launch_bounds__(256)
void conv_kernel(const float* __restrict__ cw, const float* __restrict__ cb, float* __restrict__ ws)
{
  int side = blockIdx.y;
  float* base = ws + (size_t)side*SS_;
  const float* xz = base + XZ_OFF;
  float* xc = base + XC_OFF;
  int i = blockIdx.x*256 + threadIdx.x;
  int j = i >> 7, d = i & 127;
  int l = j & 127;
  float a = cb[d];
#pragma unroll
  for (int k = 0; k < 4; ++k) {
    int ll = l - 3 + k;
    if (ll >= 0) a += xz[(size_t)(j-3+k)*256 + d] * cw[d*4 + k];
  }
  xc[i] = siluf(a);
}

// ---------------- mamba scan: fused dt(softplus) + 128-step recurrence + gate ----------------
__global__ __launch_bounds__(256)
void scan_kernel(const float* __restrict__ A_log, const float* __restrict__ Dp,
                 const float* __restrict__ dtw, const float* __restrict__ dtbias,
                 float* __restrict__ ws)
{
  int side = blockIdx.z;
  int g  = blockIdx.x;
  int d0 = blockIdx.y * 16;
  float* base = ws + (size_t)side*SS_;
  const float* dbl = base + DBL_OFF;
  const float* xcb = base + XC_OFF;
  float* xz = base + XZ_OFF;

  __shared__ float ldbl[128][40];   // dt-in(8) | B(16) | C(16)
  __shared__ float lxc[128][16];
  __shared__ float ldt[128][16];
  __shared__ float lz[128][16];
  __shared__ float ly[128][16];
  __shared__ float ltw[8][16];
  __shared__ float ltb[16];

  int tid = threadIdx.x;
  int rowbase = g*128;
  if (tid < 128)      ltw[tid>>4][tid&15] = dtw[(tid>>4)*128 + d0 + (tid&15)];
  else if (tid < 144) ltb[tid-128] = dtbias[d0 + (tid-128)];
  for (int i = tid; i < 128*40; i += 256)
    ((float*)ldbl)[i] = dbl[(size_t)rowbase*40 + i];
  for (int i = tid; i < 2048; i += 256) {
    int l = i >> 4, dd = i & 15;
    lxc[l][dd] = xcb[(size_t)(rowbase+l)*128 + d0 + dd];
    lz[l][dd]  = xz[(size_t)(rowbase+l)*256 + 128 + d0 + dd];
  }
  __syncthreads();
  // dt = softplus(dbl[:, :8] @ dtw + dtb)  — once per (l,d)
  for (int i = tid; i < 2048; i += 256) {
    int l = i >> 4, dd = i & 15;
    float a = ltb[dd];
#pragma unroll
    for (int k = 0; k < 8; ++k) a += ldbl[l][k]*ltw[k][dd];
    ldt[l][dd] = a > 20.f ? a : log1pf(expf(a));
  }
  __syncthreads();

  int s = tid & 15, dl = (tid >> 4) & 15;
  float Ac  = -expf(A_log[(d0+dl)*16 + s]);
  float dpv = Dp[d0+dl];
  float hsv = 0.f;
  for (int l = 0; l < 128; ++l) {
    float dtv = ldt[l][dl];      // broadcast across s
    float xcv = lxc[l][dl];
    float Bv  = ldbl[l][8+s];
    float Cv  = ldbl[l][24+s];
    hsv = expf(dtv*Ac)*hsv + (dtv*xcv)*Bv;
    float val = hsv*Cv;
    val += __shfl_xor(val, 1, 16);
    val += __shfl_xor(val, 2, 16);
    val += __shfl_xor(val, 4, 16);
    val += __shfl_xor(val, 8, 16);
    if (s == 0) ly[l][dl] = val + xcv*dpv;
  }
  __syncthreads();
  // gate: xz[:, :128] = y * silu(z)
  for (int i = tid; i < 2048; i += 256) {
    int l = i >> 4, dd = i & 15;
    float y = ly[l][dd];
    float z = lz[l][dd];
    xz[(size_t)(rowbase+l)*256 + d0 + dd] = y * siluf(z);
  }
}

// ---------------- column stats ----------------
__global__ __launch_bounds__(256)
void stats_kernel(const float* __restrict__ hl_in, const float* __restrict__ hr_in,
                  float* __restrict__ ws, int mode, int statsoff)
{
  int side = blockIdx.y;
  float* base = ws + (size_t)side*SS_;
  const float* h    = side ? hr_in : hl_in;
  const float* hloc = base + HL_OFF;
  const float* ha   = base + HA_OFF;
  float* x1 = base + X1_OFF;
  float* stats = base + STATS_OFF + statsoff;
  int tid = threadIdx.x;
  int c = tid & 127;
  float s1 = 0.f, s2 = 0.f;
  for (int it = 0; it < 16; ++it) {
    int r = blockIdx.x*32 + (tid >> 7) + it*2;
    size_t i = (size_t)r*128 + c;
    float v;
    if (mode == 0) { v = h[i] + hloc[i] + ha[i]; x1[i] = v; }
    else           { v = ha[i]; }
    s1 += v; s2 += v*v;
  }
  __shared__ float red[256];
  red[tid] = s1; __syncthreads();
  if (tid < 128) atomicAdd(&stats[tid], red[tid] + red[tid+128]);
  __syncthreads();
  red[tid] = s2; __syncthreads();
  if (tid < 128) atomicAdd(&stats[128+tid], red[tid] + red[tid+128]);
}

__global__ void bn_finalize_kernel(const float* __restrict__ g_, const float* __restrict__ b_,
                                   float* __restrict__ ws, int statsoff, float invM)
{
  int side = blockIdx.y;
  float* stats = ws + (size_t)side*SS_ + STATS_OFF + statsoff;
  int c = threadIdx.x;   // 128 threads
  float mean = stats[c]*invM;
  float var  = fmaxf(stats[128+c]*invM - mean*mean, 0.f);
  float scale = rsqrtf(var + 1e-5f) * g_[c];
  stats[256+c] = scale;
  stats[384+c] = b_[c] - mean*scale;
}

__global__ __launch_bounds__(256)
void bn_apply_kernel(float* __restrict__ ws, float* __restrict__ dout,
                     int srcoff, int dstoff, int statsoff, int to_dout)
{
  int side = blockIdx.y;
  float* base = ws + (size_t)side*SS_;
  const float* src = base + srcoff;
  const float* stats = base + STATS_OFF + statsoff;
  float* dst = to_dout ? (dout + (size_t)side*ND_) : (base + dstoff);
  size_t i = (size_t)blockIdx.x*256 + threadIdx.x;
  int c = (int)(i & 127);
  dst[i] = src[i]*stats[256+c] + stats[384+c];
}

// ---------------- cross attention (register-tiled); bn1 fused on residual read ------
__global__ __launch_bounds__(256)
void attn_kernel(float* __restrict__ ws)
{
  int dir = blockIdx.z;
  int g   = blockIdx.x;
  int rt  = blockIdx.y;
  float* baseq = ws + (size_t)dir*SS_;
  float* basek = ws + (size_t)(1-dir)*SS_;
  const float* qb = baseq + XC_OFF;
  const float* kb = basek + DTB_OFF;
  const float* vb = basek + YB_OFF;
  const float* x1b = baseq + X1_OFF;            // pre-bn1 x1 (hm = bn(x1))
  const float* bns = baseq + STATS_OFF + 512;   // bn1 scale/shift
  float* h2 = baseq + X1_OFF;                   // overwritten in place (same offsets)

  __shared__ float KT[128][132];   // phase A: K^T as [d][n]; phase C: V as [n][d]
  __shared__ float Qs[32][132];    // Q tile
  __shared__ float sp[32][132];    // unnormalized P tile

  const int tid = threadIdx.x;
  const int cl  = tid & 31;          // 32 col-lanes
  const int r0  = (tid >> 5) * 4;    // 8 row-groups * 4 rows = 32 rows
  const int c0  = cl * 4;            // 4 cols per thread (128 total)
  const int rowg = g*128 + rt*32;

  // ---- stage Q tile (32 x 128) ----
  {
    const float* qsrc = qb + (size_t)rowg*128;
    for (int i = tid; i < 32*32; i += 256) {
      int r = i >> 5, d4 = i & 31;
      *(float4*)&Qs[r][d4*4] = *(const float4*)&qsrc[(size_t)r*128 + d4*4];
    }
  }
  // ---- stage K^T (transpose 128x128) ----
  {
    const float* ksrc = kb + (size_t)(g*128)*128;
    for (int i = tid; i < 128*32; i += 256) {
      int d4 = i >> 7, n = i & 127;
      float4 k4 = *(const float4*)&ksrc[(size_t)n*128 + d4*4];
      KT[d4*4+0][n] = k4.x;
      KT[d4*4+1][n] = k4.y;
      KT[d4*4+2][n] = k4.z;
      KT[d4*4+3][n] = k4.w;
    }
  }
  __syncthreads();

  // ---- phase A: scores, 4 rows x 4 cols per thread ----
  float acc[4][4];
#pragma unroll
  for (int i = 0; i < 4; ++i)
#pragma unroll
    for (int j = 0; j < 4; ++j) acc[i][j] = 0.f;

  for (int d = 0; d < 128; d += 4) {
    float4 k0 = *(const float4*)&KT[d+0][c0];
    float4 k1 = *(const float4*)&KT[d+1][c0];
    float4 k2 = *(const float4*)&KT[d+2][c0];
    float4 k3 = *(const float4*)&KT[d+3][c0];
#pragma unroll
    for (int i = 0; i < 4; ++i) {
      float4 q4 = *(const float4*)&Qs[r0+i][d];
      acc[i][0] += q4.x*k0.x + q4.y*k1.x + q4.z*k2.x + q4.w*k3.x;
      acc[i][1] += q4.x*k0.y + q4.y*k1.y + q4.z*k2.y + q4.w*k3.y;
      acc[i][2] += q4.x*k0.z + q4.y*k1.z + q4.z*k2.z + q4.w*k3.z;
      acc[i][3] += q4.x*k0.w + q4.y*k1.w + q4.z*k2.w + q4.w*k3.w;
    }
  }

  // ---- softmax in registers; store unnormalized P; keep 1/sum per row ----
  float inv[4];
#pragma unroll
  for (int i = 0; i < 4; ++i) {
    float m = fmaxf(fmaxf(acc[i][0], acc[i][1]), fmaxf(acc[i][2], acc[i][3]));
#pragma unroll
    for (int off = 1; off < 32; off <<= 1) m = fmaxf(m, __shfl_xor(m, off, 32));
    float p0 = expf(acc[i][0]-m), p1 = expf(acc[i][1]-m);
    float p2 = expf(acc[i][2]-m), p3 = expf(acc[i][3]-m);
    float s = p0 + p1 + p2 + p3;
#pragma unroll
    for (int off = 1; off < 32; off <<= 1) s += __shfl_xor(s, off, 32);
    inv[i] = 1.f/s;
    *(float4*)&sp[r0+i][c0] = make_float4(p0, p1, p2, p3);
  }
  __syncthreads();

  // ---- stage V (natural [n][d], coalesced, float4 writes) ----
  {
    const float* vsrc = vb + (size_t)(g*128)*128;
    for (int i = tid; i < 128*32; i += 256) {
      int n = i >> 5, d4 = i & 31;
      *(float4*)&KT[n][d4*4] = *(const float4*)&vsrc[(size_t)n*128 + d4*4];
    }
  }
  __syncthreads();

  // ---- phase C: O = P @ V, 4 rows x 4 d-cols per thread ----
  float o[4][4];
#pragma unroll
  for (int i = 0; i < 4; ++i)
#pragma unroll
    for (int j = 0; j < 4; ++j) o[i][j] = 0.f;

  for (int n = 0; n < 128; n += 4) {
    float4 v0 = *(const float4*)&KT[n+0][c0];
    float4 v1 = *(const float4*)&KT[n+1][c0];
    float4 v2 = *(const float4*)&KT[n+2][c0];
    float4 v3 = *(const float4*)&KT[n+3][c0];
#pragma unroll
    for (int i = 0; i < 4; ++i) {
      float4 p4 = *(const float4*)&sp[r0+i][n];
      o[i][0] += p4.x*v0.x + p4.y*v1.x + p4.z*v2.x + p4.w*v3.x;
      o[i][1] += p4.x*v0.y + p4.y*v1.y + p4.z*v2.y + p4.w*v3.y;
      o[i][2] += p4.x*v0.z + p4.y*v1.z + p4.z*v2.z + p4.w*v3.z;
      o[i][3] += p4.x*v0.w + p4.y*v1.w + p4.z*v2.w + p4.w*v3.w;
    }
  }

  // ---- epilogue: h2 = bn1(x1) + O/sum (bn fused; read-before-write, same offsets) ----
  float4 sc = *(const float4*)&bns[256 + c0];
  float4 sh = *(const float4*)&bns[384 + c0];
#pragma unroll
  for (int i = 0; i < 4; ++i) {
    size_t off = (size_t)(rowg + r0 + i)*128 + c0;
    float4 xv = *(const float4*)&x1b[off];
    float4 r4;
    r4.x = xv.x*sc.x + sh.x + o[i][0]*inv[i];
    r4.y = xv.y*sc.y + sh.y + o[i][1]*inv[i];
    r4.z = xv.z*sc.z + sh.z + o[i][2]*inv[i];
    r4.w = xv.w*sc.w + sh.w + o[i][3]*inv[i];
    *(float4*)&h2[off] = r4;
  }
}

// ---------------- launch ----------------
extern "C" void kernel_launch(void* const* d_in, const int* in_sizes, int n_in,
                              void* d_out, int out_size, void* d_ws, size_t ws_size,
                              hipStream_t stream)
{
  const float* h_lig     = (const float*)d_in[0];
  const float* h_rec     = (const float*)d_in[1];
  const float* x_lig     = (const float*)d_in[2];
  const float* x_rec     = (const float*)d_in[3];
  const float* he_1      = (const float*)d_in[4];
  const float* he_2      = (const float*)d_in[5];
  const float* emlp_w1   = (const float*)d_in[6];
  const float* emlp_b1   = (const float*)d_in[7];
  const float* emlp_bn_g = (const float*)d_in[8];
  const float* emlp_bn_b = (const float*)d_in[9];
  const float* emlp_w2   = (const float*)d_in[10];
  const float* emlp_b2   = (const float*)d_in[11];
  const float* bern_temp = (const float*)d_in[12];
  const float* m_in_w    = (const float*)d_in[13];
  const float* m_conv_w  = (const float*)d_in[14];
  const float* m_conv_b  = (const float*)d_in[15];
  const float* m_xproj_w = (const float*)d_in[16];
  const float* m_dt_w    = (const float*)d_in[17];
  const float* m_dt_b    = (const float*)d_in[18];
  const float* m_A_log   = (const float*)d_in[19];
  const float* m_D       = (const float*)d_in[20];
  const float* m_out_w   = (const float*)d_in[21];
  const float* q_w       = (const float*)d_in[22];
  const float* k_w       = (const float*)d_in[23];
  const float* v_w       = (const float*)d_in[24];
  const float* bn1_g     = (const float*)d_in[25];
  const float* bn1_b     = (const float*)d_in[26];
  const float* bn2_g     = (const float*)d_in[27];
  const float* bn2_b     = (const float*)d_in[28];
  const float* ff_w1     = (const float*)d_in[29];
  const float* ff_b1     = (const float*)d_in[30];
  const float* ff_w2     = (const float*)d_in[31];
  const float* ff_b2     = (const float*)d_in[32];
  const int*   ei1       = (const int*)d_in[33];
  const int*   ei2       = (const int*)d_in[34];
  const int*   perm1     = (const int*)d_in[37];
  const int*   perm2     = (const int*)d_in[38];

  float* ws   = (float*)d_ws;
  float* dout = (float*)d_out;

#define B0(off) (ws + (size_t)(off))
#define B1(off) (ws + SS_ + (size_t)(off))

  for (int s = 0; s < 2; ++s)
    hipMemsetAsync((char*)d_ws + ((size_t)s*SS_ + DEG_OFF)*sizeof(float), 0,
                   (N_ + 2048)*sizeof(float), stream);

  // edge weights: pass1 computes t (fp16 scratch via LDS-tile flush) + stats;
  // pass2 is a cheap weighted sum over the stored t.
  edge_stats_kernel<<<dim3(256,2), 256, 0, stream>>>(x_lig,x_rec,he_1,he_2,ei1,ei2,emlp_w1,emlp_b1,ws);
  edge_finalize_kernel<<<dim3(1,2), 128, 0, stream>>>(emlp_bn_g,emlp_bn_b,emlp_w2,emlp_b2,ws);
  edge_w_kernel<<<dim3(256,2), 256, 0, stream>>>(ei1,ei2,ws);

  // bernstein propagation (Horner, 6 matmuls)
  bern_horner_kernel<<<dim3(G_*4,2), 256, 0, stream>>>(h_lig,h_rec,ei1,ei2,bern_temp,ws);

  // mamba
  gemm_kernel<128,256,64,4,0,1,0,0,0><<<dim3(512,2),256,0,stream>>>(
      h_lig,h_rec,128, m_in_w,nullptr, B0(XZ_OFF),B1(XZ_OFF),256, perm1,perm2, nullptr,nullptr);
  conv_kernel<<<dim3(2048,2), 256, 0, stream>>>(m_conv_w,m_conv_b,ws);
  gemm_kernel<128,40,64,1,0,0,0,0,0><<<dim3(128,2),256,0,stream>>>(
      B0(XC_OFF),B1(XC_OFF),128, m_xproj_w,nullptr, B0(DBL_OFF),B1(DBL_OFF),40, nullptr,nullptr, nullptr,nullptr);
  scan_kernel<<<dim3(32,8,2), 256, 0, stream>>>(m_A_log,m_D,m_dt_w,m_dt_b,ws);
  gemm_kernel<128,128,64,2,0,0,1,0,0><<<dim3(256,2),256,0,stream>>>(
      B0(XZ_OFF),B1(XZ_OFF),256, m_out_w,nullptr, B0(HA_OFF),B1(HA_OFF),128, perm1,perm2, nullptr,nullptr);

  // bn1 stats ( h + h_local + ha ); bn1 APPLY is fused into qkv + attn
  stats_kernel<<<dim3(128,2), 256, 0, stream>>>(h_lig,h_rec,ws,0,512);
  bn_finalize_kernel<<<dim3(1,2), 128, 0, stream>>>(bn1_g,bn1_b,ws,512,1.f/(float)N_);

  // q,k,v projections (bn1 fused in A-staging)
  qkv_kernel<<<dim3(256,2,3), 256, 0, stream>>>(q_w,k_w,v_w,ws);
  attn_kernel<<<dim3(32,4,2), 256, 0, stream>>>(ws);

  // ffn + bn2
  gemm_kernel<128,256,64,4,2,0,0,0,1><<<dim3(512,2),256,0,stream>>>(
      B0(X1_OFF),B1(X1_OFF),128, ff_w1,ff_b1, B0(XZ_OFF),B1(XZ_OFF),256, nullptr,nullptr, nullptr,nullptr);
  gemm_kernel<256,128,32,4,0,0,0,1,1><<<dim3(512,2),256,0,stream>>>(
      B0(XZ_OFF),B1(XZ_OFF),256, ff_w2,ff_b2, B0(HA_OFF),B1(HA_OFF),128, nullptr,nullptr, B0(X1_OFF),B1(X1_OFF));
  stats_kernel<<<dim3(128,2), 256, 0, stream>>>(h_lig,h_rec,ws,1,1024);
  bn_finalize_kernel<<<dim3(1,2), 128, 0, stream>>>(bn2_g,bn2_b,ws,1024,1.f/(float)N_);
  bn_apply_kernel<<<dim3(2048,2), 256, 0, stream>>>(ws,dout,HA_OFF,0,1024,1);
}

// Round 13
// 454.255 us; speedup vs baseline: 1.2600x; 1.2600x over previous
//
#include <hip/hip_runtime.h>
#include <math.h>

// ---------------- problem constants ----------------
#define G_    32
#define NPG_  128
#define D_    128
#define N_    4096          // G_*NPG_
#define E_    65536
#define ND_   (N_*D_)       // 524288

// ---------------- workspace layout (float offsets, per side) ----------------
#define W_OFF     0                     // E_ edge weights w
#define DEG_OFF   65536                 // N_ degrees (atomic, zeroed)
#define STATS_OFF 69632                 // 2048 floats of stats (zeroed):
//   [0:128) edge colsum  [128:256) edge colsumsq [256:384) alpha [384] beta
//   [512..1024) bn1: sum/ssq/scale/shift   [1024..1536) bn2: same
#define BUF0      71680
#define HL_OFF    (BUF0 + 0*ND_)        // h_local (bern output)
#define HA_OFF    (BUF0 + 1*ND_)        // mamba out (scattered); later x2
#define X1_OFF    (BUF0 + 2*ND_)        // pre-bn1 sum; later h2 (post-attn)
#define HMID_OFF  (BUF0 + 3*ND_)        // (unused since bn1 is fused into qkv/attn)
#define XC_OFF    (BUF0 + 4*ND_)        // conv output; later q
#define DTB_OFF   (BUF0 + 5*ND_)        // k
#define YB_OFF    (BUF0 + 6*ND_)        // v
#define XZ_OFF    (BUF0 + 7*ND_)        // 2*ND_: [xq|z] per row (256); scan gate overwrites xq
#define DBL_OFF   (BUF0 + 9*ND_)        // N_*40
#define WT_OFF    (DBL_OFF + N_*40)     // (unused scratch, kept for layout stability)
#define SS_       ((size_t)(WT_OFF + 4096))

__device__ __forceinline__ float leakyf(float x){ return x >= 0.f ? x : 0.02f*x; }
__device__ __forceinline__ float siluf (float x){ return x / (1.f + expf(-x)); }

// ---------------- edge feature helper ----------------
__device__ __forceinline__ void edge_feat(const float* __restrict__ x,
                                          const float* __restrict__ he,
                                          const int* __restrict__ ei,
                                          int e, float* feat, int& sN, int& dN)
{
  sN = ei[e]; dN = ei[E_ + e];
  float dx = x[sN*3+0]-x[dN*3+0];
  float dy = x[sN*3+1]-x[dN*3+1];
  float dz = x[sN*3+2]-x[dN*3+2];
  float d2 = dx*dx + dy*dy + dz*dz;
  feat[0] = expf(-d2);
  feat[1] = expf(d2 * -0.1f);
  feat[2] = expf(d2 * -0.01f);
  feat[3] = expf(d2 * -0.001f);
  feat[4] = expf(d2 * -0.0001f);
#pragma unroll
  for (int j = 0; j < 27; ++j) feat[5+j] = he[(size_t)e*27 + j];
}

// ---------------- E1 (champion, ~48us): per-column stats ----------------
__global__ __launch_bounds__(256)
void edge_stats_kernel(const float* __restrict__ xl, const float* __restrict__ xr,
                       const float* __restrict__ hel, const float* __restrict__ her,
                       const int* __restrict__ ei1, const int* __restrict__ ei2,
                       const float* __restrict__ w1, const float* __restrict__ b1,
                       float* __restrict__ ws)
{
  int side = blockIdx.y;
  const float* x  = side ? xr  : xl;
  const float* he = side ? her : hel;
  const int*   ei = side ? ei2 : ei1;
  float* stats = ws + (size_t)side*SS_ + STATS_OFF;
  __shared__ float featl[256*36];
  __shared__ float csum[2][128], cssq[2][128];
  int tid = threadIdx.x;
  {
    int sN, dN; float feat[32];
    edge_feat(x, he, ei, blockIdx.x*256 + tid, feat, sN, dN);
#pragma unroll
    for (int j4 = 0; j4 < 8; ++j4)
      *(float4*)&featl[tid*36 + j4*4] = *(float4*)&feat[j4*4];
  }
  int c = tid & 127, hh = tid >> 7;
  float w1c[32];
#pragma unroll
  for (int j = 0; j < 32; ++j) w1c[j] = w1[j*128 + c];
  float b1c = b1[c];
  __syncthreads();
  float s1 = 0.f, s2 = 0.f;
  for (int e = 0; e < 128; ++e) {
    const float* f = &featl[(hh*128 + e)*36];
    float acc = b1c;
#pragma unroll
    for (int j4 = 0; j4 < 8; ++j4) {
      float4 f4 = *(const float4*)&f[j4*4];
      acc += f4.x*w1c[j4*4] + f4.y*w1c[j4*4+1] + f4.z*w1c[j4*4+2] + f4.w*w1c[j4*4+3];
    }
    float t = leakyf(acc);
    s1 += t; s2 += t*t;
  }
  csum[hh][c] = s1; cssq[hh][c] = s2;
  __syncthreads();
  if (tid < 128) {
    atomicAdd(&stats[tid],     csum[0][tid] + csum[1][tid]);
    atomicAdd(&stats[128+tid], cssq[0][tid] + cssq[1][tid]);
  }
}

// ---------------- E2: finalize edge bn folded with emlp_w2 -> alpha,beta ----------------
__global__ void edge_finalize_kernel(const float* __restrict__ g_, const float* __restrict__ b_,
                                     const float* __restrict__ w2, const float* __restrict__ b2,
                                     float* __restrict__ ws)
{
  int side = blockIdx.y;
  float* stats = ws + (size_t)side*SS_ + STATS_OFF;
  __shared__ float red[128];
  int c = threadIdx.x;  // 128 threads
  const float invE = 1.f/(float)E_;
  float mean = stats[c]*invE;
  float var  = fmaxf(stats[128+c]*invE - mean*mean, 0.f);
  float scale = rsqrtf(var + 1e-5f) * g_[c];
  stats[256+c] = scale * w2[c];
  red[c] = (b_[c] - mean*scale) * w2[c];
  __syncthreads();
  for (int off = 64; off; off >>= 1) { if (c < off) red[c] += red[c+off]; __syncthreads(); }
  if (c == 0) stats[384] = red[0] + b2[0];
}

// ---------------- E3 (champion, ~47.6us): w_e ----------------
__global__ __launch_bounds__(256)
void edge_w_kernel(const float* __restrict__ xl, const float* __restrict__ xr,
                   const float* __restrict__ hel, const float* __restrict__ her,
                   const int* __restrict__ ei1, const int* __restrict__ ei2,
                   const float* __restrict__ w1, const float* __restrict__ b1,
                   float* __restrict__ ws)
{
  int side = blockIdx.y;
  const float* x  = side ? xr  : xl;
  const float* he = side ? her : hel;
  const int*   ei = side ? ei2 : ei1;
  float* base = ws + (size_t)side*SS_;
  const float* stats = base + STATS_OFF;
  float* wbuf = base + W_OFF;
  float* deg  = base + DEG_OFF;
  __shared__ float w1t[128*32];
  __shared__ float b1l[128], all_[128];
  int tid = threadIdx.x;
  for (int i = tid; i < 4096; i += 256) {
    int j = i & 31, c = i >> 5;
    w1t[c*32 + j] = w1[j*128 + c];
  }
  if (tid < 128) { b1l[tid] = b1[tid]; all_[tid] = stats[256+tid]; }
  __syncthreads();
  int e = blockIdx.x*256 + tid;
  int sN, dN; float feat[32];
  edge_feat(x, he, ei, e, feat, sN, dN);
  float accw = stats[384];
  for (int c = 0; c < 128; ++c) {
    float acc = b1l[c];
#pragma unroll
    for (int j4 = 0; j4 < 8; ++j4) {
      float4 w4 = *(const float4*)&w1t[c*32 + j4*4];
      acc += feat[j4*4]*w4.x + feat[j4*4+1]*w4.y + feat[j4*4+2]*w4.z + feat[j4*4+3]*w4.w;
    }
    accw += leakyf(acc)*all_[c];
  }
  float w = fmaxf(accw, 0.f);
  wbuf[e] = w;
  atomicAdd(&deg[sN], w);
}

// ---------------- Bernstein propagation via Horner (6 matmuls) ----------------
__global__ __launch_bounds__(256)
void bern_horner_kernel(const float* __restrict__ hl_in, const float* __restrict__ hr_in,
                        const int* __restrict__ ei1, const int* __restrict__ ei2,
                        const float* __restrict__ bern_temp, float* __restrict__ ws)
{
  int side = blockIdx.y;
  int g  = blockIdx.x >> 2;
  int d0 = (blockIdx.x & 3) * 32;
  const float* h  = side ? hr_in : hl_in;
  const int*   ei = side ? ei2 : ei1;
  float* base = ws + (size_t)side*SS_;
  const float* wbuf = base + W_OFF;
  const float* deg  = base + DEG_OFF;
  float* hloc = base + HL_OFF;

  __shared__ float A[128*132];
  __shared__ float v[128*32];
  int tid = threadIdx.x;
  for (int i = tid; i < 128*132; i += 256) A[i] = 0.f;

  const float btab[7][7] = {
    { 1,  6, 15,  20, 15,  6,  1},
    { 1,  4,  5,   0, -5, -4, -1},
    { 1,  2, -1,  -4, -1,  2,  1},
    { 1,  0, -3,   0,  3,  0, -1},
    { 1, -2, -1,   4, -1, -2,  1},
    { 1, -4,  5,   0, -5,  4, -1},
    { 1, -6, 15, -20, 15, -6,  1}};
  const float comb6[7] = {1,6,15,20,15,6,1};
  float a[7];
#pragma unroll
  for (int m = 0; m < 7; ++m) a[m] = 0.f;
#pragma unroll
  for (int j = 0; j < 7; ++j) {
    float tj = fmaxf(bern_temp[j], 0.f) * comb6[j] * (1.f/64.f);
#pragma unroll
    for (int m = 0; m < 7; ++m) a[m] += tj * btab[j][m];
  }
  __syncthreads();

  int ebase = g*2048, nbase = g*128;
  for (int i = tid; i < 2048; i += 256) {
    int e = ebase + i;
    int sN = ei[e], dN = ei[E_ + e];
    float ds_ = deg[sN], dd_ = deg[dN];
    float aa = ds_ > 0.f ? rsqrtf(ds_ + 1e-12f) : 0.f;
    float bb = dd_ > 0.f ? rsqrtf(dd_ + 1e-12f) : 0.f;
    atomicAdd(&A[(dN - nbase)*132 + (sN - nbase)], wbuf[e]*aa*bb);
  }

  const int db = (tid & 7)*4;
  const int rb = (tid >> 3)*4;
  float hreg[4][4], r[4][4], t[4][4];
#pragma unroll
  for (int i = 0; i < 4; ++i) {
    float4 h4 = *(const float4*)&h[(size_t)(nbase + rb + i)*128 + d0 + db];
    hreg[i][0]=h4.x; hreg[i][1]=h4.y; hreg[i][2]=h4.z; hreg[i][3]=h4.w;
#pragma unroll
    for (int jj = 0; jj < 4; ++jj) r[i][jj] = a[6]*hreg[i][jj];
  }

  for (int step = 5; step >= 0; --step) {
    __syncthreads();
#pragma unroll
    for (int i = 0; i < 4; ++i)
      *(float4*)&v[(rb+i)*32 + db] = make_float4(r[i][0], r[i][1], r[i][2], r[i][3]);
    __syncthreads();
#pragma unroll
    for (int i = 0; i < 4; ++i)
#pragma unroll
      for (int jj = 0; jj < 4; ++jj) t[i][jj] = 0.f;
    for (int k = 0; k < 128; k += 4) {
      float4 V0 = *(const float4*)&v[(k+0)*32 + db];
      float4 V1 = *(const float4*)&v[(k+1)*32 + db];
      float4 V2 = *(const float4*)&v[(k+2)*32 + db];
      float4 V3 = *(const float4*)&v[(k+3)*32 + db];
#pragma unroll
      for (int i = 0; i < 4; ++i) {
        float4 A4 = *(const float4*)&A[(rb+i)*132 + k];
        t[i][0] += A4.x*V0.x + A4.y*V1.x + A4.z*V2.x + A4.w*V3.x;
        t[i][1] += A4.x*V0.y + A4.y*V1.y + A4.z*V2.y + A4.w*V3.y;
        t[i][2] += A4.x*V0.z + A4.y*V1.z + A4.z*V2.z + A4.w*V3.z;
        t[i][3] += A4.x*V0.w + A4.y*V1.w + A4.z*V2.w + A4.w*V3.w;
      }
    }
    float ak = a[step];
#pragma unroll
    for (int i = 0; i < 4; ++i)
#pragma unroll
      for (int jj = 0; jj < 4; ++jj) r[i][jj] = t[i][jj] + ak*hreg[i][jj];
  }

#pragma unroll
  for (int i = 0; i < 4; ++i)
    *(float4*)&hloc[(size_t)(nbase + rb + i)*128 + d0 + db] =
        make_float4(r[i][0], r[i][1], r[i][2], r[i][3]);
}

// ---------------- generic f32 GEMM, col-split for occupancy, grid.y = side ----------------
template<int K, int NC, int TC, int CSPLIT, int ACT, int GATHER, int SCATTER, int ADDC, int BIAS>
__global__ __launch_bounds__(256)
void gemm_kernel(const float* __restrict__ A0, const float* __restrict__ A1, int lda,
                 const float* __restrict__ W, const float* __restrict__ bias,
                 float* __restrict__ C0, float* __restrict__ C1, int ldc,
                 const int* __restrict__ idx0, const int* __restrict__ idx1,
                 const float* __restrict__ add0, const float* __restrict__ add1)
{
  int side = blockIdx.y;
  const float* A = side ? A1 : A0;
  float* C = side ? C1 : C0;
  const int* idx = side ? idx1 : idx0;
  const float* addsrc = side ? add1 : add0;
  constexpr int RPT = TC/8;
  constexpr int CLEN = NC/CSPLIT;
  __shared__ float Alds[32][K];
  __shared__ float Wlds[K][TC];
  const int tid = threadIdx.x;
  const int r0 = (blockIdx.x / CSPLIT) * 32;
  const int cbase = (blockIdx.x % CSPLIT) * CLEN;
  for (int i = tid*4; i < 32*K; i += 1024) {
    int r = i / K, k = i % K;
    int row = GATHER ? idx[r0 + r] : (r0 + r);
    *(float4*)&Alds[r][k] = *(const float4*)&A[(size_t)row*lda + k];
  }
  for (int c0 = cbase; c0 < cbase + CLEN; c0 += TC) {
    __syncthreads();
    for (int i = tid*4; i < K*TC; i += 1024) {
      int k = i / TC, c = i % TC;
      if (c0 + c < NC) *(float4*)&Wlds[k][c] = *(const float4*)&W[k*NC + c0 + c];
      else             *(float4*)&Wlds[k][c] = make_float4(0.f,0.f,0.f,0.f);
    }
    __syncthreads();
    const int cl = tid % TC;
    const int rsub = (tid / TC) * RPT;
    float accv[RPT];
#pragma unroll
    for (int j = 0; j < RPT; ++j) accv[j] = 0.f;
    for (int k = 0; k < K; k += 4) {
      float w0 = Wlds[k][cl], w1v = Wlds[k+1][cl], w2v = Wlds[k+2][cl], w3v = Wlds[k+3][cl];
#pragma unroll
      for (int j = 0; j < RPT; ++j) {
        float4 a4 = *(const float4*)&Alds[rsub+j][k];
        accv[j] += a4.x*w0 + a4.y*w1v + a4.z*w2v + a4.w*w3v;
      }
    }
    int c = c0 + cl;
    if (c < NC) {
#pragma unroll
      for (int j = 0; j < RPT; ++j) {
        int row  = r0 + rsub + j;
        int orow = SCATTER ? idx[row] : row;
        float vv = accv[j];
        if (BIAS)     vv += bias[c];
        if (ACT == 1) vv = leakyf(vv);
        if (ACT == 2) vv = fmaxf(vv, 0.f);
        if (ADDC)     vv += addsrc[(size_t)orow*ldc + c];
        C[(size_t)orow*ldc + c] = vv;
      }
    }
  }
}

// ---------------- qkv: 3 projections in one dispatch; bn1 fused into A-staging ----------
__global__ __launch_bounds__(256)
void qkv_kernel(const float* __restrict__ qw, const float* __restrict__ kw,
                const float* __restrict__ vw, float* __restrict__ ws)
{
  int side = blockIdx.y;
  int mat  = blockIdx.z;
  float* base = ws + (size_t)side*SS_;
  const float* A = base + X1_OFF;                 // pre-bn1 x1
  const float* bns = base + STATS_OFF + 512;      // bn1: scale at +256, shift at +384
  const float* W = mat == 0 ? qw : (mat == 1 ? kw : vw);
  float* C = base + (mat == 0 ? XC_OFF : (mat == 1 ? DTB_OFF : YB_OFF));
  __shared__ float Alds[32][128];
  __shared__ float Wlds[128][64];
  const int tid = threadIdx.x;
  const int r0 = (blockIdx.x >> 1) * 32;
  const int c0 = (blockIdx.x & 1) * 64;
  for (int i = tid*4; i < 32*128; i += 1024) {
    int k = i & 127;
    float4 a4 = *(const float4*)&A[(size_t)(r0 + (i>>7))*128 + k];
    float4 sc = *(const float4*)&bns[256 + k];
    float4 sh = *(const float4*)&bns[384 + k];
    a4.x = a4.x*sc.x + sh.x;
    a4.y = a4.y*sc.y + sh.y;
    a4.z = a4.z*sc.z + sh.z;
    a4.w = a4.w*sc.w + sh.w;
    *(float4*)&Alds[i>>7][k] = a4;
  }
  for (int i = tid*4; i < 128*64; i += 1024)
    *(float4*)&Wlds[i>>6][i&63] = *(const float4*)&W[(i>>6)*128 + c0 + (i&63)];
  __syncthreads();
  const int cl = tid & 63;
  const int rsub = (tid >> 6) * 8;
  float accv[8];
#pragma unroll
  for (int j = 0; j < 8; ++j) accv[j] = 0.f;
  for (int k = 0; k < 128; k += 4) {
    float w0 = Wlds[k][cl], w1v = Wlds[k+1][cl], w2v = Wlds[k+2][cl], w3v = Wlds[k+3][cl];
#pragma unroll
    for (int j = 0; j < 8; ++j) {
      float4 a4 = *(const float4*)&Alds[rsub+j][k];
      accv[j] += a4.x*w0 + a4.y*w1v + a4.z*w2v + a4.w*w3v;
    }
  }
#pragma unroll
  for (int j = 0; j < 8; ++j) {
    float vv = accv[j];
    if (mat < 2) vv = leakyf(vv);
    C[(size_t)(r0 + rsub + j)*128 + c0 + cl] = vv;
  }
}

// ---------------- mamba: causal depthwise conv (DCONV=4) + silu ----------------
__global__ __launch_bounds__(256)
void conv_kernel(const float* __restrict__ cw, const float* __restrict__ cb, float* __restrict__ ws)
{
  int side = blockIdx.y;
  float* base = ws + (size_t)side*SS_;
  const float* xz = base + XZ_OFF;
  float* xc = base + XC_OFF;
  int i = blockIdx.x*256 + threadIdx.x;
  int j = i >> 7, d = i & 127;
  int l = j & 127;
  float a = cb[d];
#pragma unroll
  for (int k = 0; k < 4; ++k) {
    int ll = l - 3 + k;
    if (ll >= 0) a += xz[(size_t)(j-3+k)*256 + d] * cw[d*4 + k];
  }
  xc[i] = siluf(a);
}

// ---------------- mamba scan: fused dt(softplus) + 128-step recurrence + gate ----------------
__global__ __launch_bounds__(256)
void scan_kernel(const float* __restrict__ A_log, const float* __restrict__ Dp,
                 const float* __restrict__ dtw, const float* __restrict__ dtbias,
                 float* __restrict__ ws)
{
  int side = blockIdx.z;
  int g  = blockIdx.x;
  int d0 = blockIdx.y * 16;
  float* base = ws + (size_t)side*SS_;
  const float* dbl = base + DBL_OFF;
  const float* xcb = base + XC_OFF;
  float* xz = base + XZ_OFF;

  __shared__ float ldbl[128][40];   // dt-in(8) | B(16) | C(16)
  __shared__ float lxc[128][16];
  __shared__ float ldt[128][16];
  __shared__ float lz[128][16];
  __shared__ float ly[128][16];
  __shared__ float ltw[8][16];
  __shared__ float ltb[16];

  int tid = threadIdx.x;
  int rowbase = g*128;
  if (tid < 128)      ltw[tid>>4][tid&15] = dtw[(tid>>4)*128 + d0 + (tid&15)];
  else if (tid < 144) ltb[tid-128] = dtbias[d0 + (tid-128)];
  for (int i = tid; i < 128*40; i += 256)
    ((float*)ldbl)[i] = dbl[(size_t)rowbase*40 + i];
  for (int i = tid; i < 2048; i += 256) {
    int l = i >> 4, dd = i & 15;
    lxc[l][dd] = xcb[(size_t)(rowbase+l)*128 + d0 + dd];
    lz[l][dd]  = xz[(size_t)(rowbase+l)*256 + 128 + d0 + dd];
  }
  __syncthreads();
  // dt = softplus(dbl[:, :8] @ dtw + dtb)  — once per (l,d)
  for (int i = tid; i < 2048; i += 256) {
    int l = i >> 4, dd = i & 15;
    float a = ltb[dd];
#pragma unroll
    for (int k = 0; k < 8; ++k) a += ldbl[l][k]*ltw[k][dd];
    ldt[l][dd] = a > 20.f ? a : log1pf(expf(a));
  }
  __syncthreads();

  int s = tid & 15, dl = (tid >> 4) & 15;
  float Ac  = -expf(A_log[(d0+dl)*16 + s]);
  float dpv = Dp[d0+dl];
  float hsv = 0.f;
  for (int l = 0; l < 128; ++l) {
    float dtv = ldt[l][dl];      // broadcast across s
    float xcv = lxc[l][dl];
    float Bv  = ldbl[l][8+s];
    float Cv  = ldbl[l][24+s];
    hsv = expf(dtv*Ac)*hsv + (dtv*xcv)*Bv;
    float val = hsv*Cv;
    val += __shfl_xor(val, 1, 16);
    val += __shfl_xor(val, 2, 16);
    val += __shfl_xor(val, 4, 16);
    val += __shfl_xor(val, 8, 16);
    if (s == 0) ly[l][dl] = val + xcv*dpv;
  }
  __syncthreads();
  // gate: xz[:, :128] = y * silu(z)
  for (int i = tid; i < 2048; i += 256) {
    int l = i >> 4, dd = i & 15;
    float y = ly[l][dd];
    float z = lz[l][dd];
    xz[(size_t)(rowbase+l)*256 + d0 + dd] = y * siluf(z);
  }
}

// ---------------- column stats ----------------
__global__ __launch_bounds__(256)
void stats_kernel(const float* __restrict__ hl_in, const float* __restrict__ hr_in,
                  float* __restrict__ ws, int mode, int statsoff)
{
  int side = blockIdx.y;
  float* base = ws + (size_t)side*SS_;
  const float* h    = side ? hr_in : hl_in;
  const float* hloc = base + HL_OFF;
  const float* ha   = base + HA_OFF;
  float* x1 = base + X1_OFF;
  float* stats = base + STATS_OFF + statsoff;
  int tid = threadIdx.x;
  int c = tid & 127;
  float s1 = 0.f, s2 = 0.f;
  for (int it = 0; it < 16; ++it) {
    int r = blockIdx.x*32 + (tid >> 7) + it*2;
    size_t i = (size_t)r*128 + c;
    float v;
    if (mode == 0) { v = h[i] + hloc[i] + ha[i]; x1[i] = v; }
    else           { v = ha[i]; }
    s1 += v; s2 += v*v;
  }
  __shared__ float red[256];
  red[tid] = s1; __syncthreads();
  if (tid < 128) atomicAdd(&stats[tid], red[tid] + red[tid+128]);
  __syncthreads();
  red[tid] = s2; __syncthreads();
  if (tid < 128) atomicAdd(&stats[128+tid], red[tid] + red[tid+128]);
}

__global__ void bn_finalize_kernel(const float* __restrict__ g_, const float* __restrict__ b_,
                                   float* __restrict__ ws, int statsoff, float invM)
{
  int side = blockIdx.y;
  float* stats = ws + (size_t)side*SS_ + STATS_OFF + statsoff;
  int c = threadIdx.x;   // 128 threads
  float mean = stats[c]*invM;
  float var  = fmaxf(stats[128+c]*invM - mean*mean, 0.f);
  float scale = rsqrtf(var + 1e-5f) * g_[c];
  stats[256+c] = scale;
  stats[384+c] = b_[c] - mean*scale;
}

__global__ __launch_bounds__(256)
void bn_apply_kernel(float* __restrict__ ws, float* __restrict__ dout,
                     int srcoff, int dstoff, int statsoff, int to_dout)
{
  int side = blockIdx.y;
  float* base = ws + (size_t)side*SS_;
  const float* src = base + srcoff;
  const float* stats = base + STATS_OFF + statsoff;
  float* dst = to_dout ? (dout + (size_t)side*ND_) : (base + dstoff);
  size_t i = (size_t)blockIdx.x*256 + threadIdx.x;
  int c = (int)(i & 127);
  dst[i] = src[i]*stats[256+c] + stats[384+c];
}

// ---------------- cross attention (register-tiled); bn1 fused on residual read ------
__global__ __launch_bounds__(256)
void attn_kernel(float* __restrict__ ws)
{
  int dir = blockIdx.z;
  int g   = blockIdx.x;
  int rt  = blockIdx.y;
  float* baseq = ws + (size_t)dir*SS_;
  float* basek = ws + (size_t)(1-dir)*SS_;
  const float* qb = baseq + XC_OFF;
  const float* kb = basek + DTB_OFF;
  const float* vb = basek + YB_OFF;
  const float* x1b = baseq + X1_OFF;            // pre-bn1 x1 (hm = bn(x1))
  const float* bns = baseq + STATS_OFF + 512;   // bn1 scale/shift
  float* h2 = baseq + X1_OFF;                   // overwritten in place (same offsets)

  __shared__ float KT[128][132];   // phase A: K^T as [d][n]; phase C: V as [n][d]
  __shared__ float Qs[32][132];    // Q tile
  __shared__ float sp[32][132];    // unnormalized P tile

  const int tid = threadIdx.x;
  const int cl  = tid & 31;          // 32 col-lanes
  const int r0  = (tid >> 5) * 4;    // 8 row-groups * 4 rows = 32 rows
  const int c0  = cl * 4;            // 4 cols per thread (128 total)
  const int rowg = g*128 + rt*32;

  // ---- stage Q tile (32 x 128) ----
  {
    const float* qsrc = qb + (size_t)rowg*128;
    for (int i = tid; i < 32*32; i += 256) {
      int r = i >> 5, d4 = i & 31;
      *(float4*)&Qs[r][d4*4] = *(const float4*)&qsrc[(size_t)r*128 + d4*4];
    }
  }
  // ---- stage K^T (transpose 128x128) ----
  {
    const float* ksrc = kb + (size_t)(g*128)*128;
    for (int i = tid; i < 128*32; i += 256) {
      int d4 = i >> 7, n = i & 127;
      float4 k4 = *(const float4*)&ksrc[(size_t)n*128 + d4*4];
      KT[d4*4+0][n] = k4.x;
      KT[d4*4+1][n] = k4.y;
      KT[d4*4+2][n] = k4.z;
      KT[d4*4+3][n] = k4.w;
    }
  }
  __syncthreads();

  // ---- phase A: scores, 4 rows x 4 cols per thread ----
  float acc[4][4];
#pragma unroll
  for (int i = 0; i < 4; ++i)
#pragma unroll
    for (int j = 0; j < 4; ++j) acc[i][j] = 0.f;

  for (int d = 0; d < 128; d += 4) {
    float4 k0 = *(const float4*)&KT[d+0][c0];
    float4 k1 = *(const float4*)&KT[d+1][c0];
    float4 k2 = *(const float4*)&KT[d+2][c0];
    float4 k3 = *(const float4*)&KT[d+3][c0];
#pragma unroll
    for (int i = 0; i < 4; ++i) {
      float4 q4 = *(const float4*)&Qs[r0+i][d];
      acc[i][0] += q4.x*k0.x + q4.y*k1.x + q4.z*k2.x + q4.w*k3.x;
      acc[i][1] += q4.x*k0.y + q4.y*k1.y + q4.z*k2.y + q4.w*k3.y;
      acc[i][2] += q4.x*k0.z + q4.y*k1.z + q4.z*k2.z + q4.w*k3.z;
      acc[i][3] += q4.x*k0.w + q4.y*k1.w + q4.z*k2.w + q4.w*k3.w;
    }
  }

  // ---- softmax in registers; store unnormalized P; keep 1/sum per row ----
  float inv[4];
#pragma unroll
  for (int i = 0; i < 4; ++i) {
    float m = fmaxf(fmaxf(acc[i][0], acc[i][1]), fmaxf(acc[i][2], acc[i][3]));
#pragma unroll
    for (int off = 1; off < 32; off <<= 1) m = fmaxf(m, __shfl_xor(m, off, 32));
    float p0 = expf(acc[i][0]-m), p1 = expf(acc[i][1]-m);
    float p2 = expf(acc[i][2]-m), p3 = expf(acc[i][3]-m);
    float s = p0 + p1 + p2 + p3;
#pragma unroll
    for (int off = 1; off < 32; off <<= 1) s += __shfl_xor(s, off, 32);
    inv[i] = 1.f/s;
    *(float4*)&sp[r0+i][c0] = make_float4(p0, p1, p2, p3);
  }
  __syncthreads();

  // ---- stage V (natural [n][d], coalesced, float4 writes) ----
  {
    const float* vsrc = vb + (size_t)(g*128)*128;
    for (int i = tid; i < 128*32; i += 256) {
      int n = i >> 5, d4 = i & 31;
      *(float4*)&KT[n][d4*4] = *(const float4*)&vsrc[(size_t)n*128 + d4*4];
    }
  }
  __syncthreads();

  // ---- phase C: O = P @ V, 4 rows x 4 d-cols per thread ----
  float o[4][4];
#pragma unroll
  for (int i = 0; i < 4; ++i)
#pragma unroll
    for (int j = 0; j < 4; ++j) o[i][j] = 0.f;

  for (int n = 0; n < 128; n += 4) {
    float4 v0 = *(const float4*)&KT[n+0][c0];
    float4 v1 = *(const float4*)&KT[n+1][c0];
    float4 v2 = *(const float4*)&KT[n+2][c0];
    float4 v3 = *(const float4*)&KT[n+3][c0];
#pragma unroll
    for (int i = 0; i < 4; ++i) {
      float4 p4 = *(const float4*)&sp[r0+i][n];
      o[i][0] += p4.x*v0.x + p4.y*v1.x + p4.z*v2.x + p4.w*v3.x;
      o[i][1] += p4.x*v0.y + p4.y*v1.y + p4.z*v2.y + p4.w*v3.y;
      o[i][2] += p4.x*v0.z + p4.y*v1.z + p4.z*v2.z + p4.w*v3.z;
      o[i][3] += p4.x*v0.w + p4.y*v1.w + p4.z*v2.w + p4.w*v3.w;
    }
  }

  // ---- epilogue: h2 = bn1(x1) + O/sum (bn fused; read-before-write, same offsets) ----
  float4 sc = *(const float4*)&bns[256 + c0];
  float4 sh = *(const float4*)&bns[384 + c0];
#pragma unroll
  for (int i = 0; i < 4; ++i) {
    size_t off = (size_t)(rowg + r0 + i)*128 + c0;
    float4 xv = *(const float4*)&x1b[off];
    float4 r4;
    r4.x = xv.x*sc.x + sh.x + o[i][0]*inv[i];
    r4.y = xv.y*sc.y + sh.y + o[i][1]*inv[i];
    r4.z = xv.z*sc.z + sh.z + o[i][2]*inv[i];
    r4.w = xv.w*sc.w + sh.w + o[i][3]*inv[i];
    *(float4*)&h2[off] = r4;
  }
}

// ---------------- launch ----------------
extern "C" void kernel_launch(void* const* d_in, const int* in_sizes, int n_in,
                              void* d_out, int out_size, void* d_ws, size_t ws_size,
                              hipStream_t stream)
{
  const float* h_lig     = (const float*)d_in[0];
  const float* h_rec     = (const float*)d_in[1];
  const float* x_lig     = (const float*)d_in[2];
  const float* x_rec     = (const float*)d_in[3];
  const float* he_1      = (const float*)d_in[4];
  const float* he_2      = (const float*)d_in[5];
  const float* emlp_w1   = (const float*)d_in[6];
  const float* emlp_b1   = (const float*)d_in[7];
  const float* emlp_bn_g = (const float*)d_in[8];
  const float* emlp_bn_b = (const float*)d_in[9];
  const float* emlp_w2   = (const float*)d_in[10];
  const float* emlp_b2   = (const float*)d_in[11];
  const float* bern_temp = (const float*)d_in[12];
  const float* m_in_w    = (const float*)d_in[13];
  const float* m_conv_w  = (const float*)d_in[14];
  const float* m_conv_b  = (const float*)d_in[15];
  const float* m_xproj_w = (const float*)d_in[16];
  const float* m_dt_w    = (const float*)d_in[17];
  const float* m_dt_b    = (const float*)d_in[18];
  const float* m_A_log   = (const float*)d_in[19];
  const float* m_D       = (const float*)d_in[20];
  const float* m_out_w   = (const float*)d_in[21];
  const float* q_w       = (const float*)d_in[22];
  const float* k_w       = (const float*)d_in[23];
  const float* v_w       = (const float*)d_in[24];
  const float* bn1_g     = (const float*)d_in[25];
  const float* bn1_b     = (const float*)d_in[26];
  const float* bn2_g     = (const float*)d_in[27];
  const float* bn2_b     = (const float*)d_in[28];
  const float* ff_w1     = (const float*)d_in[29];
  const float* ff_b1     = (const float*)d_in[30];
  const float* ff_w2     = (const float*)d_in[31];
  const float* ff_b2     = (const float*)d_in[32];
  const int*   ei1       = (const int*)d_in[33];
  const int*   ei2       = (const int*)d_in[34];
  const int*   perm1     = (const int*)d_in[37];
  const int*   perm2     = (const int*)d_in[38];

  float* ws   = (float*)d_ws;
  float* dout = (float*)d_out;

#define B0(off) (ws + (size_t)(off))
#define B1(off) (ws + SS_ + (size_t)(off))

  for (int s = 0; s < 2; ++s)
    hipMemsetAsync((char*)d_ws + ((size_t)s*SS_ + DEG_OFF)*sizeof(float), 0,
                   (N_ + 2048)*sizeof(float), stream);

  // edge weights (champion kernels)
  edge_stats_kernel<<<dim3(256,2), 256, 0, stream>>>(x_lig,x_rec,he_1,he_2,ei1,ei2,emlp_w1,emlp_b1,ws);
  edge_finalize_kernel<<<dim3(1,2), 128, 0, stream>>>(emlp_bn_g,emlp_bn_b,emlp_w2,emlp_b2,ws);
  edge_w_kernel<<<dim3(256,2), 256, 0, stream>>>(x_lig,x_rec,he_1,he_2,ei1,ei2,emlp_w1,emlp_b1,ws);

  // bernstein propagation (Horner, 6 matmuls)
  bern_horner_kernel<<<dim3(G_*4,2), 256, 0, stream>>>(h_lig,h_rec,ei1,ei2,bern_temp,ws);

  // mamba
  gemm_kernel<128,256,64,4,0,1,0,0,0><<<dim3(512,2),256,0,stream>>>(
      h_lig,h_rec,128, m_in_w,nullptr, B0(XZ_OFF),B1(XZ_OFF),256, perm1,perm2, nullptr,nullptr);
  conv_kernel<<<dim3(2048,2), 256, 0, stream>>>(m_conv_w,m_conv_b,ws);
  gemm_kernel<128,40,64,1,0,0,0,0,0><<<dim3(128,2),256,0,stream>>>(
      B0(XC_OFF),B1(XC_OFF),128, m_xproj_w,nullptr, B0(DBL_OFF),B1(DBL_OFF),40, nullptr,nullptr, nullptr,nullptr);
  scan_kernel<<<dim3(32,8,2), 256, 0, stream>>>(m_A_log,m_D,m_dt_w,m_dt_b,ws);
  gemm_kernel<128,128,64,2,0,0,1,0,0><<<dim3(256,2),256,0,stream>>>(
      B0(XZ_OFF),B1(XZ_OFF),256, m_out_w,nullptr, B0(HA_OFF),B1(HA_OFF),128, perm1,perm2, nullptr,nullptr);

  // bn1 stats ( h + h_local + ha ); bn1 APPLY is fused into qkv + attn
  stats_kernel<<<dim3(128,2), 256, 0, stream>>>(h_lig,h_rec,ws,0,512);
  bn_finalize_kernel<<<dim3(1,2), 128, 0, stream>>>(bn1_g,bn1_b,ws,512,1.f/(float)N_);

  // q,k,v projections (bn1 fused in A-staging)
  qkv_kernel<<<dim3(256,2,3), 256, 0, stream>>>(q_w,k_w,v_w,ws);
  attn_kernel<<<dim3(32,4,2), 256, 0, stream>>>(ws);

  // ffn + bn2
  gemm_kernel<128,256,64,4,2,0,0,0,1><<<dim3(512,2),256,0,stream>>>(
      B0(X1_OFF),B1(X1_OFF),128, ff_w1,ff_b1, B0(XZ_OFF),B1(XZ_OFF),256, nullptr,nullptr, nullptr,nullptr);
  gemm_kernel<256,128,32,4,0,0,0,1,1><<<dim3(512,2),256,0,stream>>>(
      B0(XZ_OFF),B1(XZ_OFF),256, ff_w2,ff_b2, B0(HA_OFF),B1(HA_OFF),128, nullptr,nullptr, B0(X1_OFF),B1(X1_OFF));
  stats_kernel<<<dim3(128,2), 256, 0, stream>>>(h_lig,h_rec,ws,1,1024);
  bn_finalize_kernel<<<dim3(1,2), 128, 0, stream>>>(bn2_g,bn2_b,ws,1024,1.f/(float)N_);
  bn_apply_kernel<<<dim3(2048,2), 256, 0, stream>>>(ws,dout,HA_OFF,0,1024,1);
}

// Round 14
// 426.749 us; speedup vs baseline: 1.3412x; 1.0645x over previous
//
#include <hip/hip_runtime.h>
#include <math.h>

// ---------------- problem constants ----------------
#define G_    32
#define NPG_  128
#define D_    128
#define N_    4096          // G_*NPG_
#define E_    65536
#define ND_   (N_*D_)       // 524288

// ---------------- workspace layout (float offsets, per side) ----------------
#define W_OFF     0                     // E_ edge weights w
#define DEG_OFF   65536                 // N_ degrees (atomic, zeroed)
#define STATS_OFF 69632                 // 2048 floats of stats (zeroed):
//   [0:128) edge colsum  [128:256) edge colsumsq [256:384) alpha [384] beta
//   [512..1024) bn1: sum/ssq/scale/shift   [1024..1536) bn2: same
#define BUF0      71680
#define HL_OFF    (BUF0 + 0*ND_)        // h_local (bern output)
#define HA_OFF    (BUF0 + 1*ND_)        // mamba out (scattered); later x2
#define X1_OFF    (BUF0 + 2*ND_)        // pre-bn1 sum; later h2 (post-attn)
#define HMID_OFF  (BUF0 + 3*ND_)        // (unused since bn1 is fused into qkv/attn)
#define XC_OFF    (BUF0 + 4*ND_)        // conv output; later q
#define DTB_OFF   (BUF0 + 5*ND_)        // k
#define YB_OFF    (BUF0 + 6*ND_)        // v
#define XZ_OFF    (BUF0 + 7*ND_)        // 2*ND_: [xq|z] per row (256); scan gate overwrites xq
#define DBL_OFF   (BUF0 + 9*ND_)        // N_*40
#define WT_OFF    (DBL_OFF + N_*40)     // (unused scratch, kept for layout stability)
#define SS_       ((size_t)(WT_OFF + 4096))

__device__ __forceinline__ float leakyf(float x){ return x >= 0.f ? x : 0.02f*x; }
__device__ __forceinline__ float siluf (float x){ return x / (1.f + expf(-x)); }

// packed fp16 pair + 2-way dot with fp32 accumulate
typedef _Float16 h2 __attribute__((ext_vector_type(2)));
#if __has_builtin(__builtin_amdgcn_fdot2)
__device__ __forceinline__ float fdot2a(h2 a, h2 b, float c){
  return __builtin_amdgcn_fdot2(a, b, c, false);
}
#else
__device__ __forceinline__ float fdot2a(h2 a, h2 b, float c){
  return c + (float)a[0]*(float)b[0] + (float)a[1]*(float)b[1];
}
#endif

// ---------------- edge feature helper ----------------
__device__ __forceinline__ void edge_feat(const float* __restrict__ x,
                                          const float* __restrict__ he,
                                          const int* __restrict__ ei,
                                          int e, float* feat, int& sN, int& dN)
{
  sN = ei[e]; dN = ei[E_ + e];
  float dx = x[sN*3+0]-x[dN*3+0];
  float dy = x[sN*3+1]-x[dN*3+1];
  float dz = x[sN*3+2]-x[dN*3+2];
  float d2 = dx*dx + dy*dy + dz*dz;
  feat[0] = expf(-d2);
  feat[1] = expf(d2 * -0.1f);
  feat[2] = expf(d2 * -0.01f);
  feat[3] = expf(d2 * -0.001f);
  feat[4] = expf(d2 * -0.0001f);
#pragma unroll
  for (int j = 0; j < 27; ++j) feat[5+j] = he[(size_t)e*27 + j];
}

// ---------------- E1: per-column stats, fp16-packed dot2 core ----------------
// Champion structure (thread owns column c across its half's 128 edges);
// feat stored fp16 in LDS (rows 80B, 16B-aligned), W1 column as 16 half2 in
// VGPRs; inner loop = 4 ds_read_b128 (broadcast) + 16 fdot2 in 4 chains.
__global__ __launch_bounds__(256)
void edge_stats_kernel(const float* __restrict__ xl, const float* __restrict__ xr,
                       const float* __restrict__ hel, const float* __restrict__ her,
                       const int* __restrict__ ei1, const int* __restrict__ ei2,
                       const float* __restrict__ w1, const float* __restrict__ b1,
                       float* __restrict__ ws)
{
  int side = blockIdx.y;
  const float* x  = side ? xr  : xl;
  const float* he = side ? her : hel;
  const int*   ei = side ? ei2 : ei1;
  float* stats = ws + (size_t)side*SS_ + STATS_OFF;
  __shared__ _Float16 featl[256][40];   // rows 80B (16B-aligned)
  __shared__ float csum[2][128], cssq[2][128];
  int tid = threadIdx.x;
  {
    int sN, dN; float feat[32];
    edge_feat(x, he, ei, blockIdx.x*256 + tid, feat, sN, dN);
    h2 tmp[16];
#pragma unroll
    for (int j = 0; j < 16; ++j) { tmp[j][0] = (_Float16)feat[2*j]; tmp[j][1] = (_Float16)feat[2*j+1]; }
#pragma unroll
    for (int q = 0; q < 4; ++q)
      *(float4*)&featl[tid][q*8] = ((const float4*)tmp)[q];
  }
  int c = tid & 127, hh = tid >> 7;
  h2 w1h[16];
#pragma unroll
  for (int j = 0; j < 16; ++j) {
    w1h[j][0] = (_Float16)w1[(2*j)*128 + c];
    w1h[j][1] = (_Float16)w1[(2*j+1)*128 + c];
  }
  float b1c = b1[c];
  __syncthreads();
  float s1 = 0.f, s2 = 0.f;
  for (int e = 0; e < 128; ++e) {
    const h2* fh = (const h2*)&featl[hh*128 + e][0];
    float a0 = 0.f, a1 = 0.f, a2 = 0.f, a3 = 0.f;
#pragma unroll
    for (int q = 0; q < 4; ++q) {
      a0 = fdot2a(fh[q*4+0], w1h[q*4+0], a0);
      a1 = fdot2a(fh[q*4+1], w1h[q*4+1], a1);
      a2 = fdot2a(fh[q*4+2], w1h[q*4+2], a2);
      a3 = fdot2a(fh[q*4+3], w1h[q*4+3], a3);
    }
    float t = leakyf(b1c + ((a0+a1) + (a2+a3)));
    s1 += t; s2 += t*t;
  }
  csum[hh][c] = s1; cssq[hh][c] = s2;
  __syncthreads();
  if (tid < 128) {
    atomicAdd(&stats[tid],     csum[0][tid] + csum[1][tid]);
    atomicAdd(&stats[128+tid], cssq[0][tid] + cssq[1][tid]);
  }
}

// ---------------- E2: finalize edge bn folded with emlp_w2 -> alpha,beta ----------------
__global__ void edge_finalize_kernel(const float* __restrict__ g_, const float* __restrict__ b_,
                                     const float* __restrict__ w2, const float* __restrict__ b2,
                                     float* __restrict__ ws)
{
  int side = blockIdx.y;
  float* stats = ws + (size_t)side*SS_ + STATS_OFF;
  __shared__ float red[128];
  int c = threadIdx.x;  // 128 threads
  const float invE = 1.f/(float)E_;
  float mean = stats[c]*invE;
  float var  = fmaxf(stats[128+c]*invE - mean*mean, 0.f);
  float scale = rsqrtf(var + 1e-5f) * g_[c];
  stats[256+c] = scale * w2[c];
  red[c] = (b_[c] - mean*scale) * w2[c];
  __syncthreads();
  for (int off = 64; off; off >>= 1) { if (c < off) red[c] += red[c+off]; __syncthreads(); }
  if (c == 0) stats[384] = red[0] + b2[0];
}

// ---------------- E3: w_e, fp16-packed dot2 core ----------------
// Champion structure (thread per edge, feat in regs as 16 half2; W1^T fp16 in
// LDS, 8KB); per column: 4 b128 broadcast reads + 16 fdot2 in 4 chains.
__global__ __launch_bounds__(256)
void edge_w_kernel(const float* __restrict__ xl, const float* __restrict__ xr,
                   const float* __restrict__ hel, const float* __restrict__ her,
                   const int* __restrict__ ei1, const int* __restrict__ ei2,
                   const float* __restrict__ w1, const float* __restrict__ b1,
                   float* __restrict__ ws)
{
  int side = blockIdx.y;
  const float* x  = side ? xr  : xl;
  const float* he = side ? her : hel;
  const int*   ei = side ? ei2 : ei1;
  float* base = ws + (size_t)side*SS_;
  const float* stats = base + STATS_OFF;
  float* wbuf = base + W_OFF;
  float* deg  = base + DEG_OFF;
  __shared__ _Float16 w1t[128][32];     // rows 64B (16B-aligned), 8KB
  __shared__ float b1l[128], all_[128];
  int tid = threadIdx.x;
  for (int i = tid; i < 4096; i += 256) {
    int j = i & 31, c = i >> 5;
    w1t[c][j] = (_Float16)w1[j*128 + c];
  }
  if (tid < 128) { b1l[tid] = b1[tid]; all_[tid] = stats[256+tid]; }
  __syncthreads();
  int e = blockIdx.x*256 + tid;
  int sN, dN; float feat[32];
  edge_feat(x, he, ei, e, feat, sN, dN);
  h2 fh[16];
#pragma unroll
  for (int j = 0; j < 16; ++j) { fh[j][0] = (_Float16)feat[2*j]; fh[j][1] = (_Float16)feat[2*j+1]; }
  float accw = stats[384];
  for (int c = 0; c < 128; ++c) {
    const h2* wc = (const h2*)&w1t[c][0];
    float a0 = 0.f, a1 = 0.f, a2 = 0.f, a3 = 0.f;
#pragma unroll
    for (int q = 0; q < 4; ++q) {
      a0 = fdot2a(fh[q*4+0], wc[q*4+0], a0);
      a1 = fdot2a(fh[q*4+1], wc[q*4+1], a1);
      a2 = fdot2a(fh[q*4+2], wc[q*4+2], a2);
      a3 = fdot2a(fh[q*4+3], wc[q*4+3], a3);
    }
    accw += leakyf(b1l[c] + ((a0+a1) + (a2+a3))) * all_[c];
  }
  float w = fmaxf(accw, 0.f);
  wbuf[e] = w;
  atomicAdd(&deg[sN], w);
}

// ---------------- Bernstein propagation via Horner (6 matmuls) ----------------
__global__ __launch_bounds__(256)
void bern_horner_kernel(const float* __restrict__ hl_in, const float* __restrict__ hr_in,
                        const int* __restrict__ ei1, const int* __restrict__ ei2,
                        const float* __restrict__ bern_temp, float* __restrict__ ws)
{
  int side = blockIdx.y;
  int g  = blockIdx.x >> 2;
  int d0 = (blockIdx.x & 3) * 32;
  const float* h  = side ? hr_in : hl_in;
  const int*   ei = side ? ei2 : ei1;
  float* base = ws + (size_t)side*SS_;
  const float* wbuf = base + W_OFF;
  const float* deg  = base + DEG_OFF;
  float* hloc = base + HL_OFF;

  __shared__ float A[128*132];
  __shared__ float v[128*32];
  int tid = threadIdx.x;
  for (int i = tid; i < 128*132; i += 256) A[i] = 0.f;

  const float btab[7][7] = {
    { 1,  6, 15,  20, 15,  6,  1},
    { 1,  4,  5,   0, -5, -4, -1},
    { 1,  2, -1,  -4, -1,  2,  1},
    { 1,  0, -3,   0,  3,  0, -1},
    { 1, -2, -1,   4, -1, -2,  1},
    { 1, -4,  5,   0, -5,  4, -1},
    { 1, -6, 15, -20, 15, -6,  1}};
  const float comb6[7] = {1,6,15,20,15,6,1};
  float a[7];
#pragma unroll
  for (int m = 0; m < 7; ++m) a[m] = 0.f;
#pragma unroll
  for (int j = 0; j < 7; ++j) {
    float tj = fmaxf(bern_temp[j], 0.f) * comb6[j] * (1.f/64.f);
#pragma unroll
    for (int m = 0; m < 7; ++m) a[m] += tj * btab[j][m];
  }
  __syncthreads();

  int ebase = g*2048, nbase = g*128;
  for (int i = tid; i < 2048; i += 256) {
    int e = ebase + i;
    int sN = ei[e], dN = ei[E_ + e];
    float ds_ = deg[sN], dd_ = deg[dN];
    float aa = ds_ > 0.f ? rsqrtf(ds_ + 1e-12f) : 0.f;
    float bb = dd_ > 0.f ? rsqrtf(dd_ + 1e-12f) : 0.f;
    atomicAdd(&A[(dN - nbase)*132 + (sN - nbase)], wbuf[e]*aa*bb);
  }

  const int db = (tid & 7)*4;
  const int rb = (tid >> 3)*4;
  float hreg[4][4], r[4][4], t[4][4];
#pragma unroll
  for (int i = 0; i < 4; ++i) {
    float4 h4 = *(const float4*)&h[(size_t)(nbase + rb + i)*128 + d0 + db];
    hreg[i][0]=h4.x; hreg[i][1]=h4.y; hreg[i][2]=h4.z; hreg[i][3]=h4.w;
#pragma unroll
    for (int jj = 0; jj < 4; ++jj) r[i][jj] = a[6]*hreg[i][jj];
  }

  for (int step = 5; step >= 0; --step) {
    __syncthreads();
#pragma unroll
    for (int i = 0; i < 4; ++i)
      *(float4*)&v[(rb+i)*32 + db] = make_float4(r[i][0], r[i][1], r[i][2], r[i][3]);
    __syncthreads();
#pragma unroll
    for (int i = 0; i < 4; ++i)
#pragma unroll
      for (int jj = 0; jj < 4; ++jj) t[i][jj] = 0.f;
    for (int k = 0; k < 128; k += 4) {
      float4 V0 = *(const float4*)&v[(k+0)*32 + db];
      float4 V1 = *(const float4*)&v[(k+1)*32 + db];
      float4 V2 = *(const float4*)&v[(k+2)*32 + db];
      float4 V3 = *(const float4*)&v[(k+3)*32 + db];
#pragma unroll
      for (int i = 0; i < 4; ++i) {
        float4 A4 = *(const float4*)&A[(rb+i)*132 + k];
        t[i][0] += A4.x*V0.x + A4.y*V1.x + A4.z*V2.x + A4.w*V3.x;
        t[i][1] += A4.x*V0.y + A4.y*V1.y + A4.z*V2.y + A4.w*V3.y;
        t[i][2] += A4.x*V0.z + A4.y*V1.z + A4.z*V2.z + A4.w*V3.z;
        t[i][3] += A4.x*V0.w + A4.y*V1.w + A4.z*V2.w + A4.w*V3.w;
      }
    }
    float ak = a[step];
#pragma unroll
    for (int i = 0; i < 4; ++i)
#pragma unroll
      for (int jj = 0; jj < 4; ++jj) r[i][jj] = t[i][jj] + ak*hreg[i][jj];
  }

#pragma unroll
  for (int i = 0; i < 4; ++i)
    *(float4*)&hloc[(size_t)(nbase + rb + i)*128 + d0 + db] =
        make_float4(r[i][0], r[i][1], r[i][2], r[i][3]);
}

// ---------------- generic f32 GEMM, col-split for occupancy, grid.y = side ----------------
template<int K, int NC, int TC, int CSPLIT, int ACT, int GATHER, int SCATTER, int ADDC, int BIAS>
__global__ __launch_bounds__(256)
void gemm_kernel(const float* __restrict__ A0, const float* __restrict__ A1, int lda,
                 const float* __restrict__ W, const float* __restrict__ bias,
                 float* __restrict__ C0, float* __restrict__ C1, int ldc,
                 const int* __restrict__ idx0, const int* __restrict__ idx1,
                 const float* __restrict__ add0, const float* __restrict__ add1)
{
  int side = blockIdx.y;
  const float* A = side ? A1 : A0;
  float* C = side ? C1 : C0;
  const int* idx = side ? idx1 : idx0;
  const float* addsrc = side ? add1 : add0;
  constexpr int RPT = TC/8;
  constexpr int CLEN = NC/CSPLIT;
  __shared__ float Alds[32][K];
  __shared__ float Wlds[K][TC];
  const int tid = threadIdx.x;
  const int r0 = (blockIdx.x / CSPLIT) * 32;
  const int cbase = (blockIdx.x % CSPLIT) * CLEN;
  for (int i = tid*4; i < 32*K; i += 1024) {
    int r = i / K, k = i % K;
    int row = GATHER ? idx[r0 + r] : (r0 + r);
    *(float4*)&Alds[r][k] = *(const float4*)&A[(size_t)row*lda + k];
  }
  for (int c0 = cbase; c0 < cbase + CLEN; c0 += TC) {
    __syncthreads();
    for (int i = tid*4; i < K*TC; i += 1024) {
      int k = i / TC, c = i % TC;
      if (c0 + c < NC) *(float4*)&Wlds[k][c] = *(const float4*)&W[k*NC + c0 + c];
      else             *(float4*)&Wlds[k][c] = make_float4(0.f,0.f,0.f,0.f);
    }
    __syncthreads();
    const int cl = tid % TC;
    const int rsub = (tid / TC) * RPT;
    float accv[RPT];
#pragma unroll
    for (int j = 0; j < RPT; ++j) accv[j] = 0.f;
    for (int k = 0; k < K; k += 4) {
      float w0 = Wlds[k][cl], w1v = Wlds[k+1][cl], w2v = Wlds[k+2][cl], w3v = Wlds[k+3][cl];
#pragma unroll
      for (int j = 0; j < RPT; ++j) {
        float4 a4 = *(const float4*)&Alds[rsub+j][k];
        accv[j] += a4.x*w0 + a4.y*w1v + a4.z*w2v + a4.w*w3v;
      }
    }
    int c = c0 + cl;
    if (c < NC) {
#pragma unroll
      for (int j = 0; j < RPT; ++j) {
        int row  = r0 + rsub + j;
        int orow = SCATTER ? idx[row] : row;
        float vv = accv[j];
        if (BIAS)     vv += bias[c];
        if (ACT == 1) vv = leakyf(vv);
        if (ACT == 2) vv = fmaxf(vv, 0.f);
        if (ADDC)     vv += addsrc[(size_t)orow*ldc + c];
        C[(size_t)orow*ldc + c] = vv;
      }
    }
  }
}

// ---------------- qkv: 3 projections in one dispatch; bn1 fused into A-staging ----------
__global__ __launch_bounds__(256)
void qkv_kernel(const float* __restrict__ qw, const float* __restrict__ kw,
                const float* __restrict__ vw, float* __restrict__ ws)
{
  int side = blockIdx.y;
  int mat  = blockIdx.z;
  float* base = ws + (size_t)side*SS_;
  const float* A = base + X1_OFF;                 // pre-bn1 x1
  const float* bns = base + STATS_OFF + 512;      // bn1: scale at +256, shift at +384
  const float* W = mat == 0 ? qw : (mat == 1 ? kw : vw);
  float* C = base + (mat == 0 ? XC_OFF : (mat == 1 ? DTB_OFF : YB_OFF));
  __shared__ float Alds[32][128];
  __shared__ float Wlds[128][64];
  const int tid = threadIdx.x;
  const int r0 = (blockIdx.x >> 1) * 32;
  const int c0 = (blockIdx.x & 1) * 64;
  for (int i = tid*4; i < 32*128; i += 1024) {
    int k = i & 127;
    float4 a4 = *(const float4*)&A[(size_t)(r0 + (i>>7))*128 + k];
    float4 sc = *(const float4*)&bns[256 + k];
    float4 sh = *(const float4*)&bns[384 + k];
    a4.x = a4.x*sc.x + sh.x;
    a4.y = a4.y*sc.y + sh.y;
    a4.z = a4.z*sc.z + sh.z;
    a4.w = a4.w*sc.w + sh.w;
    *(float4*)&Alds[i>>7][k] = a4;
  }
  for (int i = tid*4; i < 128*64; i += 1024)
    *(float4*)&Wlds[i>>6][i&63] = *(const float4*)&W[(i>>6)*128 + c0 + (i&63)];
  __syncthreads();
  const int cl = tid & 63;
  const int rsub = (tid >> 6) * 8;
  float accv[8];
#pragma unroll
  for (int j = 0; j < 8; ++j) accv[j] = 0.f;
  for (int k = 0; k < 128; k += 4) {
    float w0 = Wlds[k][cl], w1v = Wlds[k+1][cl], w2v = Wlds[k+2][cl], w3v = Wlds[k+3][cl];
#pragma unroll
    for (int j = 0; j < 8; ++j) {
      float4 a4 = *(const float4*)&Alds[rsub+j][k];
      accv[j] += a4.x*w0 + a4.y*w1v + a4.z*w2v + a4.w*w3v;
    }
  }
#pragma unroll
  for (int j = 0; j < 8; ++j) {
    float vv = accv[j];
    if (mat < 2) vv = leakyf(vv);
    C[(size_t)(r0 + rsub + j)*128 + c0 + cl] = vv;
  }
}

// ---------------- mamba: causal depthwise conv (DCONV=4) + silu ----------------
__global__ __launch_bounds__(256)
void conv_kernel(const float* __restrict__ cw, const float* __restrict__ cb, float* __restrict__ ws)
{
  int side = blockIdx.y;
  float* base = ws + (size_t)side*SS_;
  const float* xz = base + XZ_OFF;
  float* xc = base + XC_OFF;
  int i = blockIdx.x*256 + threadIdx.x;
  int j = i >> 7, d = i & 127;
  int l = j & 127;
  float a = cb[d];
#pragma unroll
  for (int k = 0; k < 4; ++k) {
    int ll = l - 3 + k;
    if (ll >= 0) a += xz[(size_t)(j-3+k)*256 + d] * cw[d*4 + k];
  }
  xc[i] = siluf(a);
}

// ---------------- mamba scan: fused dt(softplus) + 128-step recurrence + gate ----------------
__global__ __launch_bounds__(256)
void scan_kernel(const float* __restrict__ A_log, const float* __restrict__ Dp,
                 const float* __restrict__ dtw, const float* __restrict__ dtbias,
                 float* __restrict__ ws)
{
  int side = blockIdx.z;
  int g  = blockIdx.x;
  int d0 = blockIdx.y * 16;
  float* base = ws + (size_t)side*SS_;
  const float* dbl = base + DBL_OFF;
  const float* xcb = base + XC_OFF;
  float* xz = base + XZ_OFF;

  __shared__ float ldbl[128][40];   // dt-in(8) | B(16) | C(16)
  __shared__ float lxc[128][16];
  __shared__ float ldt[128][16];
  __shared__ float lz[128][16];
  __shared__ float ly[128][16];
  __shared__ float ltw[8][16];
  __shared__ float ltb[16];

  int tid = threadIdx.x;
  int rowbase = g*128;
  if (tid < 128)      ltw[tid>>4][tid&15] = dtw[(tid>>4)*128 + d0 + (tid&15)];
  else if (tid < 144) ltb[tid-128] = dtbias[d0 + (tid-128)];
  for (int i = tid; i < 128*40; i += 256)
    ((float*)ldbl)[i] = dbl[(size_t)rowbase*40 + i];
  for (int i = tid; i < 2048; i += 256) {
    int l = i >> 4, dd = i & 15;
    lxc[l][dd] = xcb[(size_t)(rowbase+l)*128 + d0 + dd];
    lz[l][dd]  = xz[(size_t)(rowbase+l)*256 + 128 + d0 + dd];
  }
  __syncthreads();
  // dt = softplus(dbl[:, :8] @ dtw + dtb)  — once per (l,d)
  for (int i = tid; i < 2048; i += 256) {
    int l = i >> 4, dd = i & 15;
    float a = ltb[dd];
#pragma unroll
    for (int k = 0; k < 8; ++k) a += ldbl[l][k]*ltw[k][dd];
    ldt[l][dd] = a > 20.f ? a : log1pf(expf(a));
  }
  __syncthreads();

  int s = tid & 15, dl = (tid >> 4) & 15;
  float Ac  = -expf(A_log[(d0+dl)*16 + s]);
  float dpv = Dp[d0+dl];
  float hsv = 0.f;
  for (int l = 0; l < 128; ++l) {
    float dtv = ldt[l][dl];      // broadcast across s
    float xcv = lxc[l][dl];
    float Bv  = ldbl[l][8+s];
    float Cv  = ldbl[l][24+s];
    hsv = expf(dtv*Ac)*hsv + (dtv*xcv)*Bv;
    float val = hsv*Cv;
    val += __shfl_xor(val, 1, 16);
    val += __shfl_xor(val, 2, 16);
    val += __shfl_xor(val, 4, 16);
    val += __shfl_xor(val, 8, 16);
    if (s == 0) ly[l][dl] = val + xcv*dpv;
  }
  __syncthreads();
  // gate: xz[:, :128] = y * silu(z)
  for (int i = tid; i < 2048; i += 256) {
    int l = i >> 4, dd = i & 15;
    float y = ly[l][dd];
    float z = lz[l][dd];
    xz[(size_t)(rowbase+l)*256 + d0 + dd] = y * siluf(z);
  }
}

// ---------------- column stats ----------------
__global__ __launch_bounds__(256)
void stats_kernel(const float* __restrict__ hl_in, const float* __restrict__ hr_in,
                  float* __restrict__ ws, int mode, int statsoff)
{
  int side = blockIdx.y;
  float* base = ws + (size_t)side*SS_;
  const float* h    = side ? hr_in : hl_in;
  const float* hloc = base + HL_OFF;
  const float* ha   = base + HA_OFF;
  float* x1 = base + X1_OFF;
  float* stats = base + STATS_OFF + statsoff;
  int tid = threadIdx.x;
  int c = tid & 127;
  float s1 = 0.f, s2 = 0.f;
  for (int it = 0; it < 16; ++it) {
    int r = blockIdx.x*32 + (tid >> 7) + it*2;
    size_t i = (size_t)r*128 + c;
    float v;
    if (mode == 0) { v = h[i] + hloc[i] + ha[i]; x1[i] = v; }
    else           { v = ha[i]; }
    s1 += v; s2 += v*v;
  }
  __shared__ float red[256];
  red[tid] = s1; __syncthreads();
  if (tid < 128) atomicAdd(&stats[tid], red[tid] + red[tid+128]);
  __syncthreads();
  red[tid] = s2; __syncthreads();
  if (tid < 128) atomicAdd(&stats[128+tid], red[tid] + red[tid+128]);
}

__global__ void bn_finalize_kernel(const float* __restrict__ g_, const float* __restrict__ b_,
                                   float* __restrict__ ws, int statsoff, float invM)
{
  int side = blockIdx.y;
  float* stats = ws + (size_t)side*SS_ + STATS_OFF + statsoff;
  int c = threadIdx.x;   // 128 threads
  float mean = stats[c]*invM;
  float var  = fmaxf(stats[128+c]*invM - mean*mean, 0.f);
  float scale = rsqrtf(var + 1e-5f) * g_[c];
  stats[256+c] = scale;
  stats[384+c] = b_[c] - mean*scale;
}

__global__ __launch_bounds__(256)
void bn_apply_kernel(float* __restrict__ ws, float* __restrict__ dout,
                     int srcoff, int dstoff, int statsoff, int to_dout)
{
  int side = blockIdx.y;
  float* base = ws + (size_t)side*SS_;
  const float* src = base + srcoff;
  const float* stats = base + STATS_OFF + statsoff;
  float* dst = to_dout ? (dout + (size_t)side*ND_) : (base + dstoff);
  size_t i = (size_t)blockIdx.x*256 + threadIdx.x;
  int c = (int)(i & 127);
  dst[i] = src[i]*stats[256+c] + stats[384+c];
}

// ---------------- cross attention (register-tiled); bn1 fused on residual read ------
__global__ __launch_bounds__(256)
void attn_kernel(float* __restrict__ ws)
{
  int dir = blockIdx.z;
  int g   = blockIdx.x;
  int rt  = blockIdx.y;
  float* baseq = ws + (size_t)dir*SS_;
  float* basek = ws + (size_t)(1-dir)*SS_;
  const float* qb = baseq + XC_OFF;
  const float* kb = basek + DTB_OFF;
  const float* vb = basek + YB_OFF;
  const float* x1b = baseq + X1_OFF;            // pre-bn1 x1 (hm = bn(x1))
  const float* bns = baseq + STATS_OFF + 512;   // bn1 scale/shift
  float* h2v = baseq + X1_OFF;                  // overwritten in place (same offsets)

  __shared__ float KT[128][132];   // phase A: K^T as [d][n]; phase C: V as [n][d]
  __shared__ float Qs[32][132];    // Q tile
  __shared__ float sp[32][132];    // unnormalized P tile

  const int tid = threadIdx.x;
  const int cl  = tid & 31;          // 32 col-lanes
  const int r0  = (tid >> 5) * 4;    // 8 row-groups * 4 rows = 32 rows
  const int c0  = cl * 4;            // 4 cols per thread (128 total)
  const int rowg = g*128 + rt*32;

  // ---- stage Q tile (32 x 128) ----
  {
    const float* qsrc = qb + (size_t)rowg*128;
    for (int i = tid; i < 32*32; i += 256) {
      int r = i >> 5, d4 = i & 31;
      *(float4*)&Qs[r][d4*4] = *(const float4*)&qsrc[(size_t)r*128 + d4*4];
    }
  }
  // ---- stage K^T (transpose 128x128) ----
  {
    const float* ksrc = kb + (size_t)(g*128)*128;
    for (int i = tid; i < 128*32; i += 256) {
      int d4 = i >> 7, n = i & 127;
      float4 k4 = *(const float4*)&ksrc[(size_t)n*128 + d4*4];
      KT[d4*4+0][n] = k4.x;
      KT[d4*4+1][n] = k4.y;
      KT[d4*4+2][n] = k4.z;
      KT[d4*4+3][n] = k4.w;
    }
  }
  __syncthreads();

  // ---- phase A: scores, 4 rows x 4 cols per thread ----
  float acc[4][4];
#pragma unroll
  for (int i = 0; i < 4; ++i)
#pragma unroll
    for (int j = 0; j < 4; ++j) acc[i][j] = 0.f;

  for (int d = 0; d < 128; d += 4) {
    float4 k0 = *(const float4*)&KT[d+0][c0];
    float4 k1 = *(const float4*)&KT[d+1][c0];
    float4 k2 = *(const float4*)&KT[d+2][c0];
    float4 k3 = *(const float4*)&KT[d+3][c0];
#pragma unroll
    for (int i = 0; i < 4; ++i) {
      float4 q4 = *(const float4*)&Qs[r0+i][d];
      acc[i][0] += q4.x*k0.x + q4.y*k1.x + q4.z*k2.x + q4.w*k3.x;
      acc[i][1] += q4.x*k0.y + q4.y*k1.y + q4.z*k2.y + q4.w*k3.y;
      acc[i][2] += q4.x*k0.z + q4.y*k1.z + q4.z*k2.z + q4.w*k3.z;
      acc[i][3] += q4.x*k0.w + q4.y*k1.w + q4.z*k2.w + q4.w*k3.w;
    }
  }

  // ---- softmax in registers; store unnormalized P; keep 1/sum per row ----
  float inv[4];
#pragma unroll
  for (int i = 0; i < 4; ++i) {
    float m = fmaxf(fmaxf(acc[i][0], acc[i][1]), fmaxf(acc[i][2], acc[i][3]));
#pragma unroll
    for (int off = 1; off < 32; off <<= 1) m = fmaxf(m, __shfl_xor(m, off, 32));
    float p0 = expf(acc[i][0]-m), p1 = expf(acc[i][1]-m);
    float p2 = expf(acc[i][2]-m), p3 = expf(acc[i][3]-m);
    float s = p0 + p1 + p2 + p3;
#pragma unroll
    for (int off = 1; off < 32; off <<= 1) s += __shfl_xor(s, off, 32);
    inv[i] = 1.f/s;
    *(float4*)&sp[r0+i][c0] = make_float4(p0, p1, p2, p3);
  }
  __syncthreads();

  // ---- stage V (natural [n][d], coalesced, float4 writes) ----
  {
    const float* vsrc = vb + (size_t)(g*128)*128;
    for (int i = tid; i < 128*32; i += 256) {
      int n = i >> 5, d4 = i & 31;
      *(float4*)&KT[n][d4*4] = *(const float4*)&vsrc[(size_t)n*128 + d4*4];
    }
  }
  __syncthreads();

  // ---- phase C: O = P @ V, 4 rows x 4 d-cols per thread ----
  float o[4][4];
#pragma unroll
  for (int i = 0; i < 4; ++i)
#pragma unroll
    for (int j = 0; j < 4; ++j) o[i][j] = 0.f;

  for (int n = 0; n < 128; n += 4) {
    float4 v0 = *(const float4*)&KT[n+0][c0];
    float4 v1 = *(const float4*)&KT[n+1][c0];
    float4 v2 = *(const float4*)&KT[n+2][c0];
    float4 v3 = *(const float4*)&KT[n+3][c0];
#pragma unroll
    for (int i = 0; i < 4; ++i) {
      float4 p4 = *(const float4*)&sp[r0+i][n];
      o[i][0] += p4.x*v0.x + p4.y*v1.x + p4.z*v2.x + p4.w*v3.x;
      o[i][1] += p4.x*v0.y + p4.y*v1.y + p4.z*v2.y + p4.w*v3.y;
      o[i][2] += p4.x*v0.z + p4.y*v1.z + p4.z*v2.z + p4.w*v3.z;
      o[i][3] += p4.x*v0.w + p4.y*v1.w + p4.z*v2.w + p4.w*v3.w;
    }
  }

  // ---- epilogue: h2 = bn1(x1) + O/sum (bn fused; read-before-write, same offsets) ----
  float4 sc = *(const float4*)&bns[256 + c0];
  float4 sh = *(const float4*)&bns[384 + c0];
#pragma unroll
  for (int i = 0; i < 4; ++i) {
    size_t off = (size_t)(rowg + r0 + i)*128 + c0;
    float4 xv = *(const float4*)&x1b[off];
    float4 r4;
    r4.x = xv.x*sc.x + sh.x + o[i][0]*inv[i];
    r4.y = xv.y*sc.y + sh.y + o[i][1]*inv[i];
    r4.z = xv.z*sc.z + sh.z + o[i][2]*inv[i];
    r4.w = xv.w*sc.w + sh.w + o[i][3]*inv[i];
    *(float4*)&h2v[off] = r4;
  }
}

// ---------------- launch ----------------
extern "C" void kernel_launch(void* const* d_in, const int* in_sizes, int n_in,
                              void* d_out, int out_size, void* d_ws, size_t ws_size,
                              hipStream_t stream)
{
  const float* h_lig     = (const float*)d_in[0];
  const float* h_rec     = (const float*)d_in[1];
  const float* x_lig     = (const float*)d_in[2];
  const float* x_rec     = (const float*)d_in[3];
  const float* he_1      = (const float*)d_in[4];
  const float* he_2      = (const float*)d_in[5];
  const float* emlp_w1   = (const float*)d_in[6];
  const float* emlp_b1   = (const float*)d_in[7];
  const float* emlp_bn_g = (const float*)d_in[8];
  const float* emlp_bn_b = (const float*)d_in[9];
  const float* emlp_w2   = (const float*)d_in[10];
  const float* emlp_b2   = (const float*)d_in[11];
  const float* bern_temp = (const float*)d_in[12];
  const float* m_in_w    = (const float*)d_in[13];
  const float* m_conv_w  = (const float*)d_in[14];
  const float* m_conv_b  = (const float*)d_in[15];
  const float* m_xproj_w = (const float*)d_in[16];
  const float* m_dt_w    = (const float*)d_in[17];
  const float* m_dt_b    = (const float*)d_in[18];
  const float* m_A_log   = (const float*)d_in[19];
  const float* m_D       = (const float*)d_in[20];
  const float* m_out_w   = (const float*)d_in[21];
  const float* q_w       = (const float*)d_in[22];
  const float* k_w       = (const float*)d_in[23];
  const float* v_w       = (const float*)d_in[24];
  const float* bn1_g     = (const float*)d_in[25];
  const float* bn1_b     = (const float*)d_in[26];
  const float* bn2_g     = (const float*)d_in[27];
  const float* bn2_b     = (const float*)d_in[28];
  const float* ff_w1     = (const float*)d_in[29];
  const float* ff_b1     = (const float*)d_in[30];
  const float* ff_w2     = (const float*)d_in[31];
  const float* ff_b2     = (const float*)d_in[32];
  const int*   ei1       = (const int*)d_in[33];
  const int*   ei2       = (const int*)d_in[34];
  const int*   perm1     = (const int*)d_in[37];
  const int*   perm2     = (const int*)d_in[38];

  float* ws   = (float*)d_ws;
  float* dout = (float*)d_out;

#define B0(off) (ws + (size_t)(off))
#define B1(off) (ws + SS_ + (size_t)(off))

  for (int s = 0; s < 2; ++s)
    hipMemsetAsync((char*)d_ws + ((size_t)s*SS_ + DEG_OFF)*sizeof(float), 0,
                   (N_ + 2048)*sizeof(float), stream);

  // edge weights (champion structure, fp16-packed dot2 core)
  edge_stats_kernel<<<dim3(256,2), 256, 0, stream>>>(x_lig,x_rec,he_1,he_2,ei1,ei2,emlp_w1,emlp_b1,ws);
  edge_finalize_kernel<<<dim3(1,2), 128, 0, stream>>>(emlp_bn_g,emlp_bn_b,emlp_w2,emlp_b2,ws);
  edge_w_kernel<<<dim3(256,2), 256, 0, stream>>>(x_lig,x_rec,he_1,he_2,ei1,ei2,emlp_w1,emlp_b1,ws);

  // bernstein propagation (Horner, 6 matmuls)
  bern_horner_kernel<<<dim3(G_*4,2), 256, 0, stream>>>(h_lig,h_rec,ei1,ei2,bern_temp,ws);

  // mamba
  gemm_kernel<128,256,64,4,0,1,0,0,0><<<dim3(512,2),256,0,stream>>>(
      h_lig,h_rec,128, m_in_w,nullptr, B0(XZ_OFF),B1(XZ_OFF),256, perm1,perm2, nullptr,nullptr);
  conv_kernel<<<dim3(2048,2), 256, 0, stream>>>(m_conv_w,m_conv_b,ws);
  gemm_kernel<128,40,64,1,0,0,0,0,0><<<dim3(128,2),256,0,stream>>>(
      B0(XC_OFF),B1(XC_OFF),128, m_xproj_w,nullptr, B0(DBL_OFF),B1(DBL_OFF),40, nullptr,nullptr, nullptr,nullptr);
  scan_kernel<<<dim3(32,8,2), 256, 0, stream>>>(m_A_log,m_D,m_dt_w,m_dt_b,ws);
  gemm_kernel<128,128,64,2,0,0,1,0,0><<<dim3(256,2),256,0,stream>>>(
      B0(XZ_OFF),B1(XZ_OFF),256, m_out_w,nullptr, B0(HA_OFF),B1(HA_OFF),128, perm1,perm2, nullptr,nullptr);

  // bn1 stats ( h + h_local + ha ); bn1 APPLY is fused into qkv + attn
  stats_kernel<<<dim3(128,2), 256, 0, stream>>>(h_lig,h_rec,ws,0,512);
  bn_finalize_kernel<<<dim3(1,2), 128, 0, stream>>>(bn1_g,bn1_b,ws,512,1.f/(float)N_);

  // q,k,v projections (bn1 fused in A-staging)
  qkv_kernel<<<dim3(256,2,3), 256, 0, stream>>>(q_w,k_w,v_w,ws);
  attn_kernel<<<dim3(32,4,2), 256, 0, stream>>>(ws);

  // ffn + bn2
  gemm_kernel<128,256,64,4,2,0,0,0,1><<<dim3(512,2),256,0,stream>>>(
      B0(X1_OFF),B1(X1_OFF),128, ff_w1,ff_b1, B0(XZ_OFF),B1(XZ_OFF),256, nullptr,nullptr, nullptr,nullptr);
  gemm_kernel<256,128,32,4,0,0,0,1,1><<<dim3(512,2),256,0,stream>>>(
      B0(XZ_OFF),B1(XZ_OFF),256, ff_w2,ff_b2, B0(HA_OFF),B1(HA_OFF),128, nullptr,nullptr, B0(X1_OFF),B1(X1_OFF));
  stats_kernel<<<dim3(128,2), 256, 0, stream>>>(h_lig,h_rec,ws,1,1024);
  bn_finalize_kernel<<<dim3(1,2), 128, 0, stream>>>(bn2_g,bn2_b,ws,1024,1.f/(float)N_);
  bn_apply_kernel<<<dim3(2048,2), 256, 0, stream>>>(ws,dout,HA_OFF,0,1024,1);
}

// Round 15
// 413.990 us; speedup vs baseline: 1.3825x; 1.0308x over previous
//
#include <hip/hip_runtime.h>
#include <math.h>

// ---------------- problem constants ----------------
#define G_    32
#define NPG_  128
#define D_    128
#define N_    4096          // G_*NPG_
#define E_    65536
#define ND_   (N_*D_)       // 524288

// ---------------- workspace layout (float offsets, per side) ----------------
#define W_OFF     0                     // E_ edge weights w
#define DEG_OFF   65536                 // N_ degrees (atomic, zeroed)
#define STATS_OFF 69632                 // 2048 floats of stats (zeroed):
//   [0:128) edge colsum  [128:256) edge colsumsq [256:384) alpha [384] beta
//   [512..1024) bn1: sum/ssq/scale/shift   [1024..1536) bn2: same
#define BUF0      71680
#define HL_OFF    (BUF0 + 0*ND_)        // h_local (bern output)
#define HA_OFF    (BUF0 + 1*ND_)        // mamba out (scattered); later x2
#define X1_OFF    (BUF0 + 2*ND_)        // pre-bn1 sum; later h2 (post-attn)
#define HMID_OFF  (BUF0 + 3*ND_)        // (unused since bn1 is fused into qkv/attn)
#define XC_OFF    (BUF0 + 4*ND_)        // conv output; later q
#define DTB_OFF   (BUF0 + 5*ND_)        // k
#define YB_OFF    (BUF0 + 6*ND_)        // v
#define XZ_OFF    (BUF0 + 7*ND_)        // 2*ND_: [xq|z] per row (256); scan gate overwrites xq
#define DBL_OFF   (BUF0 + 9*ND_)        // N_*40
#define WT_OFF    (DBL_OFF + N_*40)     // (unused scratch, kept for layout stability)
#define SS_       ((size_t)(WT_OFF + 4096))

__device__ __forceinline__ float leakyf(float x){ return x >= 0.f ? x : 0.02f*x; }
__device__ __forceinline__ float siluf (float x){ return x / (1.f + expf(-x)); }

// packed fp16 pair + 2-way dot with fp32 accumulate
typedef _Float16 h2 __attribute__((ext_vector_type(2)));
#if __has_builtin(__builtin_amdgcn_fdot2)
__device__ __forceinline__ float fdot2a(h2 a, h2 b, float c){
  return __builtin_amdgcn_fdot2(a, b, c, false);
}
#else
__device__ __forceinline__ float fdot2a(h2 a, h2 b, float c){
  return c + (float)a[0]*(float)b[0] + (float)a[1]*(float)b[1];
}
#endif

// DPP row-rotate (within rows of 16 lanes) — VALU-pipe lane exchange.
// CTRL = 0x120 + n  (row_ror:n)
template<int CTRL>
__device__ __forceinline__ float dpp_rorf(float x){
  return __int_as_float(
      __builtin_amdgcn_update_dpp(0, __float_as_int(x), CTRL, 0xf, 0xf, false));
}

// ---------------- edge feature helper ----------------
__device__ __forceinline__ void edge_feat(const float* __restrict__ x,
                                          const float* __restrict__ he,
                                          const int* __restrict__ ei,
                                          int e, float* feat, int& sN, int& dN)
{
  sN = ei[e]; dN = ei[E_ + e];
  float dx = x[sN*3+0]-x[dN*3+0];
  float dy = x[sN*3+1]-x[dN*3+1];
  float dz = x[sN*3+2]-x[dN*3+2];
  float d2 = dx*dx + dy*dy + dz*dz;
  feat[0] = expf(-d2);
  feat[1] = expf(d2 * -0.1f);
  feat[2] = expf(d2 * -0.01f);
  feat[3] = expf(d2 * -0.001f);
  feat[4] = expf(d2 * -0.0001f);
#pragma unroll
  for (int j = 0; j < 27; ++j) feat[5+j] = he[(size_t)e*27 + j];
}

// ---------------- E1: per-column stats, fp16-packed dot2 core ----------------
__global__ __launch_bounds__(256)
void edge_stats_kernel(const float* __restrict__ xl, const float* __restrict__ xr,
                       const float* __restrict__ hel, const float* __restrict__ her,
                       const int* __restrict__ ei1, const int* __restrict__ ei2,
                       const float* __restrict__ w1, const float* __restrict__ b1,
                       float* __restrict__ ws)
{
  int side = blockIdx.y;
  const float* x  = side ? xr  : xl;
  const float* he = side ? her : hel;
  const int*   ei = side ? ei2 : ei1;
  float* stats = ws + (size_t)side*SS_ + STATS_OFF;
  __shared__ _Float16 featl[256][40];   // rows 80B (16B-aligned)
  __shared__ float csum[2][128], cssq[2][128];
  int tid = threadIdx.x;
  {
    int sN, dN; float feat[32];
    edge_feat(x, he, ei, blockIdx.x*256 + tid, feat, sN, dN);
    h2 tmp[16];
#pragma unroll
    for (int j = 0; j < 16; ++j) { tmp[j][0] = (_Float16)feat[2*j]; tmp[j][1] = (_Float16)feat[2*j+1]; }
#pragma unroll
    for (int q = 0; q < 4; ++q)
      *(float4*)&featl[tid][q*8] = ((const float4*)tmp)[q];
  }
  int c = tid & 127, hh = tid >> 7;
  h2 w1h[16];
#pragma unroll
  for (int j = 0; j < 16; ++j) {
    w1h[j][0] = (_Float16)w1[(2*j)*128 + c];
    w1h[j][1] = (_Float16)w1[(2*j+1)*128 + c];
  }
  float b1c = b1[c];
  __syncthreads();
  float s1 = 0.f, s2 = 0.f;
  for (int e = 0; e < 128; ++e) {
    const h2* fh = (const h2*)&featl[hh*128 + e][0];
    float a0 = 0.f, a1 = 0.f, a2 = 0.f, a3 = 0.f;
#pragma unroll
    for (int q = 0; q < 4; ++q) {
      a0 = fdot2a(fh[q*4+0], w1h[q*4+0], a0);
      a1 = fdot2a(fh[q*4+1], w1h[q*4+1], a1);
      a2 = fdot2a(fh[q*4+2], w1h[q*4+2], a2);
      a3 = fdot2a(fh[q*4+3], w1h[q*4+3], a3);
    }
    float t = leakyf(b1c + ((a0+a1) + (a2+a3)));
    s1 += t; s2 += t*t;
  }
  csum[hh][c] = s1; cssq[hh][c] = s2;
  __syncthreads();
  if (tid < 128) {
    atomicAdd(&stats[tid],     csum[0][tid] + csum[1][tid]);
    atomicAdd(&stats[128+tid], cssq[0][tid] + cssq[1][tid]);
  }
}

// ---------------- E2: finalize edge bn folded with emlp_w2 -> alpha,beta ----------------
__global__ void edge_finalize_kernel(const float* __restrict__ g_, const float* __restrict__ b_,
                                     const float* __restrict__ w2, const float* __restrict__ b2,
                                     float* __restrict__ ws)
{
  int side = blockIdx.y;
  float* stats = ws + (size_t)side*SS_ + STATS_OFF;
  __shared__ float red[128];
  int c = threadIdx.x;  // 128 threads
  const float invE = 1.f/(float)E_;
  float mean = stats[c]*invE;
  float var  = fmaxf(stats[128+c]*invE - mean*mean, 0.f);
  float scale = rsqrtf(var + 1e-5f) * g_[c];
  stats[256+c] = scale * w2[c];
  red[c] = (b_[c] - mean*scale) * w2[c];
  __syncthreads();
  for (int off = 64; off; off >>= 1) { if (c < off) red[c] += red[c+off]; __syncthreads(); }
  if (c == 0) stats[384] = red[0] + b2[0];
}

// ---------------- E3: w_e, fp16-packed dot2 core ----------------
__global__ __launch_bounds__(256)
void edge_w_kernel(const float* __restrict__ xl, const float* __restrict__ xr,
                   const float* __restrict__ hel, const float* __restrict__ her,
                   const int* __restrict__ ei1, const int* __restrict__ ei2,
                   const float* __restrict__ w1, const float* __restrict__ b1,
                   float* __restrict__ ws)
{
  int side = blockIdx.y;
  const float* x  = side ? xr  : xl;
  const float* he = side ? her : hel;
  const int*   ei = side ? ei2 : ei1;
  float* base = ws + (size_t)side*SS_;
  const float* stats = base + STATS_OFF;
  float* wbuf = base + W_OFF;
  float* deg  = base + DEG_OFF;
  __shared__ _Float16 w1t[128][32];     // rows 64B (16B-aligned), 8KB
  __shared__ float b1l[128], all_[128];
  int tid = threadIdx.x;
  for (int i = tid; i < 4096; i += 256) {
    int j = i & 31, c = i >> 5;
    w1t[c][j] = (_Float16)w1[j*128 + c];
  }
  if (tid < 128) { b1l[tid] = b1[tid]; all_[tid] = stats[256+tid]; }
  __syncthreads();
  int e = blockIdx.x*256 + tid;
  int sN, dN; float feat[32];
  edge_feat(x, he, ei, e, feat, sN, dN);
  h2 fh[16];
#pragma unroll
  for (int j = 0; j < 16; ++j) { fh[j][0] = (_Float16)feat[2*j]; fh[j][1] = (_Float16)feat[2*j+1]; }
  float accw = stats[384];
  for (int c = 0; c < 128; ++c) {
    const h2* wc = (const h2*)&w1t[c][0];
    float a0 = 0.f, a1 = 0.f, a2 = 0.f, a3 = 0.f;
#pragma unroll
    for (int q = 0; q < 4; ++q) {
      a0 = fdot2a(fh[q*4+0], wc[q*4+0], a0);
      a1 = fdot2a(fh[q*4+1], wc[q*4+1], a1);
      a2 = fdot2a(fh[q*4+2], wc[q*4+2], a2);
      a3 = fdot2a(fh[q*4+3], wc[q*4+3], a3);
    }
    accw += leakyf(b1l[c] + ((a0+a1) + (a2+a3))) * all_[c];
  }
  float w = fmaxf(accw, 0.f);
  wbuf[e] = w;
  atomicAdd(&deg[sN], w);
}

// ---------------- Bernstein propagation via Horner (6 matmuls) ----------------
__global__ __launch_bounds__(256)
void bern_horner_kernel(const float* __restrict__ hl_in, const float* __restrict__ hr_in,
                        const int* __restrict__ ei1, const int* __restrict__ ei2,
                        const float* __restrict__ bern_temp, float* __restrict__ ws)
{
  int side = blockIdx.y;
  int g  = blockIdx.x >> 2;
  int d0 = (blockIdx.x & 3) * 32;
  const float* h  = side ? hr_in : hl_in;
  const int*   ei = side ? ei2 : ei1;
  float* base = ws + (size_t)side*SS_;
  const float* wbuf = base + W_OFF;
  const float* deg  = base + DEG_OFF;
  float* hloc = base + HL_OFF;

  __shared__ float A[128*132];
  __shared__ float v[128*32];
  int tid = threadIdx.x;
  for (int i = tid; i < 128*132; i += 256) A[i] = 0.f;

  const float btab[7][7] = {
    { 1,  6, 15,  20, 15,  6,  1},
    { 1,  4,  5,   0, -5, -4, -1},
    { 1,  2, -1,  -4, -1,  2,  1},
    { 1,  0, -3,   0,  3,  0, -1},
    { 1, -2, -1,   4, -1, -2,  1},
    { 1, -4,  5,   0, -5,  4, -1},
    { 1, -6, 15, -20, 15, -6,  1}};
  const float comb6[7] = {1,6,15,20,15,6,1};
  float a[7];
#pragma unroll
  for (int m = 0; m < 7; ++m) a[m] = 0.f;
#pragma unroll
  for (int j = 0; j < 7; ++j) {
    float tj = fmaxf(bern_temp[j], 0.f) * comb6[j] * (1.f/64.f);
#pragma unroll
    for (int m = 0; m < 7; ++m) a[m] += tj * btab[j][m];
  }
  __syncthreads();

  int ebase = g*2048, nbase = g*128;
  for (int i = tid; i < 2048; i += 256) {
    int e = ebase + i;
    int sN = ei[e], dN = ei[E_ + e];
    float ds_ = deg[sN], dd_ = deg[dN];
    float aa = ds_ > 0.f ? rsqrtf(ds_ + 1e-12f) : 0.f;
    float bb = dd_ > 0.f ? rsqrtf(dd_ + 1e-12f) : 0.f;
    atomicAdd(&A[(dN - nbase)*132 + (sN - nbase)], wbuf[e]*aa*bb);
  }

  const int db = (tid & 7)*4;
  const int rb = (tid >> 3)*4;
  float hreg[4][4], r[4][4], t[4][4];
#pragma unroll
  for (int i = 0; i < 4; ++i) {
    float4 h4 = *(const float4*)&h[(size_t)(nbase + rb + i)*128 + d0 + db];
    hreg[i][0]=h4.x; hreg[i][1]=h4.y; hreg[i][2]=h4.z; hreg[i][3]=h4.w;
#pragma unroll
    for (int jj = 0; jj < 4; ++jj) r[i][jj] = a[6]*hreg[i][jj];
  }

  for (int step = 5; step >= 0; --step) {
    __syncthreads();
#pragma unroll
    for (int i = 0; i < 4; ++i)
      *(float4*)&v[(rb+i)*32 + db] = make_float4(r[i][0], r[i][1], r[i][2], r[i][3]);
    __syncthreads();
#pragma unroll
    for (int i = 0; i < 4; ++i)
#pragma unroll
      for (int jj = 0; jj < 4; ++jj) t[i][jj] = 0.f;
    for (int k = 0; k < 128; k += 4) {
      float4 V0 = *(const float4*)&v[(k+0)*32 + db];
      float4 V1 = *(const float4*)&v[(k+1)*32 + db];
      float4 V2 = *(const float4*)&v[(k+2)*32 + db];
      float4 V3 = *(const float4*)&v[(k+3)*32 + db];
#pragma unroll
      for (int i = 0; i < 4; ++i) {
        float4 A4 = *(const float4*)&A[(rb+i)*132 + k];
        t[i][0] += A4.x*V0.x + A4.y*V1.x + A4.z*V2.x + A4.w*V3.x;
        t[i][1] += A4.x*V0.y + A4.y*V1.y + A4.z*V2.y + A4.w*V3.y;
        t[i][2] += A4.x*V0.z + A4.y*V1.z + A4.z*V2.z + A4.w*V3.z;
        t[i][3] += A4.x*V0.w + A4.y*V1.w + A4.z*V2.w + A4.w*V3.w;
      }
    }
    float ak = a[step];
#pragma unroll
    for (int i = 0; i < 4; ++i)
#pragma unroll
      for (int jj = 0; jj < 4; ++jj) r[i][jj] = t[i][jj] + ak*hreg[i][jj];
  }

#pragma unroll
  for (int i = 0; i < 4; ++i)
    *(float4*)&hloc[(size_t)(nbase + rb + i)*128 + d0 + db] =
        make_float4(r[i][0], r[i][1], r[i][2], r[i][3]);
}

// ---------------- generic f32 GEMM, col-split for occupancy, grid.y = side ----------------
template<int K, int NC, int TC, int CSPLIT, int ACT, int GATHER, int SCATTER, int ADDC, int BIAS>
__global__ __launch_bounds__(256)
void gemm_kernel(const float* __restrict__ A0, const float* __restrict__ A1, int lda,
                 const float* __restrict__ W, const float* __restrict__ bias,
                 float* __restrict__ C0, float* __restrict__ C1, int ldc,
                 const int* __restrict__ idx0, const int* __restrict__ idx1,
                 const float* __restrict__ add0, const float* __restrict__ add1)
{
  int side = blockIdx.y;
  const float* A = side ? A1 : A0;
  float* C = side ? C1 : C0;
  const int* idx = side ? idx1 : idx0;
  const float* addsrc = side ? add1 : add0;
  constexpr int RPT = TC/8;
  constexpr int CLEN = NC/CSPLIT;
  __shared__ float Alds[32][K];
  __shared__ float Wlds[K][TC];
  const int tid = threadIdx.x;
  const int r0 = (blockIdx.x / CSPLIT) * 32;
  const int cbase = (blockIdx.x % CSPLIT) * CLEN;
  for (int i = tid*4; i < 32*K; i += 1024) {
    int r = i / K, k = i % K;
    int row = GATHER ? idx[r0 + r] : (r0 + r);
    *(float4*)&Alds[r][k] = *(const float4*)&A[(size_t)row*lda + k];
  }
  for (int c0 = cbase; c0 < cbase + CLEN; c0 += TC) {
    __syncthreads();
    for (int i = tid*4; i < K*TC; i += 1024) {
      int k = i / TC, c = i % TC;
      if (c0 + c < NC) *(float4*)&Wlds[k][c] = *(const float4*)&W[k*NC + c0 + c];
      else             *(float4*)&Wlds[k][c] = make_float4(0.f,0.f,0.f,0.f);
    }
    __syncthreads();
    const int cl = tid % TC;
    const int rsub = (tid / TC) * RPT;
    float accv[RPT];
#pragma unroll
    for (int j = 0; j < RPT; ++j) accv[j] = 0.f;
    for (int k = 0; k < K; k += 4) {
      float w0 = Wlds[k][cl], w1v = Wlds[k+1][cl], w2v = Wlds[k+2][cl], w3v = Wlds[k+3][cl];
#pragma unroll
      for (int j = 0; j < RPT; ++j) {
        float4 a4 = *(const float4*)&Alds[rsub+j][k];
        accv[j] += a4.x*w0 + a4.y*w1v + a4.z*w2v + a4.w*w3v;
      }
    }
    int c = c0 + cl;
    if (c < NC) {
#pragma unroll
      for (int j = 0; j < RPT; ++j) {
        int row  = r0 + rsub + j;
        int orow = SCATTER ? idx[row] : row;
        float vv = accv[j];
        if (BIAS)     vv += bias[c];
        if (ACT == 1) vv = leakyf(vv);
        if (ACT == 2) vv = fmaxf(vv, 0.f);
        if (ADDC)     vv += addsrc[(size_t)orow*ldc + c];
        C[(size_t)orow*ldc + c] = vv;
      }
    }
  }
}

// ---------------- qkv: 3 projections in one dispatch; bn1 fused into A-staging ----------
__global__ __launch_bounds__(256)
void qkv_kernel(const float* __restrict__ qw, const float* __restrict__ kw,
                const float* __restrict__ vw, float* __restrict__ ws)
{
  int side = blockIdx.y;
  int mat  = blockIdx.z;
  float* base = ws + (size_t)side*SS_;
  const float* A = base + X1_OFF;                 // pre-bn1 x1
  const float* bns = base + STATS_OFF + 512;      // bn1: scale at +256, shift at +384
  const float* W = mat == 0 ? qw : (mat == 1 ? kw : vw);
  float* C = base + (mat == 0 ? XC_OFF : (mat == 1 ? DTB_OFF : YB_OFF));
  __shared__ float Alds[32][128];
  __shared__ float Wlds[128][64];
  const int tid = threadIdx.x;
  const int r0 = (blockIdx.x >> 1) * 32;
  const int c0 = (blockIdx.x & 1) * 64;
  for (int i = tid*4; i < 32*128; i += 1024) {
    int k = i & 127;
    float4 a4 = *(const float4*)&A[(size_t)(r0 + (i>>7))*128 + k];
    float4 sc = *(const float4*)&bns[256 + k];
    float4 sh = *(const float4*)&bns[384 + k];
    a4.x = a4.x*sc.x + sh.x;
    a4.y = a4.y*sc.y + sh.y;
    a4.z = a4.z*sc.z + sh.z;
    a4.w = a4.w*sc.w + sh.w;
    *(float4*)&Alds[i>>7][k] = a4;
  }
  for (int i = tid*4; i < 128*64; i += 1024)
    *(float4*)&Wlds[i>>6][i&63] = *(const float4*)&W[(i>>6)*128 + c0 + (i&63)];
  __syncthreads();
  const int cl = tid & 63;
  const int rsub = (tid >> 6) * 8;
  float accv[8];
#pragma unroll
  for (int j = 0; j < 8; ++j) accv[j] = 0.f;
  for (int k = 0; k < 128; k += 4) {
    float w0 = Wlds[k][cl], w1v = Wlds[k+1][cl], w2v = Wlds[k+2][cl], w3v = Wlds[k+3][cl];
#pragma unroll
    for (int j = 0; j < 8; ++j) {
      float4 a4 = *(const float4*)&Alds[rsub+j][k];
      accv[j] += a4.x*w0 + a4.y*w1v + a4.z*w2v + a4.w*w3v;
    }
  }
#pragma unroll
  for (int j = 0; j < 8; ++j) {
    float vv = accv[j];
    if (mat < 2) vv = leakyf(vv);
    C[(size_t)(r0 + rsub + j)*128 + c0 + cl] = vv;
  }
}

// ---------------- mamba: causal depthwise conv (DCONV=4) + silu ----------------
__global__ __launch_bounds__(256)
void conv_kernel(const float* __restrict__ cw, const float* __restrict__ cb, float* __restrict__ ws)
{
  int side = blockIdx.y;
  float* base = ws + (size_t)side*SS_;
  const float* xz = base + XZ_OFF;
  float* xc = base + XC_OFF;
  int i = blockIdx.x*256 + threadIdx.x;
  int j = i >> 7, d = i & 127;
  int l = j & 127;
  float a = cb[d];
#pragma unroll
  for (int k = 0; k < 4; ++k) {
    int ll = l - 3 + k;
    if (ll >= 0) a += xz[(size_t)(j-3+k)*256 + d] * cw[d*4 + k];
  }
  xc[i] = siluf(a);
}

// ---------------- mamba scan: fused dt(softplus) + 128-step recurrence + gate ----------------
// Per-step 16-lane reduce now uses DPP row_ror (VALU) instead of 4 dependent
// ds_swizzle shuffles: v+=ror8; v+=ror4; v+=ror2; v+=ror1 leaves the full row
// sum in every lane of the 16-lane group.
__global__ __launch_bounds__(256)
void scan_kernel(const float* __restrict__ A_log, const float* __restrict__ Dp,
                 const float* __restrict__ dtw, const float* __restrict__ dtbias,
                 float* __restrict__ ws)
{
  int side = blockIdx.z;
  int g  = blockIdx.x;
  int d0 = blockIdx.y * 16;
  float* base = ws + (size_t)side*SS_;
  const float* dbl = base + DBL_OFF;
  const float* xcb = base + XC_OFF;
  float* xz = base + XZ_OFF;

  __shared__ float ldbl[128][40];   // dt-in(8) | B(16) | C(16)
  __shared__ float lxc[128][16];
  __shared__ float ldt[128][16];
  __shared__ float lz[128][16];
  __shared__ float ly[128][16];
  __shared__ float ltw[8][16];
  __shared__ float ltb[16];

  int tid = threadIdx.x;
  int rowbase = g*128;
  if (tid < 128)      ltw[tid>>4][tid&15] = dtw[(tid>>4)*128 + d0 + (tid&15)];
  else if (tid < 144) ltb[tid-128] = dtbias[d0 + (tid-128)];
  for (int i = tid; i < 128*40; i += 256)
    ((float*)ldbl)[i] = dbl[(size_t)rowbase*40 + i];
  for (int i = tid; i < 2048; i += 256) {
    int l = i >> 4, dd = i & 15;
    lxc[l][dd] = xcb[(size_t)(rowbase+l)*128 + d0 + dd];
    lz[l][dd]  = xz[(size_t)(rowbase+l)*256 + 128 + d0 + dd];
  }
  __syncthreads();
  // dt = softplus(dbl[:, :8] @ dtw + dtb)  — once per (l,d)
  for (int i = tid; i < 2048; i += 256) {
    int l = i >> 4, dd = i & 15;
    float a = ltb[dd];
#pragma unroll
    for (int k = 0; k < 8; ++k) a += ldbl[l][k]*ltw[k][dd];
    ldt[l][dd] = a > 20.f ? a : log1pf(expf(a));
  }
  __syncthreads();

  int s = tid & 15, dl = (tid >> 4) & 15;
  float Ac  = -expf(A_log[(d0+dl)*16 + s]);
  float dpv = Dp[d0+dl];
  float hsv = 0.f;
  for (int l = 0; l < 128; ++l) {
    float dtv = ldt[l][dl];      // broadcast across s
    float xcv = lxc[l][dl];
    float Bv  = ldbl[l][8+s];
    float Cv  = ldbl[l][24+s];
    hsv = expf(dtv*Ac)*hsv + (dtv*xcv)*Bv;
    float val = hsv*Cv;
    val += dpp_rorf<0x128>(val);   // row_ror:8
    val += dpp_rorf<0x124>(val);   // row_ror:4
    val += dpp_rorf<0x122>(val);   // row_ror:2
    val += dpp_rorf<0x121>(val);   // row_ror:1
    if (s == 0) ly[l][dl] = val + xcv*dpv;
  }
  __syncthreads();
  // gate: xz[:, :128] = y * silu(z)
  for (int i = tid; i < 2048; i += 256) {
    int l = i >> 4, dd = i & 15;
    float y = ly[l][dd];
    float z = lz[l][dd];
    xz[(size_t)(rowbase+l)*256 + d0 + dd] = y * siluf(z);
  }
}

// ---------------- column stats ----------------
__global__ __launch_bounds__(256)
void stats_kernel(const float* __restrict__ hl_in, const float* __restrict__ hr_in,
                  float* __restrict__ ws, int mode, int statsoff)
{
  int side = blockIdx.y;
  float* base = ws + (size_t)side*SS_;
  const float* h    = side ? hr_in : hl_in;
  const float* hloc = base + HL_OFF;
  const float* ha   = base + HA_OFF;
  float* x1 = base + X1_OFF;
  float* stats = base + STATS_OFF + statsoff;
  int tid = threadIdx.x;
  int c = tid & 127;
  float s1 = 0.f, s2 = 0.f;
  for (int it = 0; it < 16; ++it) {
    int r = blockIdx.x*32 + (tid >> 7) + it*2;
    size_t i = (size_t)r*128 + c;
    float v;
    if (mode == 0) { v = h[i] + hloc[i] + ha[i]; x1[i] = v; }
    else           { v = ha[i]; }
    s1 += v; s2 += v*v;
  }
  __shared__ float red[256];
  red[tid] = s1; __syncthreads();
  if (tid < 128) atomicAdd(&stats[tid], red[tid] + red[tid+128]);
  __syncthreads();
  red[tid] = s2; __syncthreads();
  if (tid < 128) atomicAdd(&stats[128+tid], red[tid] + red[tid+128]);
}

__global__ void bn_finalize_kernel(const float* __restrict__ g_, const float* __restrict__ b_,
                                   float* __restrict__ ws, int statsoff, float invM)
{
  int side = blockIdx.y;
  float* stats = ws + (size_t)side*SS_ + STATS_OFF + statsoff;
  int c = threadIdx.x;   // 128 threads
  float mean = stats[c]*invM;
  float var  = fmaxf(stats[128+c]*invM - mean*mean, 0.f);
  float scale = rsqrtf(var + 1e-5f) * g_[c];
  stats[256+c] = scale;
  stats[384+c] = b_[c] - mean*scale;
}

__global__ __launch_bounds__(256)
void bn_apply_kernel(float* __restrict__ ws, float* __restrict__ dout,
                     int srcoff, int dstoff, int statsoff, int to_dout)
{
  int side = blockIdx.y;
  float* base = ws + (size_t)side*SS_;
  const float* src = base + srcoff;
  const float* stats = base + STATS_OFF + statsoff;
  float* dst = to_dout ? (dout + (size_t)side*ND_) : (base + dstoff);
  size_t i = (size_t)blockIdx.x*256 + threadIdx.x;
  int c = (int)(i & 127);
  dst[i] = src[i]*stats[256+c] + stats[384+c];
}

// ---------------- cross attention (register-tiled); bn1 fused on residual read ------
__global__ __launch_bounds__(256)
void attn_kernel(float* __restrict__ ws)
{
  int dir = blockIdx.z;
  int g   = blockIdx.x;
  int rt  = blockIdx.y;
  float* baseq = ws + (size_t)dir*SS_;
  float* basek = ws + (size_t)(1-dir)*SS_;
  const float* qb = baseq + XC_OFF;
  const float* kb = basek + DTB_OFF;
  const float* vb = basek + YB_OFF;
  const float* x1b = baseq + X1_OFF;            // pre-bn1 x1 (hm = bn(x1))
  const float* bns = baseq + STATS_OFF + 512;   // bn1 scale/shift
  float* h2v = baseq + X1_OFF;                  // overwritten in place (same offsets)

  __shared__ float KT[128][132];   // phase A: K^T as [d][n]; phase C: V as [n][d]
  __shared__ float Qs[32][132];    // Q tile
  __shared__ float sp[32][132];    // unnormalized P tile

  const int tid = threadIdx.x;
  const int cl  = tid & 31;          // 32 col-lanes
  const int r0  = (tid >> 5) * 4;    // 8 row-groups * 4 rows = 32 rows
  const int c0  = cl * 4;            // 4 cols per thread (128 total)
  const int rowg = g*128 + rt*32;

  // ---- stage Q tile (32 x 128) ----
  {
    const float* qsrc = qb + (size_t)rowg*128;
    for (int i = tid; i < 32*32; i += 256) {
      int r = i >> 5, d4 = i & 31;
      *(float4*)&Qs[r][d4*4] = *(const float4*)&qsrc[(size_t)r*128 + d4*4];
    }
  }
  // ---- stage K^T (transpose 128x128) ----
  {
    const float* ksrc = kb + (size_t)(g*128)*128;
    for (int i = tid; i < 128*32; i += 256) {
      int d4 = i >> 7, n = i & 127;
      float4 k4 = *(const float4*)&ksrc[(size_t)n*128 + d4*4];
      KT[d4*4+0][n] = k4.x;
      KT[d4*4+1][n] = k4.y;
      KT[d4*4+2][n] = k4.z;
      KT[d4*4+3][n] = k4.w;
    }
  }
  __syncthreads();

  // ---- phase A: scores, 4 rows x 4 cols per thread ----
  float acc[4][4];
#pragma unroll
  for (int i = 0; i < 4; ++i)
#pragma unroll
    for (int j = 0; j < 4; ++j) acc[i][j] = 0.f;

  for (int d = 0; d < 128; d += 4) {
    float4 k0 = *(const float4*)&KT[d+0][c0];
    float4 k1 = *(const float4*)&KT[d+1][c0];
    float4 k2 = *(const float4*)&KT[d+2][c0];
    float4 k3 = *(const float4*)&KT[d+3][c0];
#pragma unroll
    for (int i = 0; i < 4; ++i) {
      float4 q4 = *(const float4*)&Qs[r0+i][d];
      acc[i][0] += q4.x*k0.x + q4.y*k1.x + q4.z*k2.x + q4.w*k3.x;
      acc[i][1] += q4.x*k0.y + q4.y*k1.y + q4.z*k2.y + q4.w*k3.y;
      acc[i][2] += q4.x*k0.z + q4.y*k1.z + q4.z*k2.z + q4.w*k3.z;
      acc[i][3] += q4.x*k0.w + q4.y*k1.w + q4.z*k2.w + q4.w*k3.w;
    }
  }

  // ---- softmax in registers; store unnormalized P; keep 1/sum per row ----
  float inv[4];
#pragma unroll
  for (int i = 0; i < 4; ++i) {
    float m = fmaxf(fmaxf(acc[i][0], acc[i][1]), fmaxf(acc[i][2], acc[i][3]));
#pragma unroll
    for (int off = 1; off < 32; off <<= 1) m = fmaxf(m, __shfl_xor(m, off, 32));
    float p0 = expf(acc[i][0]-m), p1 = expf(acc[i][1]-m);
    float p2 = expf(acc[i][2]-m), p3 = expf(acc[i][3]-m);
    float s = p0 + p1 + p2 + p3;
#pragma unroll
    for (int off = 1; off < 32; off <<= 1) s += __shfl_xor(s, off, 32);
    inv[i] = 1.f/s;
    *(float4*)&sp[r0+i][c0] = make_float4(p0, p1, p2, p3);
  }
  __syncthreads();

  // ---- stage V (natural [n][d], coalesced, float4 writes) ----
  {
    const float* vsrc = vb + (size_t)(g*128)*128;
    for (int i = tid; i < 128*32; i += 256) {
      int n = i >> 5, d4 = i & 31;
      *(float4*)&KT[n][d4*4] = *(const float4*)&vsrc[(size_t)n*128 + d4*4];
    }
  }
  __syncthreads();

  // ---- phase C: O = P @ V, 4 rows x 4 d-cols per thread ----
  float o[4][4];
#pragma unroll
  for (int i = 0; i < 4; ++i)
#pragma unroll
    for (int j = 0; j < 4; ++j) o[i][j] = 0.f;

  for (int n = 0; n < 128; n += 4) {
    float4 v0 = *(const float4*)&KT[n+0][c0];
    float4 v1 = *(const float4*)&KT[n+1][c0];
    float4 v2 = *(const float4*)&KT[n+2][c0];
    float4 v3 = *(const float4*)&KT[n+3][c0];
#pragma unroll
    for (int i = 0; i < 4; ++i) {
      float4 p4 = *(const float4*)&sp[r0+i][n];
      o[i][0] += p4.x*v0.x + p4.y*v1.x + p4.z*v2.x + p4.w*v3.x;
      o[i][1] += p4.x*v0.y + p4.y*v1.y + p4.z*v2.y + p4.w*v3.y;
      o[i][2] += p4.x*v0.z + p4.y*v1.z + p4.z*v2.z + p4.w*v3.z;
      o[i][3] += p4.x*v0.w + p4.y*v1.w + p4.z*v2.w + p4.w*v3.w;
    }
  }

  // ---- epilogue: h2 = bn1(x1) + O/sum (bn fused; read-before-write, same offsets) ----
  float4 sc = *(const float4*)&bns[256 + c0];
  float4 sh = *(const float4*)&bns[384 + c0];
#pragma unroll
  for (int i = 0; i < 4; ++i) {
    size_t off = (size_t)(rowg + r0 + i)*128 + c0;
    float4 xv = *(const float4*)&x1b[off];
    float4 r4;
    r4.x = xv.x*sc.x + sh.x + o[i][0]*inv[i];
    r4.y = xv.y*sc.y + sh.y + o[i][1]*inv[i];
    r4.z = xv.z*sc.z + sh.z + o[i][2]*inv[i];
    r4.w = xv.w*sc.w + sh.w + o[i][3]*inv[i];
    *(float4*)&h2v[off] = r4;
  }
}

// ---------------- launch ----------------
extern "C" void kernel_launch(void* const* d_in, const int* in_sizes, int n_in,
                              void* d_out, int out_size, void* d_ws, size_t ws_size,
                              hipStream_t stream)
{
  const float* h_lig     = (const float*)d_in[0];
  const float* h_rec     = (const float*)d_in[1];
  const float* x_lig     = (const float*)d_in[2];
  const float* x_rec     = (const float*)d_in[3];
  const float* he_1      = (const float*)d_in[4];
  const float* he_2      = (const float*)d_in[5];
  const float* emlp_w1   = (const float*)d_in[6];
  const float* emlp_b1   = (const float*)d_in[7];
  const float* emlp_bn_g = (const float*)d_in[8];
  const float* emlp_bn_b = (const float*)d_in[9];
  const float* emlp_w2   = (const float*)d_in[10];
  const float* emlp_b2   = (const float*)d_in[11];
  const float* bern_temp = (const float*)d_in[12];
  const float* m_in_w    = (const float*)d_in[13];
  const float* m_conv_w  = (const float*)d_in[14];
  const float* m_conv_b  = (const float*)d_in[15];
  const float* m_xproj_w = (const float*)d_in[16];
  const float* m_dt_w    = (const float*)d_in[17];
  const float* m_dt_b    = (const float*)d_in[18];
  const float* m_A_log   = (const float*)d_in[19];
  const float* m_D       = (const float*)d_in[20];
  const float* m_out_w   = (const float*)d_in[21];
  const float* q_w       = (const float*)d_in[22];
  const float* k_w       = (const float*)d_in[23];
  const float* v_w       = (const float*)d_in[24];
  const float* bn1_g     = (const float*)d_in[25];
  const float* bn1_b     = (const float*)d_in[26];
  const float* bn2_g     = (const float*)d_in[27];
  const float* bn2_b     = (const float*)d_in[28];
  const float* ff_w1     = (const float*)d_in[29];
  const float* ff_b1     = (const float*)d_in[30];
  const float* ff_w2     = (const float*)d_in[31];
  const float* ff_b2     = (const float*)d_in[32];
  const int*   ei1       = (const int*)d_in[33];
  const int*   ei2       = (const int*)d_in[34];
  const int*   perm1     = (const int*)d_in[37];
  const int*   perm2     = (const int*)d_in[38];

  float* ws   = (float*)d_ws;
  float* dout = (float*)d_out;

#define B0(off) (ws + (size_t)(off))
#define B1(off) (ws + SS_ + (size_t)(off))

  for (int s = 0; s < 2; ++s)
    hipMemsetAsync((char*)d_ws + ((size_t)s*SS_ + DEG_OFF)*sizeof(float), 0,
                   (N_ + 2048)*sizeof(float), stream);

  // edge weights (champion structure, fp16-packed dot2 core)
  edge_stats_kernel<<<dim3(256,2), 256, 0, stream>>>(x_lig,x_rec,he_1,he_2,ei1,ei2,emlp_w1,emlp_b1,ws);
  edge_finalize_kernel<<<dim3(1,2), 128, 0, stream>>>(emlp_bn_g,emlp_bn_b,emlp_w2,emlp_b2,ws);
  edge_w_kernel<<<dim3(256,2), 256, 0, stream>>>(x_lig,x_rec,he_1,he_2,ei1,ei2,emlp_w1,emlp_b1,ws);

  // bernstein propagation (Horner, 6 matmuls)
  bern_horner_kernel<<<dim3(G_*4,2), 256, 0, stream>>>(h_lig,h_rec,ei1,ei2,bern_temp,ws);

  // mamba
  gemm_kernel<128,256,64,4,0,1,0,0,0><<<dim3(512,2),256,0,stream>>>(
      h_lig,h_rec,128, m_in_w,nullptr, B0(XZ_OFF),B1(XZ_OFF),256, perm1,perm2, nullptr,nullptr);
  conv_kernel<<<dim3(2048,2), 256, 0, stream>>>(m_conv_w,m_conv_b,ws);
  gemm_kernel<128,40,64,1,0,0,0,0,0><<<dim3(128,2),256,0,stream>>>(
      B0(XC_OFF),B1(XC_OFF),128, m_xproj_w,nullptr, B0(DBL_OFF),B1(DBL_OFF),40, nullptr,nullptr, nullptr,nullptr);
  scan_kernel<<<dim3(32,8,2), 256, 0, stream>>>(m_A_log,m_D,m_dt_w,m_dt_b,ws);
  gemm_kernel<128,128,64,2,0,0,1,0,0><<<dim3(256,2),256,0,stream>>>(
      B0(XZ_OFF),B1(XZ_OFF),256, m_out_w,nullptr, B0(HA_OFF),B1(HA_OFF),128, perm1,perm2, nullptr,nullptr);

  // bn1 stats ( h + h_local + ha ); bn1 APPLY is fused into qkv + attn
  stats_kernel<<<dim3(128,2), 256, 0, stream>>>(h_lig,h_rec,ws,0,512);
  bn_finalize_kernel<<<dim3(1,2), 128, 0, stream>>>(bn1_g,bn1_b,ws,512,1.f/(float)N_);

  // q,k,v projections (bn1 fused in A-staging)
  qkv_kernel<<<dim3(256,2,3), 256, 0, stream>>>(q_w,k_w,v_w,ws);
  attn_kernel<<<dim3(32,4,2), 256, 0, stream>>>(ws);

  // ffn + bn2
  gemm_kernel<128,256,64,4,2,0,0,0,1><<<dim3(512,2),256,0,stream>>>(
      B0(X1_OFF),B1(X1_OFF),128, ff_w1,ff_b1, B0(XZ_OFF),B1(XZ_OFF),256, nullptr,nullptr, nullptr,nullptr);
  gemm_kernel<256,128,32,4,0,0,0,1,1><<<dim3(512,2),256,0,stream>>>(
      B0(XZ_OFF),B1(XZ_OFF),256, ff_w2,ff_b2, B0(HA_OFF),B1(HA_OFF),128, nullptr,nullptr, B0(X1_OFF),B1(X1_OFF));
  stats_kernel<<<dim3(128,2), 256, 0, stream>>>(h_lig,h_rec,ws,1,1024);
  bn_finalize_kernel<<<dim3(1,2), 128, 0, stream>>>(bn2_g,bn2_b,ws,1024,1.f/(float)N_);
  bn_apply_kernel<<<dim3(2048,2), 256, 0, stream>>>(ws,dout,HA_OFF,0,1024,1);
}

// Round 16
// 413.128 us; speedup vs baseline: 1.3854x; 1.0021x over previous
//
#include <hip/hip_runtime.h>
#include <math.h>

// ---------------- problem constants ----------------
#define G_    32
#define NPG_  128
#define D_    128
#define N_    4096          // G_*NPG_
#define E_    65536
#define ND_   (N_*D_)       // 524288

// ---------------- workspace layout (float offsets, per side) ----------------
#define W_OFF     0                     // E_ edge weights w
#define DEG_OFF   65536                 // N_ degrees (atomic, zeroed)
#define STATS_OFF 69632                 // 2048 floats of stats (zeroed):
//   [0:128) edge colsum  [128:256) edge colsumsq [256:384) alpha [384] beta
//   [512..1024) bn1: sum/ssq/scale/shift   [1024..1536) bn2: same
#define BUF0      71680
#define HL_OFF    (BUF0 + 0*ND_)        // h_local (bern output)
#define HA_OFF    (BUF0 + 1*ND_)        // mamba out (scattered); later x2
#define X1_OFF    (BUF0 + 2*ND_)        // pre-bn1 sum; later h2 (post-attn)
#define HMID_OFF  (BUF0 + 3*ND_)        // (unused since bn1 is fused into qkv/attn)
#define XC_OFF    (BUF0 + 4*ND_)        // conv output; later q
#define DTB_OFF   (BUF0 + 5*ND_)        // k
#define YB_OFF    (BUF0 + 6*ND_)        // v
#define XZ_OFF    (BUF0 + 7*ND_)        // 2*ND_: [xq|z] per row (256); scan gate overwrites xq
#define DBL_OFF   (BUF0 + 9*ND_)        // N_*40
#define WT_OFF    (DBL_OFF + N_*40)     // (unused scratch, kept for layout stability)
#define SS_       ((size_t)(WT_OFF + 4096))

__device__ __forceinline__ float leakyf(float x){ return x >= 0.f ? x : 0.02f*x; }
__device__ __forceinline__ float siluf (float x){ return x / (1.f + expf(-x)); }

// packed fp16 pair + 2-way dot with fp32 accumulate
typedef _Float16 h2 __attribute__((ext_vector_type(2)));
#if __has_builtin(__builtin_amdgcn_fdot2)
__device__ __forceinline__ float fdot2a(h2 a, h2 b, float c){
  return __builtin_amdgcn_fdot2(a, b, c, false);
}
#else
__device__ __forceinline__ float fdot2a(h2 a, h2 b, float c){
  return c + (float)a[0]*(float)b[0] + (float)a[1]*(float)b[1];
}
#endif

// DPP row-rotate (within rows of 16 lanes) — VALU-pipe lane exchange.
// CTRL = 0x120 + n  (row_ror:n)
template<int CTRL>
__device__ __forceinline__ float dpp_rorf(float x){
  return __int_as_float(
      __builtin_amdgcn_update_dpp(0, __float_as_int(x), CTRL, 0xf, 0xf, false));
}

// ---------------- edge feature helper ----------------
__device__ __forceinline__ void edge_feat(const float* __restrict__ x,
                                          const float* __restrict__ he,
                                          const int* __restrict__ ei,
                                          int e, float* feat, int& sN, int& dN)
{
  sN = ei[e]; dN = ei[E_ + e];
  float dx = x[sN*3+0]-x[dN*3+0];
  float dy = x[sN*3+1]-x[dN*3+1];
  float dz = x[sN*3+2]-x[dN*3+2];
  float d2 = dx*dx + dy*dy + dz*dz;
  feat[0] = expf(-d2);
  feat[1] = expf(d2 * -0.1f);
  feat[2] = expf(d2 * -0.01f);
  feat[3] = expf(d2 * -0.001f);
  feat[4] = expf(d2 * -0.0001f);
#pragma unroll
  for (int j = 0; j < 27; ++j) feat[5+j] = he[(size_t)e*27 + j];
}

// ---------------- E1: per-column stats, fp16-packed dot2 core ----------------
__global__ __launch_bounds__(256)
void edge_stats_kernel(const float* __restrict__ xl, const float* __restrict__ xr,
                       const float* __restrict__ hel, const float* __restrict__ her,
                       const int* __restrict__ ei1, const int* __restrict__ ei2,
                       const float* __restrict__ w1, const float* __restrict__ b1,
                       float* __restrict__ ws)
{
  int side = blockIdx.y;
  const float* x  = side ? xr  : xl;
  const float* he = side ? her : hel;
  const int*   ei = side ? ei2 : ei1;
  float* stats = ws + (size_t)side*SS_ + STATS_OFF;
  __shared__ _Float16 featl[256][40];   // rows 80B (16B-aligned)
  __shared__ float csum[2][128], cssq[2][128];
  int tid = threadIdx.x;
  {
    int sN, dN; float feat[32];
    edge_feat(x, he, ei, blockIdx.x*256 + tid, feat, sN, dN);
    h2 tmp[16];
#pragma unroll
    for (int j = 0; j < 16; ++j) { tmp[j][0] = (_Float16)feat[2*j]; tmp[j][1] = (_Float16)feat[2*j+1]; }
#pragma unroll
    for (int q = 0; q < 4; ++q)
      *(float4*)&featl[tid][q*8] = ((const float4*)tmp)[q];
  }
  int c = tid & 127, hh = tid >> 7;
  h2 w1h[16];
#pragma unroll
  for (int j = 0; j < 16; ++j) {
    w1h[j][0] = (_Float16)w1[(2*j)*128 + c];
    w1h[j][1] = (_Float16)w1[(2*j+1)*128 + c];
  }
  float b1c = b1[c];
  __syncthreads();
  float s1 = 0.f, s2 = 0.f;
  for (int e = 0; e < 128; ++e) {
    const h2* fh = (const h2*)&featl[hh*128 + e][0];
    float a0 = 0.f, a1 = 0.f, a2 = 0.f, a3 = 0.f;
#pragma unroll
    for (int q = 0; q < 4; ++q) {
      a0 = fdot2a(fh[q*4+0], w1h[q*4+0], a0);
      a1 = fdot2a(fh[q*4+1], w1h[q*4+1], a1);
      a2 = fdot2a(fh[q*4+2], w1h[q*4+2], a2);
      a3 = fdot2a(fh[q*4+3], w1h[q*4+3], a3);
    }
    float t = leakyf(b1c + ((a0+a1) + (a2+a3)));
    s1 += t; s2 += t*t;
  }
  csum[hh][c] = s1; cssq[hh][c] = s2;
  __syncthreads();
  if (tid < 128) {
    atomicAdd(&stats[tid],     csum[0][tid] + csum[1][tid]);
    atomicAdd(&stats[128+tid], cssq[0][tid] + cssq[1][tid]);
  }
}

// ---------------- E2: finalize edge bn folded with emlp_w2 -> alpha,beta ----------------
__global__ void edge_finalize_kernel(const float* __restrict__ g_, const float* __restrict__ b_,
                                     const float* __restrict__ w2, const float* __restrict__ b2,
                                     float* __restrict__ ws)
{
  int side = blockIdx.y;
  float* stats = ws + (size_t)side*SS_ + STATS_OFF;
  __shared__ float red[128];
  int c = threadIdx.x;  // 128 threads
  const float invE = 1.f/(float)E_;
  float mean = stats[c]*invE;
  float var  = fmaxf(stats[128+c]*invE - mean*mean, 0.f);
  float scale = rsqrtf(var + 1e-5f) * g_[c];
  stats[256+c] = scale * w2[c];
  red[c] = (b_[c] - mean*scale) * w2[c];
  __syncthreads();
  for (int off = 64; off; off >>= 1) { if (c < off) red[c] += red[c+off]; __syncthreads(); }
  if (c == 0) stats[384] = red[0] + b2[0];
}

// ---------------- E3: w_e, fp16-packed dot2 core ----------------
__global__ __launch_bounds__(256)
void edge_w_kernel(const float* __restrict__ xl, const float* __restrict__ xr,
                   const float* __restrict__ hel, const float* __restrict__ her,
                   const int* __restrict__ ei1, const int* __restrict__ ei2,
                   const float* __restrict__ w1, const float* __restrict__ b1,
                   float* __restrict__ ws)
{
  int side = blockIdx.y;
  const float* x  = side ? xr  : xl;
  const float* he = side ? her : hel;
  const int*   ei = side ? ei2 : ei1;
  float* base = ws + (size_t)side*SS_;
  const float* stats = base + STATS_OFF;
  float* wbuf = base + W_OFF;
  float* deg  = base + DEG_OFF;
  __shared__ _Float16 w1t[128][32];     // rows 64B (16B-aligned), 8KB
  __shared__ float b1l[128], all_[128];
  int tid = threadIdx.x;
  for (int i = tid; i < 4096; i += 256) {
    int j = i & 31, c = i >> 5;
    w1t[c][j] = (_Float16)w1[j*128 + c];
  }
  if (tid < 128) { b1l[tid] = b1[tid]; all_[tid] = stats[256+tid]; }
  __syncthreads();
  int e = blockIdx.x*256 + tid;
  int sN, dN; float feat[32];
  edge_feat(x, he, ei, e, feat, sN, dN);
  h2 fh[16];
#pragma unroll
  for (int j = 0; j < 16; ++j) { fh[j][0] = (_Float16)feat[2*j]; fh[j][1] = (_Float16)feat[2*j+1]; }
  float accw = stats[384];
  for (int c = 0; c < 128; ++c) {
    const h2* wc = (const h2*)&w1t[c][0];
    float a0 = 0.f, a1 = 0.f, a2 = 0.f, a3 = 0.f;
#pragma unroll
    for (int q = 0; q < 4; ++q) {
      a0 = fdot2a(fh[q*4+0], wc[q*4+0], a0);
      a1 = fdot2a(fh[q*4+1], wc[q*4+1], a1);
      a2 = fdot2a(fh[q*4+2], wc[q*4+2], a2);
      a3 = fdot2a(fh[q*4+3], wc[q*4+3], a3);
    }
    accw += leakyf(b1l[c] + ((a0+a1) + (a2+a3))) * all_[c];
  }
  float w = fmaxf(accw, 0.f);
  wbuf[e] = w;
  atomicAdd(&deg[sN], w);
}

// ---------------- Bernstein propagation via Horner (6 matmuls) ----------------
__global__ __launch_bounds__(256)
void bern_horner_kernel(const float* __restrict__ hl_in, const float* __restrict__ hr_in,
                        const int* __restrict__ ei1, const int* __restrict__ ei2,
                        const float* __restrict__ bern_temp, float* __restrict__ ws)
{
  int side = blockIdx.y;
  int g  = blockIdx.x >> 2;
  int d0 = (blockIdx.x & 3) * 32;
  const float* h  = side ? hr_in : hl_in;
  const int*   ei = side ? ei2 : ei1;
  float* base = ws + (size_t)side*SS_;
  const float* wbuf = base + W_OFF;
  const float* deg  = base + DEG_OFF;
  float* hloc = base + HL_OFF;

  __shared__ float A[128*132];
  __shared__ float v[128*32];
  int tid = threadIdx.x;
  for (int i = tid; i < 128*132; i += 256) A[i] = 0.f;

  const float btab[7][7] = {
    { 1,  6, 15,  20, 15,  6,  1},
    { 1,  4,  5,   0, -5, -4, -1},
    { 1,  2, -1,  -4, -1,  2,  1},
    { 1,  0, -3,   0,  3,  0, -1},
    { 1, -2, -1,   4, -1, -2,  1},
    { 1, -4,  5,   0, -5,  4, -1},
    { 1, -6, 15, -20, 15, -6,  1}};
  const float comb6[7] = {1,6,15,20,15,6,1};
  float a[7];
#pragma unroll
  for (int m = 0; m < 7; ++m) a[m] = 0.f;
#pragma unroll
  for (int j = 0; j < 7; ++j) {
    float tj = fmaxf(bern_temp[j], 0.f) * comb6[j] * (1.f/64.f);
#pragma unroll
    for (int m = 0; m < 7; ++m) a[m] += tj * btab[j][m];
  }
  __syncthreads();

  int ebase = g*2048, nbase = g*128;
  for (int i = tid; i < 2048; i += 256) {
    int e = ebase + i;
    int sN = ei[e], dN = ei[E_ + e];
    float ds_ = deg[sN], dd_ = deg[dN];
    float aa = ds_ > 0.f ? rsqrtf(ds_ + 1e-12f) : 0.f;
    float bb = dd_ > 0.f ? rsqrtf(dd_ + 1e-12f) : 0.f;
    atomicAdd(&A[(dN - nbase)*132 + (sN - nbase)], wbuf[e]*aa*bb);
  }

  const int db = (tid & 7)*4;
  const int rb = (tid >> 3)*4;
  float hreg[4][4], r[4][4], t[4][4];
#pragma unroll
  for (int i = 0; i < 4; ++i) {
    float4 h4 = *(const float4*)&h[(size_t)(nbase + rb + i)*128 + d0 + db];
    hreg[i][0]=h4.x; hreg[i][1]=h4.y; hreg[i][2]=h4.z; hreg[i][3]=h4.w;
#pragma unroll
    for (int jj = 0; jj < 4; ++jj) r[i][jj] = a[6]*hreg[i][jj];
  }

  for (int step = 5; step >= 0; --step) {
    __syncthreads();
#pragma unroll
    for (int i = 0; i < 4; ++i)
      *(float4*)&v[(rb+i)*32 + db] = make_float4(r[i][0], r[i][1], r[i][2], r[i][3]);
    __syncthreads();
#pragma unroll
    for (int i = 0; i < 4; ++i)
#pragma unroll
      for (int jj = 0; jj < 4; ++jj) t[i][jj] = 0.f;
    for (int k = 0; k < 128; k += 4) {
      float4 V0 = *(const float4*)&v[(k+0)*32 + db];
      float4 V1 = *(const float4*)&v[(k+1)*32 + db];
      float4 V2 = *(const float4*)&v[(k+2)*32 + db];
      float4 V3 = *(const float4*)&v[(k+3)*32 + db];
#pragma unroll
      for (int i = 0; i < 4; ++i) {
        float4 A4 = *(const float4*)&A[(rb+i)*132 + k];
        t[i][0] += A4.x*V0.x + A4.y*V1.x + A4.z*V2.x + A4.w*V3.x;
        t[i][1] += A4.x*V0.y + A4.y*V1.y + A4.z*V2.y + A4.w*V3.y;
        t[i][2] += A4.x*V0.z + A4.y*V1.z + A4.z*V2.z + A4.w*V3.z;
        t[i][3] += A4.x*V0.w + A4.y*V1.w + A4.z*V2.w + A4.w*V3.w;
      }
    }
    float ak = a[step];
#pragma unroll
    for (int i = 0; i < 4; ++i)
#pragma unroll
      for (int jj = 0; jj < 4; ++jj) r[i][jj] = t[i][jj] + ak*hreg[i][jj];
  }

#pragma unroll
  for (int i = 0; i < 4; ++i)
    *(float4*)&hloc[(size_t)(nbase + rb + i)*128 + d0 + db] =
        make_float4(r[i][0], r[i][1], r[i][2], r[i][3]);
}

// ---------------- generic f32 GEMM, col-split for occupancy, grid.y = side ----------------
// STATS=1 (requires CLEN==TC): epilogue accumulates per-column sum/ssq of the
// written outputs into st{0,1}[c] / st{0,1}[128+c] via LDS pre-reduce + atomics.
template<int K, int NC, int TC, int CSPLIT, int ACT, int GATHER, int SCATTER, int ADDC, int BIAS, int STATS = 0>
__global__ __launch_bounds__(256)
void gemm_kernel(const float* __restrict__ A0, const float* __restrict__ A1, int lda,
                 const float* __restrict__ W, const float* __restrict__ bias,
                 float* __restrict__ C0, float* __restrict__ C1, int ldc,
                 const int* __restrict__ idx0, const int* __restrict__ idx1,
                 const float* __restrict__ add0, const float* __restrict__ add1,
                 float* __restrict__ st0, float* __restrict__ st1)
{
  int side = blockIdx.y;
  const float* A = side ? A1 : A0;
  float* C = side ? C1 : C0;
  const int* idx = side ? idx1 : idx0;
  const float* addsrc = side ? add1 : add0;
  constexpr int RPT = TC/8;
  constexpr int CLEN = NC/CSPLIT;
  __shared__ float Alds[32][K];
  __shared__ float Wlds[K][TC];
  __shared__ float sbuf[2*TC];
  const int tid = threadIdx.x;
  const int r0 = (blockIdx.x / CSPLIT) * 32;
  const int cbase = (blockIdx.x % CSPLIT) * CLEN;
  float ts1 = 0.f, ts2 = 0.f;
  for (int i = tid*4; i < 32*K; i += 1024) {
    int r = i / K, k = i % K;
    int row = GATHER ? idx[r0 + r] : (r0 + r);
    *(float4*)&Alds[r][k] = *(const float4*)&A[(size_t)row*lda + k];
  }
  for (int c0 = cbase; c0 < cbase + CLEN; c0 += TC) {
    __syncthreads();
    for (int i = tid*4; i < K*TC; i += 1024) {
      int k = i / TC, c = i % TC;
      if (c0 + c < NC) *(float4*)&Wlds[k][c] = *(const float4*)&W[k*NC + c0 + c];
      else             *(float4*)&Wlds[k][c] = make_float4(0.f,0.f,0.f,0.f);
    }
    __syncthreads();
    const int cl = tid % TC;
    const int rsub = (tid / TC) * RPT;
    float accv[RPT];
#pragma unroll
    for (int j = 0; j < RPT; ++j) accv[j] = 0.f;
    for (int k = 0; k < K; k += 4) {
      float w0 = Wlds[k][cl], w1v = Wlds[k+1][cl], w2v = Wlds[k+2][cl], w3v = Wlds[k+3][cl];
#pragma unroll
      for (int j = 0; j < RPT; ++j) {
        float4 a4 = *(const float4*)&Alds[rsub+j][k];
        accv[j] += a4.x*w0 + a4.y*w1v + a4.z*w2v + a4.w*w3v;
      }
    }
    int c = c0 + cl;
    if (c < NC) {
#pragma unroll
      for (int j = 0; j < RPT; ++j) {
        int row  = r0 + rsub + j;
        int orow = SCATTER ? idx[row] : row;
        float vv = accv[j];
        if (BIAS)     vv += bias[c];
        if (ACT == 1) vv = leakyf(vv);
        if (ACT == 2) vv = fmaxf(vv, 0.f);
        if (ADDC)     vv += addsrc[(size_t)orow*ldc + c];
        C[(size_t)orow*ldc + c] = vv;
        if (STATS) { ts1 += vv; ts2 += vv*vv; }
      }
    }
  }
  if (STATS) {
    float* st = side ? st1 : st0;
    int clx = tid % TC;
    __syncthreads();
    if (tid < 2*TC) sbuf[tid] = 0.f;
    __syncthreads();
    atomicAdd(&sbuf[clx],      ts1);
    atomicAdd(&sbuf[TC + clx], ts2);
    __syncthreads();
    if (tid < TC)            atomicAdd(&st[cbase + tid],            sbuf[tid]);
    else if (tid < 2*TC)     atomicAdd(&st[128 + cbase + (tid-TC)], sbuf[tid]);
  }
}

// ---------------- qkv: 3 projections in one dispatch; bn1 fused into A-staging ----------
__global__ __launch_bounds__(256)
void qkv_kernel(const float* __restrict__ qw, const float* __restrict__ kw,
                const float* __restrict__ vw, float* __restrict__ ws)
{
  int side = blockIdx.y;
  int mat  = blockIdx.z;
  float* base = ws + (size_t)side*SS_;
  const float* A = base + X1_OFF;                 // pre-bn1 x1
  const float* bns = base + STATS_OFF + 512;      // bn1: scale at +256, shift at +384
  const float* W = mat == 0 ? qw : (mat == 1 ? kw : vw);
  float* C = base + (mat == 0 ? XC_OFF : (mat == 1 ? DTB_OFF : YB_OFF));
  __shared__ float Alds[32][128];
  __shared__ float Wlds[128][64];
  const int tid = threadIdx.x;
  const int r0 = (blockIdx.x >> 1) * 32;
  const int c0 = (blockIdx.x & 1) * 64;
  for (int i = tid*4; i < 32*128; i += 1024) {
    int k = i & 127;
    float4 a4 = *(const float4*)&A[(size_t)(r0 + (i>>7))*128 + k];
    float4 sc = *(const float4*)&bns[256 + k];
    float4 sh = *(const float4*)&bns[384 + k];
    a4.x = a4.x*sc.x + sh.x;
    a4.y = a4.y*sc.y + sh.y;
    a4.z = a4.z*sc.z + sh.z;
    a4.w = a4.w*sc.w + sh.w;
    *(float4*)&Alds[i>>7][k] = a4;
  }
  for (int i = tid*4; i < 128*64; i += 1024)
    *(float4*)&Wlds[i>>6][i&63] = *(const float4*)&W[(i>>6)*128 + c0 + (i&63)];
  __syncthreads();
  const int cl = tid & 63;
  const int rsub = (tid >> 6) * 8;
  float accv[8];
#pragma unroll
  for (int j = 0; j < 8; ++j) accv[j] = 0.f;
  for (int k = 0; k < 128; k += 4) {
    float w0 = Wlds[k][cl], w1v = Wlds[k+1][cl], w2v = Wlds[k+2][cl], w3v = Wlds[k+3][cl];
#pragma unroll
    for (int j = 0; j < 8; ++j) {
      float4 a4 = *(const float4*)&Alds[rsub+j][k];
      accv[j] += a4.x*w0 + a4.y*w1v + a4.z*w2v + a4.w*w3v;
    }
  }
#pragma unroll
  for (int j = 0; j < 8; ++j) {
    float vv = accv[j];
    if (mat < 2) vv = leakyf(vv);
    C[(size_t)(r0 + rsub + j)*128 + c0 + cl] = vv;
  }
}

// ---------------- mamba: causal depthwise conv (DCONV=4) + silu ----------------
__global__ __launch_bounds__(256)
void conv_kernel(const float* __restrict__ cw, const float* __restrict__ cb, float* __restrict__ ws)
{
  int side = blockIdx.y;
  float* base = ws + (size_t)side*SS_;
  const float* xz = base + XZ_OFF;
  float* xc = base + XC_OFF;
  int i = blockIdx.x*256 + threadIdx.x;
  int j = i >> 7, d = i & 127;
  int l = j & 127;
  float a = cb[d];
#pragma unroll
  for (int k = 0; k < 4; ++k) {
    int ll = l - 3 + k;
    if (ll >= 0) a += xz[(size_t)(j-3+k)*256 + d] * cw[d*4 + k];
  }
  xc[i] = siluf(a);
}

// ---------------- mamba scan: fused dt(softplus) + 128-step recurrence + gate ----------------
// Per-step 16-lane reduce via DPP row_ror (VALU): v+=ror8;+=ror4;+=ror2;+=ror1.
__global__ __launch_bounds__(256)
void scan_kernel(const float* __restrict__ A_log, const float* __restrict__ Dp,
                 const float* __restrict__ dtw, const float* __restrict__ dtbias,
                 float* __restrict__ ws)
{
  int side = blockIdx.z;
  int g  = blockIdx.x;
  int d0 = blockIdx.y * 16;
  float* base = ws + (size_t)side*SS_;
  const float* dbl = base + DBL_OFF;
  const float* xcb = base + XC_OFF;
  float* xz = base + XZ_OFF;

  __shared__ float ldbl[128][40];   // dt-in(8) | B(16) | C(16)
  __shared__ float lxc[128][16];
  __shared__ float ldt[128][16];
  __shared__ float lz[128][16];
  __shared__ float ly[128][16];
  __shared__ float ltw[8][16];
  __shared__ float ltb[16];

  int tid = threadIdx.x;
  int rowbase = g*128;
  if (tid < 128)      ltw[tid>>4][tid&15] = dtw[(tid>>4)*128 + d0 + (tid&15)];
  else if (tid < 144) ltb[tid-128] = dtbias[d0 + (tid-128)];
  for (int i = tid; i < 128*40; i += 256)
    ((float*)ldbl)[i] = dbl[(size_t)rowbase*40 + i];
  for (int i = tid; i < 2048; i += 256) {
    int l = i >> 4, dd = i & 15;
    lxc[l][dd] = xcb[(size_t)(rowbase+l)*128 + d0 + dd];
    lz[l][dd]  = xz[(size_t)(rowbase+l)*256 + 128 + d0 + dd];
  }
  __syncthreads();
  // dt = softplus(dbl[:, :8] @ dtw + dtb)  — once per (l,d)
  for (int i = tid; i < 2048; i += 256) {
    int l = i >> 4, dd = i & 15;
    float a = ltb[dd];
#pragma unroll
    for (int k = 0; k < 8; ++k) a += ldbl[l][k]*ltw[k][dd];
    ldt[l][dd] = a > 20.f ? a : log1pf(expf(a));
  }
  __syncthreads();

  int s = tid & 15, dl = (tid >> 4) & 15;
  float Ac  = -expf(A_log[(d0+dl)*16 + s]);
  float dpv = Dp[d0+dl];
  float hsv = 0.f;
  for (int l = 0; l < 128; ++l) {
    float dtv = ldt[l][dl];      // broadcast across s
    float xcv = lxc[l][dl];
    float Bv  = ldbl[l][8+s];
    float Cv  = ldbl[l][24+s];
    hsv = expf(dtv*Ac)*hsv + (dtv*xcv)*Bv;
    float val = hsv*Cv;
    val += dpp_rorf<0x128>(val);   // row_ror:8
    val += dpp_rorf<0x124>(val);   // row_ror:4
    val += dpp_rorf<0x122>(val);   // row_ror:2
    val += dpp_rorf<0x121>(val);   // row_ror:1
    if (s == 0) ly[l][dl] = val + xcv*dpv;
  }
  __syncthreads();
  // gate: xz[:, :128] = y * silu(z)
  for (int i = tid; i < 2048; i += 256) {
    int l = i >> 4, dd = i & 15;
    float y = ly[l][dd];
    float z = lz[l][dd];
    xz[(size_t)(rowbase+l)*256 + d0 + dd] = y * siluf(z);
  }
}

// ---------------- column stats (mode 0 only: x1 = h + hloc + ha) ----------------
__global__ __launch_bounds__(256)
void stats_kernel(const float* __restrict__ hl_in, const float* __restrict__ hr_in,
                  float* __restrict__ ws, int mode, int statsoff)
{
  int side = blockIdx.y;
  float* base = ws + (size_t)side*SS_;
  const float* h    = side ? hr_in : hl_in;
  const float* hloc = base + HL_OFF;
  const float* ha   = base + HA_OFF;
  float* x1 = base + X1_OFF;
  float* stats = base + STATS_OFF + statsoff;
  int tid = threadIdx.x;
  int c = tid & 127;
  float s1 = 0.f, s2 = 0.f;
  for (int it = 0; it < 16; ++it) {
    int r = blockIdx.x*32 + (tid >> 7) + it*2;
    size_t i = (size_t)r*128 + c;
    float v;
    if (mode == 0) { v = h[i] + hloc[i] + ha[i]; x1[i] = v; }
    else           { v = ha[i]; }
    s1 += v; s2 += v*v;
  }
  __shared__ float red[256];
  red[tid] = s1; __syncthreads();
  if (tid < 128) atomicAdd(&stats[tid], red[tid] + red[tid+128]);
  __syncthreads();
  red[tid] = s2; __syncthreads();
  if (tid < 128) atomicAdd(&stats[128+tid], red[tid] + red[tid+128]);
}

__global__ void bn_finalize_kernel(const float* __restrict__ g_, const float* __restrict__ b_,
                                   float* __restrict__ ws, int statsoff, float invM)
{
  int side = blockIdx.y;
  float* stats = ws + (size_t)side*SS_ + STATS_OFF + statsoff;
  int c = threadIdx.x;   // 128 threads
  float mean = stats[c]*invM;
  float var  = fmaxf(stats[128+c]*invM - mean*mean, 0.f);
  float scale = rsqrtf(var + 1e-5f) * g_[c];
  stats[256+c] = scale;
  stats[384+c] = b_[c] - mean*scale;
}

__global__ __launch_bounds__(256)
void bn_apply_kernel(float* __restrict__ ws, float* __restrict__ dout,
                     int srcoff, int dstoff, int statsoff, int to_dout)
{
  int side = blockIdx.y;
  float* base = ws + (size_t)side*SS_;
  const float* src = base + srcoff;
  const float* stats = base + STATS_OFF + statsoff;
  float* dst = to_dout ? (dout + (size_t)side*ND_) : (base + dstoff);
  size_t i = (size_t)blockIdx.x*256 + threadIdx.x;
  int c = (int)(i & 127);
  dst[i] = src[i]*stats[256+c] + stats[384+c];
}

// ---------------- cross attention (register-tiled); bn1 fused on residual read ------
__global__ __launch_bounds__(256)
void attn_kernel(float* __restrict__ ws)
{
  int dir = blockIdx.z;
  int g   = blockIdx.x;
  int rt  = blockIdx.y;
  float* baseq = ws + (size_t)dir*SS_;
  float* basek = ws + (size_t)(1-dir)*SS_;
  const float* qb = baseq + XC_OFF;
  const float* kb = basek + DTB_OFF;
  const float* vb = basek + YB_OFF;
  const float* x1b = baseq + X1_OFF;            // pre-bn1 x1 (hm = bn(x1))
  const float* bns = baseq + STATS_OFF + 512;   // bn1 scale/shift
  float* h2v = baseq + X1_OFF;                  // overwritten in place (same offsets)

  __shared__ float KT[128][132];   // phase A: K^T as [d][n]; phase C: V as [n][d]
  __shared__ float Qs[32][132];    // Q tile
  __shared__ float sp[32][132];    // unnormalized P tile

  const int tid = threadIdx.x;
  const int cl  = tid & 31;          // 32 col-lanes
  const int r0  = (tid >> 5) * 4;    // 8 row-groups * 4 rows = 32 rows
  const int c0  = cl * 4;            // 4 cols per thread (128 total)
  const int rowg = g*128 + rt*32;

  // ---- stage Q tile (32 x 128) ----
  {
    const float* qsrc = qb + (size_t)rowg*128;
    for (int i = tid; i < 32*32; i += 256) {
      int r = i >> 5, d4 = i & 31;
      *(float4*)&Qs[r][d4*4] = *(const float4*)&qsrc[(size_t)r*128 + d4*4];
    }
  }
  // ---- stage K^T (transpose 128x128) ----
  {
    const float* ksrc = kb + (size_t)(g*128)*128;
    for (int i = tid; i < 128*32; i += 256) {
      int d4 = i >> 7, n = i & 127;
      float4 k4 = *(const float4*)&ksrc[(size_t)n*128 + d4*4];
      KT[d4*4+0][n] = k4.x;
      KT[d4*4+1][n] = k4.y;
      KT[d4*4+2][n] = k4.z;
      KT[d4*4+3][n] = k4.w;
    }
  }
  __syncthreads();

  // ---- phase A: scores, 4 rows x 4 cols per thread ----
  float acc[4][4];
#pragma unroll
  for (int i = 0; i < 4; ++i)
#pragma unroll
    for (int j = 0; j < 4; ++j) acc[i][j] = 0.f;

  for (int d = 0; d < 128; d += 4) {
    float4 k0 = *(const float4*)&KT[d+0][c0];
    float4 k1 = *(const float4*)&KT[d+1][c0];
    float4 k2 = *(const float4*)&KT[d+2][c0];
    float4 k3 = *(const float4*)&KT[d+3][c0];
#pragma unroll
    for (int i = 0; i < 4; ++i) {
      float4 q4 = *(const float4*)&Qs[r0+i][d];
      acc[i][0] += q4.x*k0.x + q4.y*k1.x + q4.z*k2.x + q4.w*k3.x;
      acc[i][1] += q4.x*k0.y + q4.y*k1.y + q4.z*k2.y + q4.w*k3.y;
      acc[i][2] += q4.x*k0.z + q4.y*k1.z + q4.z*k2.z + q4.w*k3.z;
      acc[i][3] += q4.x*k0.w + q4.y*k1.w + q4.z*k2.w + q4.w*k3.w;
    }
  }

  // ---- softmax in registers; store unnormalized P; keep 1/sum per row ----
  float inv[4];
#pragma unroll
  for (int i = 0; i < 4; ++i) {
    float m = fmaxf(fmaxf(acc[i][0], acc[i][1]), fmaxf(acc[i][2], acc[i][3]));
#pragma unroll
    for (int off = 1; off < 32; off <<= 1) m = fmaxf(m, __shfl_xor(m, off, 32));
    float p0 = expf(acc[i][0]-m), p1 = expf(acc[i][1]-m);
    float p2 = expf(acc[i][2]-m), p3 = expf(acc[i][3]-m);
    float s = p0 + p1 + p2 + p3;
#pragma unroll
    for (int off = 1; off < 32; off <<= 1) s += __shfl_xor(s, off, 32);
    inv[i] = 1.f/s;
    *(float4*)&sp[r0+i][c0] = make_float4(p0, p1, p2, p3);
  }
  __syncthreads();

  // ---- stage V (natural [n][d], coalesced, float4 writes) ----
  {
    const float* vsrc = vb + (size_t)(g*128)*128;
    for (int i = tid; i < 128*32; i += 256) {
      int n = i >> 5, d4 = i & 31;
      *(float4*)&KT[n][d4*4] = *(const float4*)&vsrc[(size_t)n*128 + d4*4];
    }
  }
  __syncthreads();

  // ---- phase C: O = P @ V, 4 rows x 4 d-cols per thread ----
  float o[4][4];
#pragma unroll
  for (int i = 0; i < 4; ++i)
#pragma unroll
    for (int j = 0; j < 4; ++j) o[i][j] = 0.f;

  for (int n = 0; n < 128; n += 4) {
    float4 v0 = *(const float4*)&KT[n+0][c0];
    float4 v1 = *(const float4*)&KT[n+1][c0];
    float4 v2 = *(const float4*)&KT[n+2][c0];
    float4 v3 = *(const float4*)&KT[n+3][c0];
#pragma unroll
    for (int i = 0; i < 4; ++i) {
      float4 p4 = *(const float4*)&sp[r0+i][n];
      o[i][0] += p4.x*v0.x + p4.y*v1.x + p4.z*v2.x + p4.w*v3.x;
      o[i][1] += p4.x*v0.y + p4.y*v1.y + p4.z*v2.y + p4.w*v3.y;
      o[i][2] += p4.x*v0.z + p4.y*v1.z + p4.z*v2.z + p4.w*v3.z;
      o[i][3] += p4.x*v0.w + p4.y*v1.w + p4.z*v2.w + p4.w*v3.w;
    }
  }

  // ---- epilogue: h2 = bn1(x1) + O/sum (bn fused; read-before-write, same offsets) ----
  float4 sc = *(const float4*)&bns[256 + c0];
  float4 sh = *(const float4*)&bns[384 + c0];
#pragma unroll
  for (int i = 0; i < 4; ++i) {
    size_t off = (size_t)(rowg + r0 + i)*128 + c0;
    float4 xv = *(const float4*)&x1b[off];
    float4 r4;
    r4.x = xv.x*sc.x + sh.x + o[i][0]*inv[i];
    r4.y = xv.y*sc.y + sh.y + o[i][1]*inv[i];
    r4.z = xv.z*sc.z + sh.z + o[i][2]*inv[i];
    r4.w = xv.w*sc.w + sh.w + o[i][3]*inv[i];
    *(float4*)&h2v[off] = r4;
  }
}

// ---------------- launch ----------------
extern "C" void kernel_launch(void* const* d_in, const int* in_sizes, int n_in,
                              void* d_out, int out_size, void* d_ws, size_t ws_size,
                              hipStream_t stream)
{
  const float* h_lig     = (const float*)d_in[0];
  const float* h_rec     = (const float*)d_in[1];
  const float* x_lig     = (const float*)d_in[2];
  const float* x_rec     = (const float*)d_in[3];
  const float* he_1      = (const float*)d_in[4];
  const float* he_2      = (const float*)d_in[5];
  const float* emlp_w1   = (const float*)d_in[6];
  const float* emlp_b1   = (const float*)d_in[7];
  const float* emlp_bn_g = (const float*)d_in[8];
  const float* emlp_bn_b = (const float*)d_in[9];
  const float* emlp_w2   = (const float*)d_in[10];
  const float* emlp_b2   = (const float*)d_in[11];
  const float* bern_temp = (const float*)d_in[12];
  const float* m_in_w    = (const float*)d_in[13];
  const float* m_conv_w  = (const float*)d_in[14];
  const float* m_conv_b  = (const float*)d_in[15];
  const float* m_xproj_w = (const float*)d_in[16];
  const float* m_dt_w    = (const float*)d_in[17];
  const float* m_dt_b    = (const float*)d_in[18];
  const float* m_A_log   = (const float*)d_in[19];
  const float* m_D       = (const float*)d_in[20];
  const float* m_out_w   = (const float*)d_in[21];
  const float* q_w       = (const float*)d_in[22];
  const float* k_w       = (const float*)d_in[23];
  const float* v_w       = (const float*)d_in[24];
  const float* bn1_g     = (const float*)d_in[25];
  const float* bn1_b     = (const float*)d_in[26];
  const float* bn2_g     = (const float*)d_in[27];
  const float* bn2_b     = (const float*)d_in[28];
  const float* ff_w1     = (const float*)d_in[29];
  const float* ff_b1     = (const float*)d_in[30];
  const float* ff_w2     = (const float*)d_in[31];
  const float* ff_b2     = (const float*)d_in[32];
  const int*   ei1       = (const int*)d_in[33];
  const int*   ei2       = (const int*)d_in[34];
  const int*   perm1     = (const int*)d_in[37];
  const int*   perm2     = (const int*)d_in[38];

  float* ws   = (float*)d_ws;
  float* dout = (float*)d_out;

#define B0(off) (ws + (size_t)(off))
#define B1(off) (ws + SS_ + (size_t)(off))

  for (int s = 0; s < 2; ++s)
    hipMemsetAsync((char*)d_ws + ((size_t)s*SS_ + DEG_OFF)*sizeof(float), 0,
                   (N_ + 2048)*sizeof(float), stream);

  // edge weights (champion structure, fp16-packed dot2 core)
  edge_stats_kernel<<<dim3(256,2), 256, 0, stream>>>(x_lig,x_rec,he_1,he_2,ei1,ei2,emlp_w1,emlp_b1,ws);
  edge_finalize_kernel<<<dim3(1,2), 128, 0, stream>>>(emlp_bn_g,emlp_bn_b,emlp_w2,emlp_b2,ws);
  edge_w_kernel<<<dim3(256,2), 256, 0, stream>>>(x_lig,x_rec,he_1,he_2,ei1,ei2,emlp_w1,emlp_b1,ws);

  // bernstein propagation (Horner, 6 matmuls)
  bern_horner_kernel<<<dim3(G_*4,2), 256, 0, stream>>>(h_lig,h_rec,ei1,ei2,bern_temp,ws);

  // mamba
  gemm_kernel<128,256,64,4,0,1,0,0,0><<<dim3(512,2),256,0,stream>>>(
      h_lig,h_rec,128, m_in_w,nullptr, B0(XZ_OFF),B1(XZ_OFF),256, perm1,perm2, nullptr,nullptr, nullptr,nullptr);
  conv_kernel<<<dim3(2048,2), 256, 0, stream>>>(m_conv_w,m_conv_b,ws);
  gemm_kernel<128,40,64,1,0,0,0,0,0><<<dim3(128,2),256,0,stream>>>(
      B0(XC_OFF),B1(XC_OFF),128, m_xproj_w,nullptr, B0(DBL_OFF),B1(DBL_OFF),40, nullptr,nullptr, nullptr,nullptr, nullptr,nullptr);
  scan_kernel<<<dim3(32,8,2), 256, 0, stream>>>(m_A_log,m_D,m_dt_w,m_dt_b,ws);
  gemm_kernel<128,128,64,2,0,0,1,0,0><<<dim3(256,2),256,0,stream>>>(
      B0(XZ_OFF),B1(XZ_OFF),256, m_out_w,nullptr, B0(HA_OFF),B1(HA_OFF),128, perm1,perm2, nullptr,nullptr, nullptr,nullptr);

  // bn1 stats ( h + h_local + ha ); bn1 APPLY is fused into qkv + attn
  stats_kernel<<<dim3(128,2), 256, 0, stream>>>(h_lig,h_rec,ws,0,512);
  bn_finalize_kernel<<<dim3(1,2), 128, 0, stream>>>(bn1_g,bn1_b,ws,512,1.f/(float)N_);

  // q,k,v projections (bn1 fused in A-staging)
  qkv_kernel<<<dim3(256,2,3), 256, 0, stream>>>(q_w,k_w,v_w,ws);
  attn_kernel<<<dim3(32,4,2), 256, 0, stream>>>(ws);

  // ffn + bn2 (bn2 stats fused into ff_w2 epilogue; stats_kernel mode=1 removed)
  gemm_kernel<128,256,64,4,2,0,0,0,1><<<dim3(512,2),256,0,stream>>>(
      B0(X1_OFF),B1(X1_OFF),128, ff_w1,ff_b1, B0(XZ_OFF),B1(XZ_OFF),256, nullptr,nullptr, nullptr,nullptr, nullptr,nullptr);
  gemm_kernel<256,128,32,4,0,0,0,1,1,1><<<dim3(512,2),256,0,stream>>>(
      B0(XZ_OFF),B1(XZ_OFF),256, ff_w2,ff_b2, B0(HA_OFF),B1(HA_OFF),128, nullptr,nullptr, B0(X1_OFF),B1(X1_OFF),
      B0(STATS_OFF+1024), B1(STATS_OFF+1024));
  bn_finalize_kernel<<<dim3(1,2), 128, 0, stream>>>(bn2_g,bn2_b,ws,1024,1.f/(float)N_);
  bn_apply_kernel<<<dim3(2048,2), 256, 0, stream>>>(ws,dout,HA_OFF,0,1024,1);
}

// Round 17
// 393.256 us; speedup vs baseline: 1.4554x; 1.0505x over previous
//
#include <hip/hip_runtime.h>
#include <math.h>

// ---------------- problem constants ----------------
#define G_    32
#define NPG_  128
#define D_    128
#define N_    4096          // G_*NPG_
#define E_    65536
#define ND_   (N_*D_)       // 524288

// ---------------- workspace layout (float offsets, per side) ----------------
#define W_OFF     0                     // E_ edge weights w
#define DEG_OFF   65536                 // N_ degrees (atomic, zeroed)
#define STATS_OFF 69632                 // 2048 floats of stats (zeroed):
//   [0:128) edge colsum  [128:256) edge colsumsq [256:384) alpha [384] beta
//   [512..1024) bn1: sum/ssq/scale/shift   [1024..1536) bn2: same
#define BUF0      71680
#define HL_OFF    (BUF0 + 0*ND_)        // h_local (bern output)
#define HA_OFF    (BUF0 + 1*ND_)        // mamba out (scattered); later x2
#define X1_OFF    (BUF0 + 2*ND_)        // pre-bn1 sum; later h2 (post-attn)
#define HMID_OFF  (BUF0 + 3*ND_)        // (unused since bn1 is fused into qkv/attn)
#define XC_OFF    (BUF0 + 4*ND_)        // conv output; later q
#define DTB_OFF   (BUF0 + 5*ND_)        // k
#define YB_OFF    (BUF0 + 6*ND_)        // v
#define XZ_OFF    (BUF0 + 7*ND_)        // 2*ND_: [xq|z] per row (256); scan gate overwrites xq
#define DBL_OFF   (BUF0 + 9*ND_)        // N_*40
#define WT_OFF    (DBL_OFF + N_*40)     // (unused scratch, kept for layout stability)
#define SS_       ((size_t)(WT_OFF + 4096))

__device__ __forceinline__ float leakyf(float x){ return x >= 0.f ? x : 0.02f*x; }
__device__ __forceinline__ float siluf (float x){ return x / (1.f + expf(-x)); }

// packed fp16 pair + 2-way dot with fp32 accumulate
typedef _Float16 h2 __attribute__((ext_vector_type(2)));
#if __has_builtin(__builtin_amdgcn_fdot2)
__device__ __forceinline__ float fdot2a(h2 a, h2 b, float c){
  return __builtin_amdgcn_fdot2(a, b, c, false);
}
#else
__device__ __forceinline__ float fdot2a(h2 a, h2 b, float c){
  return c + (float)a[0]*(float)b[0] + (float)a[1]*(float)b[1];
}
#endif

// DPP row-rotate (within rows of 16 lanes) — VALU-pipe lane exchange.
// CTRL = 0x120 + n  (row_ror:n)
template<int CTRL>
__device__ __forceinline__ float dpp_rorf(float x){
  return __int_as_float(
      __builtin_amdgcn_update_dpp(0, __float_as_int(x), CTRL, 0xf, 0xf, false));
}

// ---------------- edge feature helper ----------------
__device__ __forceinline__ void edge_feat(const float* __restrict__ x,
                                          const float* __restrict__ he,
                                          const int* __restrict__ ei,
                                          int e, float* feat, int& sN, int& dN)
{
  sN = ei[e]; dN = ei[E_ + e];
  float dx = x[sN*3+0]-x[dN*3+0];
  float dy = x[sN*3+1]-x[dN*3+1];
  float dz = x[sN*3+2]-x[dN*3+2];
  float d2 = dx*dx + dy*dy + dz*dz;
  feat[0] = expf(-d2);
  feat[1] = expf(d2 * -0.1f);
  feat[2] = expf(d2 * -0.01f);
  feat[3] = expf(d2 * -0.001f);
  feat[4] = expf(d2 * -0.0001f);
#pragma unroll
  for (int j = 0; j < 27; ++j) feat[5+j] = he[(size_t)e*27 + j];
}

// ---------------- E1: per-column stats, fp16-packed dot2 core ----------------
__global__ __launch_bounds__(256)
void edge_stats_kernel(const float* __restrict__ xl, const float* __restrict__ xr,
                       const float* __restrict__ hel, const float* __restrict__ her,
                       const int* __restrict__ ei1, const int* __restrict__ ei2,
                       const float* __restrict__ w1, const float* __restrict__ b1,
                       float* __restrict__ ws)
{
  int side = blockIdx.y;
  const float* x  = side ? xr  : xl;
  const float* he = side ? her : hel;
  const int*   ei = side ? ei2 : ei1;
  float* stats = ws + (size_t)side*SS_ + STATS_OFF;
  __shared__ _Float16 featl[256][40];   // rows 80B (16B-aligned)
  __shared__ float csum[2][128], cssq[2][128];
  int tid = threadIdx.x;
  {
    int sN, dN; float feat[32];
    edge_feat(x, he, ei, blockIdx.x*256 + tid, feat, sN, dN);
    h2 tmp[16];
#pragma unroll
    for (int j = 0; j < 16; ++j) { tmp[j][0] = (_Float16)feat[2*j]; tmp[j][1] = (_Float16)feat[2*j+1]; }
#pragma unroll
    for (int q = 0; q < 4; ++q)
      *(float4*)&featl[tid][q*8] = ((const float4*)tmp)[q];
  }
  int c = tid & 127, hh = tid >> 7;
  h2 w1h[16];
#pragma unroll
  for (int j = 0; j < 16; ++j) {
    w1h[j][0] = (_Float16)w1[(2*j)*128 + c];
    w1h[j][1] = (_Float16)w1[(2*j+1)*128 + c];
  }
  float b1c = b1[c];
  __syncthreads();
  float s1 = 0.f, s2 = 0.f;
  for (int e = 0; e < 128; ++e) {
    const h2* fh = (const h2*)&featl[hh*128 + e][0];
    float a0 = 0.f, a1 = 0.f, a2 = 0.f, a3 = 0.f;
#pragma unroll
    for (int q = 0; q < 4; ++q) {
      a0 = fdot2a(fh[q*4+0], w1h[q*4+0], a0);
      a1 = fdot2a(fh[q*4+1], w1h[q*4+1], a1);
      a2 = fdot2a(fh[q*4+2], w1h[q*4+2], a2);
      a3 = fdot2a(fh[q*4+3], w1h[q*4+3], a3);
    }
    float t = leakyf(b1c + ((a0+a1) + (a2+a3)));
    s1 += t; s2 += t*t;
  }
  csum[hh][c] = s1; cssq[hh][c] = s2;
  __syncthreads();
  if (tid < 128) {
    atomicAdd(&stats[tid],     csum[0][tid] + csum[1][tid]);
    atomicAdd(&stats[128+tid], cssq[0][tid] + cssq[1][tid]);
  }
}

// ---------------- E2: finalize edge bn folded with emlp_w2 -> alpha,beta ----------------
__global__ void edge_finalize_kernel(const float* __restrict__ g_, const float* __restrict__ b_,
                                     const float* __restrict__ w2, const float* __restrict__ b2,
                                     float* __restrict__ ws)
{
  int side = blockIdx.y;
  float* stats = ws + (size_t)side*SS_ + STATS_OFF;
  __shared__ float red[128];
  int c = threadIdx.x;  // 128 threads
  const float invE = 1.f/(float)E_;
  float mean = stats[c]*invE;
  float var  = fmaxf(stats[128+c]*invE - mean*mean, 0.f);
  float scale = rsqrtf(var + 1e-5f) * g_[c];
  stats[256+c] = scale * w2[c];
  red[c] = (b_[c] - mean*scale) * w2[c];
  __syncthreads();
  for (int off = 64; off; off >>= 1) { if (c < off) red[c] += red[c+off]; __syncthreads(); }
  if (c == 0) stats[384] = red[0] + b2[0];
}

// ---------------- E3: w_e, fp16-packed dot2 core ----------------
__global__ __launch_bounds__(256)
void edge_w_kernel(const float* __restrict__ xl, const float* __restrict__ xr,
                   const float* __restrict__ hel, const float* __restrict__ her,
                   const int* __restrict__ ei1, const int* __restrict__ ei2,
                   const float* __restrict__ w1, const float* __restrict__ b1,
                   float* __restrict__ ws)
{
  int side = blockIdx.y;
  const float* x  = side ? xr  : xl;
  const float* he = side ? her : hel;
  const int*   ei = side ? ei2 : ei1;
  float* base = ws + (size_t)side*SS_;
  const float* stats = base + STATS_OFF;
  float* wbuf = base + W_OFF;
  float* deg  = base + DEG_OFF;
  __shared__ _Float16 w1t[128][32];     // rows 64B (16B-aligned), 8KB
  __shared__ float b1l[128], all_[128];
  int tid = threadIdx.x;
  for (int i = tid; i < 4096; i += 256) {
    int j = i & 31, c = i >> 5;
    w1t[c][j] = (_Float16)w1[j*128 + c];
  }
  if (tid < 128) { b1l[tid] = b1[tid]; all_[tid] = stats[256+tid]; }
  __syncthreads();
  int e = blockIdx.x*256 + tid;
  int sN, dN; float feat[32];
  edge_feat(x, he, ei, e, feat, sN, dN);
  h2 fh[16];
#pragma unroll
  for (int j = 0; j < 16; ++j) { fh[j][0] = (_Float16)feat[2*j]; fh[j][1] = (_Float16)feat[2*j+1]; }
  float accw = stats[384];
  for (int c = 0; c < 128; ++c) {
    const h2* wc = (const h2*)&w1t[c][0];
    float a0 = 0.f, a1 = 0.f, a2 = 0.f, a3 = 0.f;
#pragma unroll
    for (int q = 0; q < 4; ++q) {
      a0 = fdot2a(fh[q*4+0], wc[q*4+0], a0);
      a1 = fdot2a(fh[q*4+1], wc[q*4+1], a1);
      a2 = fdot2a(fh[q*4+2], wc[q*4+2], a2);
      a3 = fdot2a(fh[q*4+3], wc[q*4+3], a3);
    }
    accw += leakyf(b1l[c] + ((a0+a1) + (a2+a3))) * all_[c];
  }
  float w = fmaxf(accw, 0.f);
  wbuf[e] = w;
  atomicAdd(&deg[sN], w);
}

// ---------------- Bernstein propagation via Horner (6 matmuls) ----------------
__global__ __launch_bounds__(256)
void bern_horner_kernel(const float* __restrict__ hl_in, const float* __restrict__ hr_in,
                        const int* __restrict__ ei1, const int* __restrict__ ei2,
                        const float* __restrict__ bern_temp, float* __restrict__ ws)
{
  int side = blockIdx.y;
  int g  = blockIdx.x >> 2;
  int d0 = (blockIdx.x & 3) * 32;
  const float* h  = side ? hr_in : hl_in;
  const int*   ei = side ? ei2 : ei1;
  float* base = ws + (size_t)side*SS_;
  const float* wbuf = base + W_OFF;
  const float* deg  = base + DEG_OFF;
  float* hloc = base + HL_OFF;

  __shared__ float A[128*132];
  __shared__ float v[128*32];
  int tid = threadIdx.x;
  for (int i = tid; i < 128*132; i += 256) A[i] = 0.f;

  const float btab[7][7] = {
    { 1,  6, 15,  20, 15,  6,  1},
    { 1,  4,  5,   0, -5, -4, -1},
    { 1,  2, -1,  -4, -1,  2,  1},
    { 1,  0, -3,   0,  3,  0, -1},
    { 1, -2, -1,   4, -1, -2,  1},
    { 1, -4,  5,   0, -5,  4, -1},
    { 1, -6, 15, -20, 15, -6,  1}};
  const float comb6[7] = {1,6,15,20,15,6,1};
  float a[7];
#pragma unroll
  for (int m = 0; m < 7; ++m) a[m] = 0.f;
#pragma unroll
  for (int j = 0; j < 7; ++j) {
    float tj = fmaxf(bern_temp[j], 0.f) * comb6[j] * (1.f/64.f);
#pragma unroll
    for (int m = 0; m < 7; ++m) a[m] += tj * btab[j][m];
  }
  __syncthreads();

  int ebase = g*2048, nbase = g*128;
  for (int i = tid; i < 2048; i += 256) {
    int e = ebase + i;
    int sN = ei[e], dN = ei[E_ + e];
    float ds_ = deg[sN], dd_ = deg[dN];
    float aa = ds_ > 0.f ? rsqrtf(ds_ + 1e-12f) : 0.f;
    float bb = dd_ > 0.f ? rsqrtf(dd_ + 1e-12f) : 0.f;
    atomicAdd(&A[(dN - nbase)*132 + (sN - nbase)], wbuf[e]*aa*bb);
  }

  const int db = (tid & 7)*4;
  const int rb = (tid >> 3)*4;
  float hreg[4][4], r[4][4], t[4][4];
#pragma unroll
  for (int i = 0; i < 4; ++i) {
    float4 h4 = *(const float4*)&h[(size_t)(nbase + rb + i)*128 + d0 + db];
    hreg[i][0]=h4.x; hreg[i][1]=h4.y; hreg[i][2]=h4.z; hreg[i][3]=h4.w;
#pragma unroll
    for (int jj = 0; jj < 4; ++jj) r[i][jj] = a[6]*hreg[i][jj];
  }

  for (int step = 5; step >= 0; --step) {
    __syncthreads();
#pragma unroll
    for (int i = 0; i < 4; ++i)
      *(float4*)&v[(rb+i)*32 + db] = make_float4(r[i][0], r[i][1], r[i][2], r[i][3]);
    __syncthreads();
#pragma unroll
    for (int i = 0; i < 4; ++i)
#pragma unroll
      for (int jj = 0; jj < 4; ++jj) t[i][jj] = 0.f;
    for (int k = 0; k < 128; k += 4) {
      float4 V0 = *(const float4*)&v[(k+0)*32 + db];
      float4 V1 = *(const float4*)&v[(k+1)*32 + db];
      float4 V2 = *(const float4*)&v[(k+2)*32 + db];
      float4 V3 = *(const float4*)&v[(k+3)*32 + db];
#pragma unroll
      for (int i = 0; i < 4; ++i) {
        float4 A4 = *(const float4*)&A[(rb+i)*132 + k];
        t[i][0] += A4.x*V0.x + A4.y*V1.x + A4.z*V2.x + A4.w*V3.x;
        t[i][1] += A4.x*V0.y + A4.y*V1.y + A4.z*V2.y + A4.w*V3.y;
        t[i][2] += A4.x*V0.z + A4.y*V1.z + A4.z*V2.z + A4.w*V3.z;
        t[i][3] += A4.x*V0.w + A4.y*V1.w + A4.z*V2.w + A4.w*V3.w;
      }
    }
    float ak = a[step];
#pragma unroll
    for (int i = 0; i < 4; ++i)
#pragma unroll
      for (int jj = 0; jj < 4; ++jj) r[i][jj] = t[i][jj] + ak*hreg[i][jj];
  }

#pragma unroll
  for (int i = 0; i < 4; ++i)
    *(float4*)&hloc[(size_t)(nbase + rb + i)*128 + d0 + db] =
        make_float4(r[i][0], r[i][1], r[i][2], r[i][3]);
}

// ---------------- generic GEMM, col-split; optional fp16-fdot2 core; optional stats ----
// FP16=1: A/W staged to LDS as packed h2 (conversion in staging), fdot2 inner
// loop, fp32 accumulate/bias/act/residual. STATS=1 (CLEN==TC): per-column
// sum/ssq of outputs -> st{0,1} via LDS pre-reduce + atomics.
template<int K, int NC, int TC, int CSPLIT, int ACT, int GATHER, int SCATTER, int ADDC, int BIAS, int STATS = 0, int FP16 = 0>
__global__ __launch_bounds__(256)
void gemm_kernel(const float* __restrict__ A0, const float* __restrict__ A1, int lda,
                 const float* __restrict__ W, const float* __restrict__ bias,
                 float* __restrict__ C0, float* __restrict__ C1, int ldc,
                 const int* __restrict__ idx0, const int* __restrict__ idx1,
                 const float* __restrict__ add0, const float* __restrict__ add1,
                 float* __restrict__ st0, float* __restrict__ st1)
{
  int side = blockIdx.y;
  const float* A = side ? A1 : A0;
  float* C = side ? C1 : C0;
  const int* idx = side ? idx1 : idx0;
  const float* addsrc = side ? add1 : add0;
  constexpr int RPT = TC/8;
  constexpr int CLEN = NC/CSPLIT;
  __shared__ __align__(16) unsigned char AldsRaw[32*K*(FP16?2:4)];
  __shared__ __align__(16) unsigned char WldsRaw[(size_t)K*TC*(FP16?2:4)];
  __shared__ float sbuf[2*TC];
  const int tid = threadIdx.x;
  const int r0 = (blockIdx.x / CSPLIT) * 32;
  const int cbase = (blockIdx.x % CSPLIT) * CLEN;
  float ts1 = 0.f, ts2 = 0.f;

  if (FP16) {
    h2 (*Al2)[K/2] = (h2(*)[K/2])AldsRaw;
    for (int i = tid*4; i < 32*K; i += 1024) {
      int r = i / K, k = i % K;
      int row = GATHER ? idx[r0 + r] : (r0 + r);
      float4 a4 = *(const float4*)&A[(size_t)row*lda + k];
      h2 p0, p1;
      p0[0] = (_Float16)a4.x; p0[1] = (_Float16)a4.y;
      p1[0] = (_Float16)a4.z; p1[1] = (_Float16)a4.w;
      Al2[r][k/2]   = p0;
      Al2[r][k/2+1] = p1;
    }
  } else {
    float (*Alds)[K] = (float(*)[K])AldsRaw;
    for (int i = tid*4; i < 32*K; i += 1024) {
      int r = i / K, k = i % K;
      int row = GATHER ? idx[r0 + r] : (r0 + r);
      *(float4*)&Alds[r][k] = *(const float4*)&A[(size_t)row*lda + k];
    }
  }

  for (int c0 = cbase; c0 < cbase + CLEN; c0 += TC) {
    __syncthreads();
    if (FP16) {
      h2 (*Wl2)[TC] = (h2(*)[TC])WldsRaw;
      for (int i = tid; i < (K/2)*TC; i += 256) {
        int kk = i / TC, c = i % TC;
        float wa = (c0 + c < NC) ? W[(2*kk)*NC + c0 + c]   : 0.f;
        float wb = (c0 + c < NC) ? W[(2*kk+1)*NC + c0 + c] : 0.f;
        h2 p; p[0] = (_Float16)wa; p[1] = (_Float16)wb;
        Wl2[kk][c] = p;
      }
    } else {
      float (*Wlds)[TC] = (float(*)[TC])WldsRaw;
      for (int i = tid*4; i < K*TC; i += 1024) {
        int k = i / TC, c = i % TC;
        if (c0 + c < NC) *(float4*)&Wlds[k][c] = *(const float4*)&W[k*NC + c0 + c];
        else             *(float4*)&Wlds[k][c] = make_float4(0.f,0.f,0.f,0.f);
      }
    }
    __syncthreads();
    const int cl = tid % TC;
    const int rsub = (tid / TC) * RPT;
    float accv[RPT];
#pragma unroll
    for (int j = 0; j < RPT; ++j) accv[j] = 0.f;
    if (FP16) {
      h2 (*Al2)[K/2] = (h2(*)[K/2])AldsRaw;
      h2 (*Wl2)[TC] = (h2(*)[TC])WldsRaw;
      for (int kk = 0; kk < K/2; kk += 4) {
        h2 w0 = Wl2[kk+0][cl], w1p = Wl2[kk+1][cl], w2p = Wl2[kk+2][cl], w3p = Wl2[kk+3][cl];
#pragma unroll
        for (int j = 0; j < RPT; ++j) {
          float4 av = *(const float4*)&Al2[rsub+j][kk];
          const h2* ah = (const h2*)&av;
          accv[j] = fdot2a(ah[0], w0,  accv[j]);
          accv[j] = fdot2a(ah[1], w1p, accv[j]);
          accv[j] = fdot2a(ah[2], w2p, accv[j]);
          accv[j] = fdot2a(ah[3], w3p, accv[j]);
        }
      }
    } else {
      float (*Alds)[K] = (float(*)[K])AldsRaw;
      float (*Wlds)[TC] = (float(*)[TC])WldsRaw;
      for (int k = 0; k < K; k += 4) {
        float w0 = Wlds[k][cl], w1v = Wlds[k+1][cl], w2v = Wlds[k+2][cl], w3v = Wlds[k+3][cl];
#pragma unroll
        for (int j = 0; j < RPT; ++j) {
          float4 a4 = *(const float4*)&Alds[rsub+j][k];
          accv[j] += a4.x*w0 + a4.y*w1v + a4.z*w2v + a4.w*w3v;
        }
      }
    }
    int c = c0 + cl;
    if (c < NC) {
#pragma unroll
      for (int j = 0; j < RPT; ++j) {
        int row  = r0 + rsub + j;
        int orow = SCATTER ? idx[row] : row;
        float vv = accv[j];
        if (BIAS)     vv += bias[c];
        if (ACT == 1) vv = leakyf(vv);
        if (ACT == 2) vv = fmaxf(vv, 0.f);
        if (ADDC)     vv += addsrc[(size_t)orow*ldc + c];
        C[(size_t)orow*ldc + c] = vv;
        if (STATS) { ts1 += vv; ts2 += vv*vv; }
      }
    }
  }
  if (STATS) {
    float* st = side ? st1 : st0;
    int clx = tid % TC;
    __syncthreads();
    if (tid < 2*TC) sbuf[tid] = 0.f;
    __syncthreads();
    atomicAdd(&sbuf[clx],      ts1);
    atomicAdd(&sbuf[TC + clx], ts2);
    __syncthreads();
    if (tid < TC)            atomicAdd(&st[cbase + tid],            sbuf[tid]);
    else if (tid < 2*TC)     atomicAdd(&st[128 + cbase + (tid-TC)], sbuf[tid]);
  }
}

// ---------------- qkv: 3 projections, fp16-fdot2 core; bn1 fused into A-staging -------
__global__ __launch_bounds__(256)
void qkv_kernel(const float* __restrict__ qw, const float* __restrict__ kw,
                const float* __restrict__ vw, float* __restrict__ ws)
{
  int side = blockIdx.y;
  int mat  = blockIdx.z;
  float* base = ws + (size_t)side*SS_;
  const float* A = base + X1_OFF;                 // pre-bn1 x1
  const float* bns = base + STATS_OFF + 512;      // bn1: scale at +256, shift at +384
  const float* W = mat == 0 ? qw : (mat == 1 ? kw : vw);
  float* C = base + (mat == 0 ? XC_OFF : (mat == 1 ? DTB_OFF : YB_OFF));
  __shared__ h2 Al2[32][64];    // 8KB
  __shared__ h2 Wl2[64][64];    // 16KB
  const int tid = threadIdx.x;
  const int r0 = (blockIdx.x >> 1) * 32;
  const int c0 = (blockIdx.x & 1) * 64;
  for (int i = tid*4; i < 32*128; i += 1024) {
    int k = i & 127;
    float4 a4 = *(const float4*)&A[(size_t)(r0 + (i>>7))*128 + k];
    float4 sc = *(const float4*)&bns[256 + k];
    float4 sh = *(const float4*)&bns[384 + k];
    a4.x = a4.x*sc.x + sh.x;
    a4.y = a4.y*sc.y + sh.y;
    a4.z = a4.z*sc.z + sh.z;
    a4.w = a4.w*sc.w + sh.w;
    h2 p0, p1;
    p0[0] = (_Float16)a4.x; p0[1] = (_Float16)a4.y;
    p1[0] = (_Float16)a4.z; p1[1] = (_Float16)a4.w;
    Al2[i>>7][k/2]   = p0;
    Al2[i>>7][k/2+1] = p1;
  }
  for (int i = tid; i < 64*64; i += 256) {
    int kk = i >> 6, c = i & 63;
    h2 p;
    p[0] = (_Float16)W[(2*kk)*128 + c0 + c];
    p[1] = (_Float16)W[(2*kk+1)*128 + c0 + c];
    Wl2[kk][c] = p;
  }
  __syncthreads();
  const int cl = tid & 63;
  const int rsub = (tid >> 6) * 8;
  float accv[8];
#pragma unroll
  for (int j = 0; j < 8; ++j) accv[j] = 0.f;
  for (int kk = 0; kk < 64; kk += 4) {
    h2 w0 = Wl2[kk+0][cl], w1p = Wl2[kk+1][cl], w2p = Wl2[kk+2][cl], w3p = Wl2[kk+3][cl];
#pragma unroll
    for (int j = 0; j < 8; ++j) {
      float4 av = *(const float4*)&Al2[rsub+j][kk];
      const h2* ah = (const h2*)&av;
      accv[j] = fdot2a(ah[0], w0,  accv[j]);
      accv[j] = fdot2a(ah[1], w1p, accv[j]);
      accv[j] = fdot2a(ah[2], w2p, accv[j]);
      accv[j] = fdot2a(ah[3], w3p, accv[j]);
    }
  }
#pragma unroll
  for (int j = 0; j < 8; ++j) {
    float vv = accv[j];
    if (mat < 2) vv = leakyf(vv);
    C[(size_t)(r0 + rsub + j)*128 + c0 + cl] = vv;
  }
}

// ---------------- mamba: causal depthwise conv (DCONV=4) + silu ----------------
__global__ __launch_bounds__(256)
void conv_kernel(const float* __restrict__ cw, const float* __restrict__ cb, float* __restrict__ ws)
{
  int side = blockIdx.y;
  float* base = ws + (size_t)side*SS_;
  const float* xz = base + XZ_OFF;
  float* xc = base + XC_OFF;
  int i = blockIdx.x*256 + threadIdx.x;
  int j = i >> 7, d = i & 127;
  int l = j & 127;
  float a = cb[d];
#pragma unroll
  for (int k = 0; k < 4; ++k) {
    int ll = l - 3 + k;
    if (ll >= 0) a += xz[(size_t)(j-3+k)*256 + d] * cw[d*4 + k];
  }
  xc[i] = siluf(a);
}

// ---------------- mamba scan: fused dt(softplus) + 128-step recurrence + gate ----------------
// Per-step 16-lane reduce via DPP row_ror (VALU): v+=ror8;+=ror4;+=ror2;+=ror1.
__global__ __launch_bounds__(256)
void scan_kernel(const float* __restrict__ A_log, const float* __restrict__ Dp,
                 const float* __restrict__ dtw, const float* __restrict__ dtbias,
                 float* __restrict__ ws)
{
  int side = blockIdx.z;
  int g  = blockIdx.x;
  int d0 = blockIdx.y * 16;
  float* base = ws + (size_t)side*SS_;
  const float* dbl = base + DBL_OFF;
  const float* xcb = base + XC_OFF;
  float* xz = base + XZ_OFF;

  __shared__ float ldbl[128][40];   // dt-in(8) | B(16) | C(16)
  __shared__ float lxc[128][16];
  __shared__ float ldt[128][16];
  __shared__ float lz[128][16];
  __shared__ float ly[128][16];
  __shared__ float ltw[8][16];
  __shared__ float ltb[16];

  int tid = threadIdx.x;
  int rowbase = g*128;
  if (tid < 128)      ltw[tid>>4][tid&15] = dtw[(tid>>4)*128 + d0 + (tid&15)];
  else if (tid < 144) ltb[tid-128] = dtbias[d0 + (tid-128)];
  for (int i = tid; i < 128*40; i += 256)
    ((float*)ldbl)[i] = dbl[(size_t)rowbase*40 + i];
  for (int i = tid; i < 2048; i += 256) {
    int l = i >> 4, dd = i & 15;
    lxc[l][dd] = xcb[(size_t)(rowbase+l)*128 + d0 + dd];
    lz[l][dd]  = xz[(size_t)(rowbase+l)*256 + 128 + d0 + dd];
  }
  __syncthreads();
  // dt = softplus(dbl[:, :8] @ dtw + dtb)  — once per (l,d)
  for (int i = tid; i < 2048; i += 256) {
    int l = i >> 4, dd = i & 15;
    float a = ltb[dd];
#pragma unroll
    for (int k = 0; k < 8; ++k) a += ldbl[l][k]*ltw[k][dd];
    ldt[l][dd] = a > 20.f ? a : log1pf(expf(a));
  }
  __syncthreads();

  int s = tid & 15, dl = (tid >> 4) & 15;
  float Ac  = -expf(A_log[(d0+dl)*16 + s]);
  float dpv = Dp[d0+dl];
  float hsv = 0.f;
  for (int l = 0; l < 128; ++l) {
    float dtv = ldt[l][dl];      // broadcast across s
    float xcv = lxc[l][dl];
    float Bv  = ldbl[l][8+s];
    float Cv  = ldbl[l][24+s];
    hsv = expf(dtv*Ac)*hsv + (dtv*xcv)*Bv;
    float val = hsv*Cv;
    val += dpp_rorf<0x128>(val);   // row_ror:8
    val += dpp_rorf<0x124>(val);   // row_ror:4
    val += dpp_rorf<0x122>(val);   // row_ror:2
    val += dpp_rorf<0x121>(val);   // row_ror:1
    if (s == 0) ly[l][dl] = val + xcv*dpv;
  }
  __syncthreads();
  // gate: xz[:, :128] = y * silu(z)
  for (int i = tid; i < 2048; i += 256) {
    int l = i >> 4, dd = i & 15;
    float y = ly[l][dd];
    float z = lz[l][dd];
    xz[(size_t)(rowbase+l)*256 + d0 + dd] = y * siluf(z);
  }
}

// ---------------- column stats (mode 0 only: x1 = h + hloc + ha) ----------------
__global__ __launch_bounds__(256)
void stats_kernel(const float* __restrict__ hl_in, const float* __restrict__ hr_in,
                  float* __restrict__ ws, int mode, int statsoff)
{
  int side = blockIdx.y;
  float* base = ws + (size_t)side*SS_;
  const float* h    = side ? hr_in : hl_in;
  const float* hloc = base + HL_OFF;
  const float* ha   = base + HA_OFF;
  float* x1 = base + X1_OFF;
  float* stats = base + STATS_OFF + statsoff;
  int tid = threadIdx.x;
  int c = tid & 127;
  float s1 = 0.f, s2 = 0.f;
  for (int it = 0; it < 16; ++it) {
    int r = blockIdx.x*32 + (tid >> 7) + it*2;
    size_t i = (size_t)r*128 + c;
    float v;
    if (mode == 0) { v = h[i] + hloc[i] + ha[i]; x1[i] = v; }
    else           { v = ha[i]; }
    s1 += v; s2 += v*v;
  }
  __shared__ float red[256];
  red[tid] = s1; __syncthreads();
  if (tid < 128) atomicAdd(&stats[tid], red[tid] + red[tid+128]);
  __syncthreads();
  red[tid] = s2; __syncthreads();
  if (tid < 128) atomicAdd(&stats[128+tid], red[tid] + red[tid+128]);
}

__global__ void bn_finalize_kernel(const float* __restrict__ g_, const float* __restrict__ b_,
                                   float* __restrict__ ws, int statsoff, float invM)
{
  int side = blockIdx.y;
  float* stats = ws + (size_t)side*SS_ + STATS_OFF + statsoff;
  int c = threadIdx.x;   // 128 threads
  float mean = stats[c]*invM;
  float var  = fmaxf(stats[128+c]*invM - mean*mean, 0.f);
  float scale = rsqrtf(var + 1e-5f) * g_[c];
  stats[256+c] = scale;
  stats[384+c] = b_[c] - mean*scale;
}

__global__ __launch_bounds__(256)
void bn_apply_kernel(float* __restrict__ ws, float* __restrict__ dout,
                     int srcoff, int dstoff, int statsoff, int to_dout)
{
  int side = blockIdx.y;
  float* base = ws + (size_t)side*SS_;
  const float* src = base + srcoff;
  const float* stats = base + STATS_OFF + statsoff;
  float* dst = to_dout ? (dout + (size_t)side*ND_) : (base + dstoff);
  size_t i = (size_t)blockIdx.x*256 + threadIdx.x;
  int c = (int)(i & 127);
  dst[i] = src[i]*stats[256+c] + stats[384+c];
}

// ---------------- cross attention (register-tiled); bn1 fused on residual read ------
__global__ __launch_bounds__(256)
void attn_kernel(float* __restrict__ ws)
{
  int dir = blockIdx.z;
  int g   = blockIdx.x;
  int rt  = blockIdx.y;
  float* baseq = ws + (size_t)dir*SS_;
  float* basek = ws + (size_t)(1-dir)*SS_;
  const float* qb = baseq + XC_OFF;
  const float* kb = basek + DTB_OFF;
  const float* vb = basek + YB_OFF;
  const float* x1b = baseq + X1_OFF;            // pre-bn1 x1 (hm = bn(x1))
  const float* bns = baseq + STATS_OFF + 512;   // bn1 scale/shift
  float* h2v = baseq + X1_OFF;                  // overwritten in place (same offsets)

  __shared__ float KT[128][132];   // phase A: K^T as [d][n]; phase C: V as [n][d]
  __shared__ float Qs[32][132];    // Q tile
  __shared__ float sp[32][132];    // unnormalized P tile

  const int tid = threadIdx.x;
  const int cl  = tid & 31;          // 32 col-lanes
  const int r0  = (tid >> 5) * 4;    // 8 row-groups * 4 rows = 32 rows
  const int c0  = cl * 4;            // 4 cols per thread (128 total)
  const int rowg = g*128 + rt*32;

  // ---- stage Q tile (32 x 128) ----
  {
    const float* qsrc = qb + (size_t)rowg*128;
    for (int i = tid; i < 32*32; i += 256) {
      int r = i >> 5, d4 = i & 31;
      *(float4*)&Qs[r][d4*4] = *(const float4*)&qsrc[(size_t)r*128 + d4*4];
    }
  }
  // ---- stage K^T (transpose 128x128) ----
  {
    const float* ksrc = kb + (size_t)(g*128)*128;
    for (int i = tid; i < 128*32; i += 256) {
      int d4 = i >> 7, n = i & 127;
      float4 k4 = *(const float4*)&ksrc[(size_t)n*128 + d4*4];
      KT[d4*4+0][n] = k4.x;
      KT[d4*4+1][n] = k4.y;
      KT[d4*4+2][n] = k4.z;
      KT[d4*4+3][n] = k4.w;
    }
  }
  __syncthreads();

  // ---- phase A: scores, 4 rows x 4 cols per thread ----
  float acc[4][4];
#pragma unroll
  for (int i = 0; i < 4; ++i)
#pragma unroll
    for (int j = 0; j < 4; ++j) acc[i][j] = 0.f;

  for (int d = 0; d < 128; d += 4) {
    float4 k0 = *(const float4*)&KT[d+0][c0];
    float4 k1 = *(const float4*)&KT[d+1][c0];
    float4 k2 = *(const float4*)&KT[d+2][c0];
    float4 k3 = *(const float4*)&KT[d+3][c0];
#pragma unroll
    for (int i = 0; i < 4; ++i) {
      float4 q4 = *(const float4*)&Qs[r0+i][d];
      acc[i][0] += q4.x*k0.x + q4.y*k1.x + q4.z*k2.x + q4.w*k3.x;
      acc[i][1] += q4.x*k0.y + q4.y*k1.y + q4.z*k2.y + q4.w*k3.y;
      acc[i][2] += q4.x*k0.z + q4.y*k1.z + q4.z*k2.z + q4.w*k3.z;
      acc[i][3] += q4.x*k0.w + q4.y*k1.w + q4.z*k2.w + q4.w*k3.w;
    }
  }

  // ---- softmax in registers; store unnormalized P; keep 1/sum per row ----
  float inv[4];
#pragma unroll
  for (int i = 0; i < 4; ++i) {
    float m = fmaxf(fmaxf(acc[i][0], acc[i][1]), fmaxf(acc[i][2], acc[i][3]));
#pragma unroll
    for (int off = 1; off < 32; off <<= 1) m = fmaxf(m, __shfl_xor(m, off, 32));
    float p0 = expf(acc[i][0]-m), p1 = expf(acc[i][1]-m);
    float p2 = expf(acc[i][2]-m), p3 = expf(acc[i][3]-m);
    float s = p0 + p1 + p2 + p3;
#pragma unroll
    for (int off = 1; off < 32; off <<= 1) s += __shfl_xor(s, off, 32);
    inv[i] = 1.f/s;
    *(float4*)&sp[r0+i][c0] = make_float4(p0, p1, p2, p3);
  }
  __syncthreads();

  // ---- stage V (natural [n][d], coalesced, float4 writes) ----
  {
    const float* vsrc = vb + (size_t)(g*128)*128;
    for (int i = tid; i < 128*32; i += 256) {
      int n = i >> 5, d4 = i & 31;
      *(float4*)&KT[n][d4*4] = *(const float4*)&vsrc[(size_t)n*128 + d4*4];
    }
  }
  __syncthreads();

  // ---- phase C: O = P @ V, 4 rows x 4 d-cols per thread ----
  float o[4][4];
#pragma unroll
  for (int i = 0; i < 4; ++i)
#pragma unroll
    for (int j = 0; j < 4; ++j) o[i][j] = 0.f;

  for (int n = 0; n < 128; n += 4) {
    float4 v0 = *(const float4*)&KT[n+0][c0];
    float4 v1 = *(const float4*)&KT[n+1][c0];
    float4 v2 = *(const float4*)&KT[n+2][c0];
    float4 v3 = *(const float4*)&KT[n+3][c0];
#pragma unroll
    for (int i = 0; i < 4; ++i) {
      float4 p4 = *(const float4*)&sp[r0+i][n];
      o[i][0] += p4.x*v0.x + p4.y*v1.x + p4.z*v2.x + p4.w*v3.x;
      o[i][1] += p4.x*v0.y + p4.y*v1.y + p4.z*v2.y + p4.w*v3.y;
      o[i][2] += p4.x*v0.z + p4.y*v1.z + p4.z*v2.z + p4.w*v3.z;
      o[i][3] += p4.x*v0.w + p4.y*v1.w + p4.z*v2.w + p4.w*v3.w;
    }
  }

  // ---- epilogue: h2 = bn1(x1) + O/sum (bn fused; read-before-write, same offsets) ----
  float4 sc = *(const float4*)&bns[256 + c0];
  float4 sh = *(const float4*)&bns[384 + c0];
#pragma unroll
  for (int i = 0; i < 4; ++i) {
    size_t off = (size_t)(rowg + r0 + i)*128 + c0;
    float4 xv = *(const float4*)&x1b[off];
    float4 r4;
    r4.x = xv.x*sc.x + sh.x + o[i][0]*inv[i];
    r4.y = xv.y*sc.y + sh.y + o[i][1]*inv[i];
    r4.z = xv.z*sc.z + sh.z + o[i][2]*inv[i];
    r4.w = xv.w*sc.w + sh.w + o[i][3]*inv[i];
    *(float4*)&h2v[off] = r4;
  }
}

// ---------------- launch ----------------
extern "C" void kernel_launch(void* const* d_in, const int* in_sizes, int n_in,
                              void* d_out, int out_size, void* d_ws, size_t ws_size,
                              hipStream_t stream)
{
  const float* h_lig     = (const float*)d_in[0];
  const float* h_rec     = (const float*)d_in[1];
  const float* x_lig     = (const float*)d_in[2];
  const float* x_rec     = (const float*)d_in[3];
  const float* he_1      = (const float*)d_in[4];
  const float* he_2      = (const float*)d_in[5];
  const float* emlp_w1   = (const float*)d_in[6];
  const float* emlp_b1   = (const float*)d_in[7];
  const float* emlp_bn_g = (const float*)d_in[8];
  const float* emlp_bn_b = (const float*)d_in[9];
  const float* emlp_w2   = (const float*)d_in[10];
  const float* emlp_b2   = (const float*)d_in[11];
  const float* bern_temp = (const float*)d_in[12];
  const float* m_in_w    = (const float*)d_in[13];
  const float* m_conv_w  = (const float*)d_in[14];
  const float* m_conv_b  = (const float*)d_in[15];
  const float* m_xproj_w = (const float*)d_in[16];
  const float* m_dt_w    = (const float*)d_in[17];
  const float* m_dt_b    = (const float*)d_in[18];
  const float* m_A_log   = (const float*)d_in[19];
  const float* m_D       = (const float*)d_in[20];
  const float* m_out_w   = (const float*)d_in[21];
  const float* q_w       = (const float*)d_in[22];
  const float* k_w       = (const float*)d_in[23];
  const float* v_w       = (const float*)d_in[24];
  const float* bn1_g     = (const float*)d_in[25];
  const float* bn1_b     = (const float*)d_in[26];
  const float* bn2_g     = (const float*)d_in[27];
  const float* bn2_b     = (const float*)d_in[28];
  const float* ff_w1     = (const float*)d_in[29];
  const float* ff_b1     = (const float*)d_in[30];
  const float* ff_w2     = (const float*)d_in[31];
  const float* ff_b2     = (const float*)d_in[32];
  const int*   ei1       = (const int*)d_in[33];
  const int*   ei2       = (const int*)d_in[34];
  const int*   perm1     = (const int*)d_in[37];
  const int*   perm2     = (const int*)d_in[38];

  float* ws   = (float*)d_ws;
  float* dout = (float*)d_out;

#define B0(off) (ws + (size_t)(off))
#define B1(off) (ws + SS_ + (size_t)(off))

  for (int s = 0; s < 2; ++s)
    hipMemsetAsync((char*)d_ws + ((size_t)s*SS_ + DEG_OFF)*sizeof(float), 0,
                   (N_ + 2048)*sizeof(float), stream);

  // edge weights (champion structure, fp16-packed dot2 core)
  edge_stats_kernel<<<dim3(256,2), 256, 0, stream>>>(x_lig,x_rec,he_1,he_2,ei1,ei2,emlp_w1,emlp_b1,ws);
  edge_finalize_kernel<<<dim3(1,2), 128, 0, stream>>>(emlp_bn_g,emlp_bn_b,emlp_w2,emlp_b2,ws);
  edge_w_kernel<<<dim3(256,2), 256, 0, stream>>>(x_lig,x_rec,he_1,he_2,ei1,ei2,emlp_w1,emlp_b1,ws);

  // bernstein propagation (Horner, 6 matmuls)
  bern_horner_kernel<<<dim3(G_*4,2), 256, 0, stream>>>(h_lig,h_rec,ei1,ei2,bern_temp,ws);

  // mamba (in_w / out_w GEMMs in fp16-fdot2; xproj stays fp32)
  gemm_kernel<128,256,64,4,0,1,0,0,0,0,1><<<dim3(512,2),256,0,stream>>>(
      h_lig,h_rec,128, m_in_w,nullptr, B0(XZ_OFF),B1(XZ_OFF),256, perm1,perm2, nullptr,nullptr, nullptr,nullptr);
  conv_kernel<<<dim3(2048,2), 256, 0, stream>>>(m_conv_w,m_conv_b,ws);
  gemm_kernel<128,40,64,1,0,0,0,0,0><<<dim3(128,2),256,0,stream>>>(
      B0(XC_OFF),B1(XC_OFF),128, m_xproj_w,nullptr, B0(DBL_OFF),B1(DBL_OFF),40, nullptr,nullptr, nullptr,nullptr, nullptr,nullptr);
  scan_kernel<<<dim3(32,8,2), 256, 0, stream>>>(m_A_log,m_D,m_dt_w,m_dt_b,ws);
  gemm_kernel<128,128,64,2,0,0,1,0,0,0,1><<<dim3(256,2),256,0,stream>>>(
      B0(XZ_OFF),B1(XZ_OFF),256, m_out_w,nullptr, B0(HA_OFF),B1(HA_OFF),128, perm1,perm2, nullptr,nullptr, nullptr,nullptr);

  // bn1 stats ( h + h_local + ha ); bn1 APPLY is fused into qkv + attn
  stats_kernel<<<dim3(128,2), 256, 0, stream>>>(h_lig,h_rec,ws,0,512);
  bn_finalize_kernel<<<dim3(1,2), 128, 0, stream>>>(bn1_g,bn1_b,ws,512,1.f/(float)N_);

  // q,k,v projections (bn1 fused in A-staging, fp16-fdot2)
  qkv_kernel<<<dim3(256,2,3), 256, 0, stream>>>(q_w,k_w,v_w,ws);
  attn_kernel<<<dim3(32,4,2), 256, 0, stream>>>(ws);

  // ffn + bn2 (fp16-fdot2; bn2 stats fused into ff_w2 epilogue)
  gemm_kernel<128,256,64,4,2,0,0,0,1,0,1><<<dim3(512,2),256,0,stream>>>(
      B0(X1_OFF),B1(X1_OFF),128, ff_w1,ff_b1, B0(XZ_OFF),B1(XZ_OFF),256, nullptr,nullptr, nullptr,nullptr, nullptr,nullptr);
  gemm_kernel<256,128,32,4,0,0,0,1,1,1,1><<<dim3(512,2),256,0,stream>>>(
      B0(XZ_OFF),B1(XZ_OFF),256, ff_w2,ff_b2, B0(HA_OFF),B1(HA_OFF),128, nullptr,nullptr, B0(X1_OFF),B1(X1_OFF),
      B0(STATS_OFF+1024), B1(STATS_OFF+1024));
  bn_finalize_kernel<<<dim3(1,2), 128, 0, stream>>>(bn2_g,bn2_b,ws,1024,1.f/(float)N_);
  bn_apply_kernel<<<dim3(2048,2), 256, 0, stream>>>(ws,dout,HA_OFF,0,1024,1);
}